// Round 5
// baseline (1733.662 us; speedup 1.0000x reference)
//
#include <hip/hip_runtime.h>
#include <hip/hip_cooperative_groups.h>
#include <cstdint>

namespace cg = cooperative_groups;

#define NEG_SLOPE 0.2f
#define LDA 136
#define HB  128         // hist/pair chunks
#define CAP 5120        // per-bucket pair capacity (mean 4096 + 16 sigma)
#define FUSED_GRID 1280 // 5 blocks/CU on 256 CUs
#define SMEM_BYTES (64 * LDA * 2)   // 17408 B, max over all phases

__device__ __forceinline__ float leaky(float v) { return v > 0.f ? v : NEG_SLOPE * v; }
__device__ __forceinline__ float elu(float v) { return v > 0.f ? v : __expf(v) - 1.f; }

typedef _Float16 half2v __attribute__((ext_vector_type(2)));
typedef _Float16 f16x8 __attribute__((ext_vector_type(8)));
typedef float f32x4 __attribute__((ext_vector_type(4)));
union H8 { float4 f4; half2v h[4]; };
union H4 { float2 f2; half2v h[2]; };
union HF2 { float2 f2; _Float16 h[4]; };

// ================= phase bodies (shared by fused + fallback) =================

__device__ __forceinline__ void prep_body(int bid, int G, int tid,
        const float* __restrict__ W1, const float* __restrict__ W2,
        _Float16* __restrict__ W1t, _Float16* __restrict__ W2t) {
    for (int i = bid * 256 + tid; i < 128 * 128; i += G * 256) {
        int c = i >> 7, k = i & 127;
        W1t[i] = (_Float16)W1[k * 128 + c];
    }
    for (int i = bid * 256 + tid; i < 32 * 128; i += G * 256) {
        int c = i >> 7, k = i & 127;
        W2t[i] = (_Float16)W2[k * 32 + c];
    }
}

__device__ __forceinline__ void gemm1_tile(int b, int tid, _Float16* Ah,
        const float* __restrict__ x, const _Float16* __restrict__ W1t,
        const float* __restrict__ a_src, const float* __restrict__ a_dst,
        _Float16* __restrict__ h1h, float* __restrict__ as1, float* __restrict__ ad1,
        int n) {
    int row0 = b * 64;
    const float4* x4 = (const float4*)x;
#pragma unroll
    for (int i = 0; i < 8; ++i) {
        int idx = tid + i * 256;          // float4 id: row*32 + c4
        int row = idx >> 5, c4 = idx & 31;
        float4 v = make_float4(0.f, 0.f, 0.f, 0.f);
        if (row0 + row < n) v = x4[(size_t)(row0 + row) * 32 + c4];
        HF2 u;
        u.h[0] = (_Float16)v.x; u.h[1] = (_Float16)v.y;
        u.h[2] = (_Float16)v.z; u.h[3] = (_Float16)v.w;
        *(float2*)&Ah[row * LDA + c4 * 4] = u.f2;
    }
    __syncthreads();

    int l = tid & 63, w = tid >> 6;
    int lr = l & 15, lg = l >> 4;
    f16x8 af[4];
#pragma unroll
    for (int kk = 0; kk < 4; ++kk)
        af[kk] = *(const f16x8*)&Ah[(w * 16 + lr) * LDA + kk * 32 + lg * 8];
    f32x4 acc[8];
#pragma unroll
    for (int t = 0; t < 8; ++t) acc[t] = (f32x4)0.f;
#pragma unroll
    for (int t = 0; t < 8; ++t) {
#pragma unroll
        for (int kk = 0; kk < 4; ++kk) {
            f16x8 bf = *(const f16x8*)&W1t[(size_t)(t * 16 + lr) * 128 + kk * 32 + lg * 8];
            acc[t] = __builtin_amdgcn_mfma_f32_16x16x32_f16(af[kk], bf, acc[t], 0, 0, 0);
        }
    }
    __syncthreads();
#pragma unroll
    for (int t = 0; t < 8; ++t)
#pragma unroll
        for (int r = 0; r < 4; ++r)
            Ah[(w * 16 + lg * 4 + r) * LDA + t * 16 + lr] = (_Float16)acc[t][r];
    __syncthreads();
    int row = tid >> 2, q = tid & 3;
    if (row0 + row < n) {
        const float* asv = a_src + q * 32;
        const float* adv = a_dst + q * 32;
        float ps = 0.f, pd = 0.f;
#pragma unroll
        for (int j = 0; j < 4; ++j) {
            f16x8 v = *(const f16x8*)&Ah[row * LDA + q * 32 + j * 8];
            *(f16x8*)&h1h[(size_t)(row0 + row) * 128 + q * 32 + j * 8] = v;
#pragma unroll
            for (int e = 0; e < 8; ++e) {
                float f = (float)v[e];
                ps += f * asv[j * 8 + e];
                pd += f * adv[j * 8 + e];
            }
        }
        as1[(row0 + row) * 4 + q] = ps;
        ad1[(row0 + row) * 4 + q] = pd;
    }
    __syncthreads();
}

__device__ __forceinline__ void hist_chunk(int c, int tid, int* lh,
        const int* __restrict__ dstp, int* __restrict__ hist, int E, int NB, int CH) {
    for (int t = tid; t < NB; t += 256) lh[t] = 0;
    __syncthreads();
    int e0 = c * CH, e1 = min(e0 + CH, E);
    int nv = (e1 - e0) & ~3;
    for (int i = e0 + tid * 4; i < e0 + nv; i += 1024) {
        int4 d = *(const int4*)(dstp + i);
        atomicAdd(&lh[d.x >> 8], 1);
        atomicAdd(&lh[d.y >> 8], 1);
        atomicAdd(&lh[d.z >> 8], 1);
        atomicAdd(&lh[d.w >> 8], 1);
    }
    for (int i = e0 + nv + tid; i < e1; i += 256)
        atomicAdd(&lh[dstp[i] >> 8], 1);
    __syncthreads();
    for (int t = tid; t < NB; t += 256) hist[c * NB + t] = lh[t];
    __syncthreads();
}

__device__ __forceinline__ void pair_chunk(int c, int tid, int* lcur,
        const int* __restrict__ src, const int* __restrict__ dstp,
        const int* __restrict__ hist, int2* __restrict__ pairs,
        int E, int NB, int CH) {
    for (int b = tid; b < NB; b += 256) {
        int s = 0;
        for (int i = 0; i < c; ++i) s += hist[i * NB + b];
        lcur[b] = s;
    }
    __syncthreads();
    int e0 = c * CH, e1 = min(e0 + CH, E);
    int nv = (e1 - e0) & ~3;
    for (int i = e0 + tid * 4; i < e0 + nv; i += 1024) {
        int4 d = *(const int4*)(dstp + i);
        int4 s = *(const int4*)(src + i);
        int b0 = d.x >> 8, b1 = d.y >> 8, b2 = d.z >> 8, b3 = d.w >> 8;
        int r0 = atomicAdd(&lcur[b0], 1);
        int r1 = atomicAdd(&lcur[b1], 1);
        int r2 = atomicAdd(&lcur[b2], 1);
        int r3 = atomicAdd(&lcur[b3], 1);
        if (r0 < CAP) pairs[(size_t)b0 * CAP + r0] = make_int2(s.x, d.x & 255);
        if (r1 < CAP) pairs[(size_t)b1 * CAP + r1] = make_int2(s.y, d.y & 255);
        if (r2 < CAP) pairs[(size_t)b2 * CAP + r2] = make_int2(s.z, d.z & 255);
        if (r3 < CAP) pairs[(size_t)b3 * CAP + r3] = make_int2(s.w, d.w & 255);
    }
    for (int i = e0 + nv + tid; i < e1; i += 256) {
        int d = dstp[i];
        int b = d >> 8;
        int r = atomicAdd(&lcur[b], 1);
        if (r < CAP) pairs[(size_t)b * CAP + r] = make_int2(src[i], d & 255);
    }
    __syncthreads();
}

__device__ __forceinline__ void csr_bucket(int b, int tid, unsigned char* smem,
        const int2* __restrict__ pairs, const int* __restrict__ hist,
        int* __restrict__ rp, int* __restrict__ col, int E, int N, int NB) {
    int* lsz    = (int*)smem;
    int* lstart = lsz + 256;
    int* lnh    = lstart + 256;
    int* lnex   = lnh + 256;
    int* lncur  = lnex + 256;
    int* wsum   = lncur + 256;
    int* woff   = wsum + 4;
    int lane = tid & 63, wv = tid >> 6;

    {
        int s = 0;
        if (tid < NB)
            for (int i = 0; i < HB; ++i) s += hist[i * NB + tid];
        lsz[tid] = s;
    }
    __syncthreads();
    int v = lsz[tid];
    int x = v;
#pragma unroll
    for (int o = 1; o < 64; o <<= 1) { int u = __shfl_up(x, o); if (lane >= o) x += u; }
    if (lane == 63) wsum[wv] = x;
    __syncthreads();
    if (tid == 0) { int a = 0; for (int i = 0; i < 4; ++i) { woff[i] = a; a += wsum[i]; } }
    __syncthreads();
    lstart[tid] = x - v + woff[wv];
    __syncthreads();

    if (b >= NB) { if (tid == 0) rp[N] = E; return; }
    int myStart = lstart[b];
    int S = lsz[b]; if (S > CAP) S = CAP;
    const int2* pb = pairs + (size_t)b * CAP;

    lnh[tid] = 0;
    __syncthreads();
    for (int i = tid; i < S; i += 256) atomicAdd(&lnh[pb[i].y], 1);
    __syncthreads();
    int v2 = lnh[tid];
    int x2 = v2;
#pragma unroll
    for (int o = 1; o < 64; o <<= 1) { int u = __shfl_up(x2, o); if (lane >= o) x2 += u; }
    if (lane == 63) wsum[wv] = x2;
    __syncthreads();
    if (tid == 0) { int a = 0; for (int i = 0; i < 4; ++i) { woff[i] = a; a += wsum[i]; } }
    __syncthreads();
    int ex2 = x2 - v2 + woff[wv];
    lnex[tid] = ex2;
    lncur[tid] = 0;
    int node = (b << 8) + tid;
    if (node <= N) rp[node] = myStart + ex2;
    __syncthreads();
    for (int i = tid; i < S; i += 256) {
        int2 p = pb[i];
        int r = atomicAdd(&lncur[p.y], 1);
        col[myStart + lnex[p.y] + r] = p.x;
    }
    __syncthreads();
}

__device__ __forceinline__ void agg1_group(int v, int tid, float4* s_p,
        const _Float16* __restrict__ h1h, const float4* __restrict__ as1,
        const float4* __restrict__ ad1, const int* __restrict__ rp,
        const int* __restrict__ col, const float* __restrict__ b1,
        _Float16* __restrict__ hph, int n) {
    int wave = tid >> 6, lane = tid & 63;
    int nid = v * 4 + wave;
    if (nid >= n) return;
    float4* sp = s_p + wave * 64;
    int start = rp[nid], end = rp[nid + 1];
    float4 adn = ad1[nid], asn = as1[nid];
    float4 psf;
    psf.x = __expf(leaky(asn.x + adn.x));
    psf.y = __expf(leaky(asn.y + adn.y));
    psf.z = __expf(leaky(asn.z + adn.z));
    psf.w = __expf(leaky(asn.w + adn.w));
    float4 dsum = make_float4(0.f, 0.f, 0.f, 0.f);
    int g = lane & 15, sub = lane >> 4;
    int head = g >> 2;
    float4 a0 = make_float4(0.f, 0.f, 0.f, 0.f);
    float4 a1 = a0;

    for (int base = start; base < end; base += 64) {
        int i = base + lane;
        int sidx = 0;
        float4 p = make_float4(0.f, 0.f, 0.f, 0.f);
        if (i < end) {
            sidx = col[i];
            float4 a = as1[sidx];
            p.x = __expf(leaky(a.x + adn.x));
            p.y = __expf(leaky(a.y + adn.y));
            p.z = __expf(leaky(a.z + adn.z));
            p.w = __expf(leaky(a.w + adn.w));
            dsum.x += p.x; dsum.y += p.y; dsum.z += p.z; dsum.w += p.w;
        }
        sp[lane] = p;
        int len = min(64, end - base);
        int steps = (len + 3) >> 2;
        for (int s = 0; s < steps; ++s) {
            int j = s * 4 + sub;
            int js = (j < len) ? j : 0;
            int rj = __shfl(sidx, js);
            if (j < len) {
                float pj = ((const float*)&sp[js])[head];
                H8 u = ((const H8*)(h1h + (size_t)rj * 128))[g];
                a0.x += (float)u.h[0].x * pj; a0.y += (float)u.h[0].y * pj;
                a0.z += (float)u.h[1].x * pj; a0.w += (float)u.h[1].y * pj;
                a1.x += (float)u.h[2].x * pj; a1.y += (float)u.h[2].y * pj;
                a1.z += (float)u.h[3].x * pj; a1.w += (float)u.h[3].y * pj;
            }
        }
    }
    if (sub == 0) {
        float pj = (head == 0) ? psf.x : (head == 1) ? psf.y : (head == 2) ? psf.z : psf.w;
        H8 u = ((const H8*)(h1h + (size_t)nid * 128))[g];
        a0.x += (float)u.h[0].x * pj; a0.y += (float)u.h[0].y * pj;
        a0.z += (float)u.h[1].x * pj; a0.w += (float)u.h[1].y * pj;
        a1.x += (float)u.h[2].x * pj; a1.y += (float)u.h[2].y * pj;
        a1.z += (float)u.h[3].x * pj; a1.w += (float)u.h[3].y * pj;
    }
    if (lane == 0) {
        dsum.x += psf.x; dsum.y += psf.y; dsum.z += psf.z; dsum.w += psf.w;
    }
#pragma unroll
    for (int o = 1; o < 64; o <<= 1) {
        dsum.x += __shfl_xor(dsum.x, o); dsum.y += __shfl_xor(dsum.y, o);
        dsum.z += __shfl_xor(dsum.z, o); dsum.w += __shfl_xor(dsum.w, o);
    }
#pragma unroll
    for (int o = 16; o < 64; o <<= 1) {
        a0.x += __shfl_xor(a0.x, o); a0.y += __shfl_xor(a0.y, o);
        a0.z += __shfl_xor(a0.z, o); a0.w += __shfl_xor(a0.w, o);
        a1.x += __shfl_xor(a1.x, o); a1.y += __shfl_xor(a1.y, o);
        a1.z += __shfl_xor(a1.z, o); a1.w += __shfl_xor(a1.w, o);
    }
    if (sub == 0) {
        float den = (head == 0) ? dsum.x : (head == 1) ? dsum.y : (head == 2) ? dsum.z : dsum.w;
        float inv = __builtin_amdgcn_rcpf(den);
        const float4* b4 = (const float4*)b1;
        float4 bb0 = b4[g * 2], bb1 = b4[g * 2 + 1];
        float4 r0 = make_float4(elu(a0.x * inv + bb0.x), elu(a0.y * inv + bb0.y),
                                elu(a0.z * inv + bb0.z), elu(a0.w * inv + bb0.w));
        float4 r1 = make_float4(elu(a1.x * inv + bb1.x), elu(a1.y * inv + bb1.y),
                                elu(a1.z * inv + bb1.z), elu(a1.w * inv + bb1.w));
        H8 o8;
        o8.h[0] = half2v{(_Float16)r0.x, (_Float16)r0.y};
        o8.h[1] = half2v{(_Float16)r0.z, (_Float16)r0.w};
        o8.h[2] = half2v{(_Float16)r1.x, (_Float16)r1.y};
        o8.h[3] = half2v{(_Float16)r1.z, (_Float16)r1.w};
        *(float4*)&hph[(size_t)nid * 128 + g * 8] = o8.f4;
    }
}

__device__ __forceinline__ void gemm2_tile(int b, int tid,
        const _Float16* __restrict__ hph, const _Float16* __restrict__ W2t,
        const float* __restrict__ a_src, const float* __restrict__ a_dst,
        _Float16* __restrict__ h2h, float* __restrict__ as2, float* __restrict__ ad2,
        int n) {
    int l = tid & 63, w = tid >> 6;
    int lr = l & 15, lg = l >> 4;
    int row0 = b * 64;
    int arow = row0 + w * 16 + lr;
    size_t abase = (size_t)(arow < n ? arow : 0) * 128;
    f16x8 af[4];
#pragma unroll
    for (int kk = 0; kk < 4; ++kk)
        af[kk] = *(const f16x8*)&hph[abase + kk * 32 + lg * 8];
    f32x4 acc[2];
    acc[0] = (f32x4)0.f; acc[1] = (f32x4)0.f;
#pragma unroll
    for (int t = 0; t < 2; ++t)
#pragma unroll
        for (int kk = 0; kk < 4; ++kk) {
            f16x8 bf = *(const f16x8*)&W2t[(t * 16 + lr) * 128 + kk * 32 + lg * 8];
            acc[t] = __builtin_amdgcn_mfma_f32_16x16x32_f16(af[kk], bf, acc[t], 0, 0, 0);
        }
    float a0 = a_src[lr], a1 = a_src[16 + lr];
    float d0 = a_dst[lr], d1 = a_dst[16 + lr];
#pragma unroll
    for (int r = 0; r < 4; ++r) {
        int row = row0 + w * 16 + lg * 4 + r;
        float ps = acc[0][r] * a0 + acc[1][r] * a1;
        float pd = acc[0][r] * d0 + acc[1][r] * d1;
#pragma unroll
        for (int o = 1; o < 16; o <<= 1) { ps += __shfl_xor(ps, o); pd += __shfl_xor(pd, o); }
        if (row < n) {
            h2h[(size_t)row * 32 + lr] = (_Float16)acc[0][r];
            h2h[(size_t)row * 32 + 16 + lr] = (_Float16)acc[1][r];
            if (lr == 0) { as2[row] = ps; ad2[row] = pd; }
        }
    }
}

__device__ __forceinline__ void agg2_group(int v, int tid,
        const _Float16* __restrict__ h2h, const float* __restrict__ as2,
        const float* __restrict__ ad2, const int* __restrict__ rp,
        const int* __restrict__ col, const float* __restrict__ b2,
        float* __restrict__ out, int n) {
    int wave = tid >> 6, lane = tid & 63;
    int nid = v * 4 + wave;
    if (nid >= n) return;
    int start = rp[nid], end = rp[nid + 1];
    float adn = ad2[nid];
    float psf = __expf(leaky(as2[nid] + adn));
    float dsum = 0.f;
    int g = lane & 7, sub = lane >> 3;
    float4 acc = make_float4(0.f, 0.f, 0.f, 0.f);
    for (int base = start; base < end; base += 64) {
        int i = base + lane;
        int sidx = 0;
        float p = 0.f;
        if (i < end) {
            sidx = col[i];
            p = __expf(leaky(as2[sidx] + adn));
            dsum += p;
        }
        int len = min(64, end - base);
        int steps = (len + 7) >> 3;
        for (int s = 0; s < steps; ++s) {
            int j = s * 8 + sub;
            int js = (j < len) ? j : 0;
            int rj = __shfl(sidx, js);
            float pj = __shfl(p, js);
            if (j < len) {
                H4 u = ((const H4*)(h2h + (size_t)rj * 32))[g];
                acc.x += (float)u.h[0].x * pj; acc.y += (float)u.h[0].y * pj;
                acc.z += (float)u.h[1].x * pj; acc.w += (float)u.h[1].y * pj;
            }
        }
    }
    if (sub == 0) {
        H4 u = ((const H4*)(h2h + (size_t)nid * 32))[g];
        acc.x += (float)u.h[0].x * psf; acc.y += (float)u.h[0].y * psf;
        acc.z += (float)u.h[1].x * psf; acc.w += (float)u.h[1].y * psf;
    }
    if (lane == 0) dsum += psf;
#pragma unroll
    for (int o = 1; o < 64; o <<= 1) dsum += __shfl_xor(dsum, o);
#pragma unroll
    for (int o = 8; o < 64; o <<= 1) {
        acc.x += __shfl_xor(acc.x, o); acc.y += __shfl_xor(acc.y, o);
        acc.z += __shfl_xor(acc.z, o); acc.w += __shfl_xor(acc.w, o);
    }
    if (sub == 0) {
        float inv = __builtin_amdgcn_rcpf(dsum);
        float4 bb = ((const float4*)b2)[g];
        ((float4*)(out + (size_t)nid * 32))[g] =
            make_float4(acc.x * inv + bb.x, acc.y * inv + bb.y,
                        acc.z * inv + bb.z, acc.w * inv + bb.w);
    }
}

// ================= fused cooperative kernel =================

struct FP {
    const float* x; const int* src; const int* dstp;
    const float* W1; const float* a_src1; const float* a_dst1; const float* b1;
    const float* W2; const float* a_src2; const float* a_dst2; const float* b2;
    float* out;
    _Float16 *h1h, *hph, *h2h, *W1t, *W2t;
    float *as1, *ad1, *as2, *ad2;
    int *rp, *col, *hist;
    int2* pairs;
    int N, E, NB, KB, CH, gemmBlocks, gemm2Blocks, aggGroups;
};

__global__ __launch_bounds__(256, 5) void fused_kernel(FP p) {
    cg::grid_group grid = cg::this_grid();
    __shared__ __align__(16) unsigned char smem[SMEM_BYTES];
    int tid = threadIdx.x, bid = (int)blockIdx.x, G = (int)gridDim.x;

    // P0: weight transposes
    prep_body(bid, G, tid, p.W1, p.W2, p.W1t, p.W2t);
    __threadfence();
    grid.sync();

    // P1: gemm1 tiles + level-1 histogram
    for (int b = bid; b < p.gemmBlocks; b += G)
        gemm1_tile(b, tid, (_Float16*)smem, p.x, p.W1t, p.a_src1, p.a_dst1,
                   p.h1h, p.as1, p.ad1, p.N);
    if (G >= p.gemmBlocks + HB) {
        int c = bid - (G - HB);
        if (c >= 0 && c < HB) {
            __syncthreads();
            hist_chunk(c, tid, (int*)smem, p.dstp, p.hist, p.E, p.NB, p.CH);
        }
    } else {
        for (int c = bid; c < HB; c += G) {
            __syncthreads();
            hist_chunk(c, tid, (int*)smem, p.dstp, p.hist, p.E, p.NB, p.CH);
        }
    }
    __threadfence();
    grid.sync();

    // P2: pair scatter
    for (int c = bid; c < HB; c += G)
        pair_chunk(c, tid, (int*)smem, p.src, p.dstp, p.hist, p.pairs, p.E, p.NB, p.CH);
    __threadfence();
    grid.sync();

    // P3: per-bucket CSR build
    for (int b = bid; b < p.KB; b += G) {
        csr_bucket(b, tid, smem, p.pairs, p.hist, p.rp, p.col, p.E, p.N, p.NB);
        __syncthreads();
    }
    __threadfence();
    grid.sync();

    // P4: layer-1 aggregate
    for (int v = bid; v < p.aggGroups; v += G)
        agg1_group(v, tid, (float4*)smem, p.h1h, (const float4*)p.as1,
                   (const float4*)p.ad1, p.rp, p.col, p.b1, p.hph, p.N);
    __threadfence();
    grid.sync();

    // P5: layer-2 GEMM
    for (int b = bid; b < p.gemm2Blocks; b += G)
        gemm2_tile(b, tid, p.hph, p.W2t, p.a_src2, p.a_dst2, p.h2h, p.as2, p.ad2, p.N);
    __threadfence();
    grid.sync();

    // P6: layer-2 aggregate
    for (int v = bid; v < p.aggGroups; v += G)
        agg2_group(v, tid, p.h2h, p.as2, p.ad2, p.rp, p.col, p.b2, p.out, p.N);
}

// ================= fallback standalone kernels (round-4 path) =================

__global__ __launch_bounds__(256) void prep_kernel(const float* __restrict__ W1,
                                                   const float* __restrict__ W2,
                                                   _Float16* __restrict__ W1t,
                                                   _Float16* __restrict__ W2t) {
    prep_body(blockIdx.x, gridDim.x, threadIdx.x, W1, W2, W1t, W2t);
}

__global__ __launch_bounds__(256) void gemm1_hist_kernel(
        const float* __restrict__ x, const _Float16* __restrict__ W1t,
        const float* __restrict__ a_src, const float* __restrict__ a_dst,
        _Float16* __restrict__ h1h, float* __restrict__ as1, float* __restrict__ ad1,
        int n, int gemmBlocks,
        const int* __restrict__ dstp, int* __restrict__ hist, int E, int NB, int CH) {
    __shared__ __align__(16) unsigned char smem[SMEM_BYTES];
    if ((int)blockIdx.x >= gemmBlocks) {
        hist_chunk((int)blockIdx.x - gemmBlocks, threadIdx.x, (int*)smem, dstp, hist, E, NB, CH);
        return;
    }
    gemm1_tile(blockIdx.x, threadIdx.x, (_Float16*)smem, x, W1t, a_src, a_dst,
               h1h, as1, ad1, n);
}

__global__ __launch_bounds__(256) void pair_kernel(const int* __restrict__ src,
                                                   const int* __restrict__ dstp,
                                                   const int* __restrict__ hist,
                                                   int2* __restrict__ pairs,
                                                   int E, int NB, int CH) {
    __shared__ int lcur[256];
    pair_chunk(blockIdx.x, threadIdx.x, lcur, src, dstp, hist, pairs, E, NB, CH);
}

__global__ __launch_bounds__(256) void csr_kernel(const int2* __restrict__ pairs,
                                                  const int* __restrict__ hist,
                                                  int* __restrict__ rp,
                                                  int* __restrict__ col,
                                                  int E, int N, int NB) {
    __shared__ __align__(16) unsigned char smem[5152];
    csr_bucket(blockIdx.x, threadIdx.x, smem, pairs, hist, rp, col, E, N, NB);
}

__global__ __launch_bounds__(256) void agg1_kernel(const _Float16* __restrict__ h1h,
                                                   const float4* __restrict__ as1,
                                                   const float4* __restrict__ ad1,
                                                   const int* __restrict__ rp,
                                                   const int* __restrict__ col,
                                                   const float* __restrict__ b1,
                                                   _Float16* __restrict__ hph, int n) {
    __shared__ float4 s_p[4 * 64];
    agg1_group(blockIdx.x, threadIdx.x, s_p, h1h, as1, ad1, rp, col, b1, hph, n);
}

__global__ __launch_bounds__(256) void gemm2_kernel(const _Float16* __restrict__ hph,
                                                    const _Float16* __restrict__ W2t,
                                                    const float* __restrict__ a_src,
                                                    const float* __restrict__ a_dst,
                                                    _Float16* __restrict__ h2h,
                                                    float* __restrict__ as2,
                                                    float* __restrict__ ad2, int n) {
    gemm2_tile(blockIdx.x, threadIdx.x, hph, W2t, a_src, a_dst, h2h, as2, ad2, n);
}

__global__ __launch_bounds__(256) void agg2_kernel(const _Float16* __restrict__ h2h,
                                                   const float* __restrict__ as2,
                                                   const float* __restrict__ ad2,
                                                   const int* __restrict__ rp,
                                                   const int* __restrict__ col,
                                                   const float* __restrict__ b2,
                                                   float* __restrict__ out, int n) {
    agg2_group(blockIdx.x, threadIdx.x, h2h, as2, ad2, rp, col, b2, out, n);
}

// ================= launch =================

extern "C" void kernel_launch(void* const* d_in, const int* in_sizes, int n_in,
                              void* d_out, int out_size, void* d_ws, size_t ws_size,
                              hipStream_t stream) {
    const float* x      = (const float*)d_in[0];
    const int*   ei     = (const int*)d_in[1];
    const float* W1     = (const float*)d_in[2];
    const float* a_src1 = (const float*)d_in[3];
    const float* a_dst1 = (const float*)d_in[4];
    const float* b1     = (const float*)d_in[5];
    const float* W2     = (const float*)d_in[6];
    const float* a_src2 = (const float*)d_in[7];
    const float* a_dst2 = (const float*)d_in[8];
    const float* b2     = (const float*)d_in[9];
    float* out = (float*)d_out;

    const int N = in_sizes[0] / 128;
    const int E = in_sizes[1] / 2;
    const int* src = ei;
    const int* dstp = ei + E;

    uint8_t* w = (uint8_t*)d_ws;
    auto carve = [&](size_t bytes) {
        uint8_t* p = w;
        w += (bytes + 255) & ~(size_t)255;
        return p;
    };
    _Float16* h1h = (_Float16*)carve((size_t)N * 128 * 2);
    _Float16* hph = (_Float16*)carve((size_t)N * 128 * 2);   // aliased by pairs (disjoint lifetime)
    _Float16* h2h = (_Float16*)carve((size_t)N * 32 * 2);
    _Float16* W1t = (_Float16*)carve((size_t)128 * 128 * 2);
    _Float16* W2t = (_Float16*)carve((size_t)32 * 128 * 2);
    float* as1 = (float*)carve((size_t)N * 4 * 4);
    float* ad1 = (float*)carve((size_t)N * 4 * 4);
    float* as2 = (float*)carve((size_t)N * 4);
    float* ad2 = (float*)carve((size_t)N * 4);
    int* rp    = (int*)carve((size_t)(N + 1) * 4);
    int* col   = (int*)carve((size_t)E * 4);
    int* hist  = (int*)carve((size_t)HB * 256 * 4);

    int2* pairs = (int2*)hph;            // NB*CAP*8 = 8.0 MB <= N*256 B

    const int NB = ((N - 1) >> 8) + 1;
    const int KB = (N >> 8) + 1;
    int CH = (E + HB - 1) / HB;
    CH = (CH + 3) & ~3;                  // keep int4 alignment of chunk bases
    const int gemmBlocks = (N + 63) / 64;
    const int gemm2Blocks = (N + 63) / 64;
    const int aggGroups = (N + 3) / 4;

    FP p = { x, src, dstp, W1, a_src1, a_dst1, b1, W2, a_src2, a_dst2, b2, out,
             h1h, hph, h2h, W1t, W2t, as1, ad1, as2, ad2, rp, col, hist, pairs,
             N, E, NB, KB, CH, gemmBlocks, gemm2Blocks, aggGroups };

    void* args[] = { (void*)&p };
    hipError_t err = hipLaunchCooperativeKernel((const void*)fused_kernel,
                                                dim3(FUSED_GRID), dim3(256),
                                                args, 0, stream);
    if (err != hipSuccess) {
        (void)hipGetLastError();   // clear sticky error, fall back to 7 dispatches
        prep_kernel<<<64, 256, 0, stream>>>(W1, W2, W1t, W2t);
        gemm1_hist_kernel<<<gemmBlocks + HB, 256, 0, stream>>>(
            x, W1t, a_src1, a_dst1, h1h, as1, ad1, N, gemmBlocks, dstp, hist, E, NB, CH);
        pair_kernel<<<HB, 256, 0, stream>>>(src, dstp, hist, pairs, E, NB, CH);
        csr_kernel<<<KB, 256, 0, stream>>>(pairs, hist, rp, col, E, N, NB);
        agg1_kernel<<<aggGroups, 256, 0, stream>>>(h1h, (const float4*)as1,
                                                   (const float4*)ad1, rp, col, b1, hph, N);
        gemm2_kernel<<<gemm2Blocks, 256, 0, stream>>>(hph, W2t, a_src2, a_dst2,
                                                      h2h, as2, ad2, N);
        agg2_kernel<<<aggGroups, 256, 0, stream>>>(h2h, as2, ad2, rp, col, b2, out, N);
    }
}

// Round 6
// 236.027 us; speedup vs baseline: 7.3452x; 7.3452x over previous
//
#include <hip/hip_runtime.h>
#include <cstdint>

#define NEG_SLOPE 0.2f
#define LDA 136
#define HB  128         // hist/pair chunks
#define CAP 5120        // per-bucket pair capacity (mean 4096 + 16 sigma)
#define SMEM_BYTES (64 * LDA * 2)   // 17408 B

__device__ __forceinline__ float leaky(float v) { return v > 0.f ? v : NEG_SLOPE * v; }
__device__ __forceinline__ float elu(float v) { return v > 0.f ? v : __expf(v) - 1.f; }

typedef _Float16 half2v __attribute__((ext_vector_type(2)));
typedef _Float16 f16x8 __attribute__((ext_vector_type(8)));
typedef float f32x4 __attribute__((ext_vector_type(4)));
union H8 { float4 f4; half2v h[4]; f16x8 v8; };
union H4 { float2 f2; half2v h[2]; };
union HF2 { float2 f2; _Float16 h[4]; };
union HH { f16x8 v; half2v h[4]; };

// ================= phase bodies =================

__device__ __forceinline__ void prep_body(int bid, int G, int tid,
        const float* __restrict__ W1, const float* __restrict__ W2,
        _Float16* __restrict__ W1t, _Float16* __restrict__ W2t) {
    for (int i = bid * 256 + tid; i < 128 * 128; i += G * 256) {
        int c = i >> 7, k = i & 127;
        W1t[i] = (_Float16)W1[k * 128 + c];
    }
    for (int i = bid * 256 + tid; i < 32 * 128; i += G * 256) {
        int c = i >> 7, k = i & 127;
        W2t[i] = (_Float16)W2[k * 32 + c];
    }
}

__device__ __forceinline__ void hist_chunk(int c, int tid, int* lh,
        const int* __restrict__ dstp, int* __restrict__ hist, int E, int NB, int CH) {
    for (int t = tid; t < NB; t += 256) lh[t] = 0;
    __syncthreads();
    int e0 = c * CH, e1 = min(e0 + CH, E);
    int nv = (e1 - e0) & ~3;
    for (int i = e0 + tid * 4; i < e0 + nv; i += 1024) {
        int4 d = *(const int4*)(dstp + i);
        atomicAdd(&lh[d.x >> 8], 1);
        atomicAdd(&lh[d.y >> 8], 1);
        atomicAdd(&lh[d.z >> 8], 1);
        atomicAdd(&lh[d.w >> 8], 1);
    }
    for (int i = e0 + nv + tid; i < e1; i += 256)
        atomicAdd(&lh[dstp[i] >> 8], 1);
    __syncthreads();
    for (int t = tid; t < NB; t += 256) hist[c * NB + t] = lh[t];
}

__device__ __forceinline__ void gemm1_tile(int b, int tid, _Float16* Ah,
        const float* __restrict__ x, const _Float16* __restrict__ W1t,
        const float* __restrict__ a_src, const float* __restrict__ a_dst,
        _Float16* __restrict__ h1h, float* __restrict__ as1, float* __restrict__ ad1,
        int n) {
    int row0 = b * 64;
    const float4* x4 = (const float4*)x;
#pragma unroll
    for (int i = 0; i < 8; ++i) {
        int idx = tid + i * 256;          // float4 id: row*32 + c4
        int row = idx >> 5, c4 = idx & 31;
        float4 v = make_float4(0.f, 0.f, 0.f, 0.f);
        if (row0 + row < n) v = x4[(size_t)(row0 + row) * 32 + c4];
        HF2 u;
        u.h[0] = (_Float16)v.x; u.h[1] = (_Float16)v.y;
        u.h[2] = (_Float16)v.z; u.h[3] = (_Float16)v.w;
        *(float2*)&Ah[row * LDA + c4 * 4] = u.f2;
    }
    __syncthreads();

    int l = tid & 63, w = tid >> 6;
    int lr = l & 15, lg = l >> 4;
    f16x8 af[4];
#pragma unroll
    for (int kk = 0; kk < 4; ++kk)
        af[kk] = *(const f16x8*)&Ah[(w * 16 + lr) * LDA + kk * 32 + lg * 8];
    f32x4 acc[8];
#pragma unroll
    for (int t = 0; t < 8; ++t) acc[t] = (f32x4)0.f;
#pragma unroll
    for (int t = 0; t < 8; ++t) {
#pragma unroll
        for (int kk = 0; kk < 4; ++kk) {
            f16x8 bf = *(const f16x8*)&W1t[(size_t)(t * 16 + lr) * 128 + kk * 32 + lg * 8];
            acc[t] = __builtin_amdgcn_mfma_f32_16x16x32_f16(af[kk], bf, acc[t], 0, 0, 0);
        }
    }
    __syncthreads();
#pragma unroll
    for (int t = 0; t < 8; ++t)
#pragma unroll
        for (int r = 0; r < 4; ++r)
            Ah[(w * 16 + lg * 4 + r) * LDA + t * 16 + lr] = (_Float16)acc[t][r];
    __syncthreads();
    int row = tid >> 2, q = tid & 3;
    if (row0 + row < n) {
        const float* asv = a_src + q * 32;
        const float* adv = a_dst + q * 32;
        float ps = 0.f, pd = 0.f;
#pragma unroll
        for (int j = 0; j < 4; ++j) {
            f16x8 v = *(const f16x8*)&Ah[row * LDA + q * 32 + j * 8];
            *(f16x8*)&h1h[(size_t)(row0 + row) * 128 + q * 32 + j * 8] = v;
#pragma unroll
            for (int e = 0; e < 8; ++e) {
                float f = (float)v[e];
                ps += f * asv[j * 8 + e];
                pd += f * adv[j * 8 + e];
            }
        }
        as1[(row0 + row) * 4 + q] = ps;
        ad1[(row0 + row) * 4 + q] = pd;
    }
}

__device__ __forceinline__ void pair_chunk(int c, int tid, int* lcur,
        const int* __restrict__ src, const int* __restrict__ dstp,
        const int* __restrict__ hist, int2* __restrict__ pairs,
        int E, int NB, int CH) {
    for (int b = tid; b < NB; b += 256) {
        int s = 0;
        for (int i = 0; i < c; ++i) s += hist[i * NB + b];
        lcur[b] = s;
    }
    __syncthreads();
    int e0 = c * CH, e1 = min(e0 + CH, E);
    int nv = (e1 - e0) & ~3;
    for (int i = e0 + tid * 4; i < e0 + nv; i += 1024) {
        int4 d = *(const int4*)(dstp + i);
        int4 s = *(const int4*)(src + i);
        int b0 = d.x >> 8, b1 = d.y >> 8, b2 = d.z >> 8, b3 = d.w >> 8;
        int r0 = atomicAdd(&lcur[b0], 1);
        int r1 = atomicAdd(&lcur[b1], 1);
        int r2 = atomicAdd(&lcur[b2], 1);
        int r3 = atomicAdd(&lcur[b3], 1);
        if (r0 < CAP) pairs[(size_t)b0 * CAP + r0] = make_int2(s.x, d.x & 255);
        if (r1 < CAP) pairs[(size_t)b1 * CAP + r1] = make_int2(s.y, d.y & 255);
        if (r2 < CAP) pairs[(size_t)b2 * CAP + r2] = make_int2(s.z, d.z & 255);
        if (r3 < CAP) pairs[(size_t)b3 * CAP + r3] = make_int2(s.w, d.w & 255);
    }
    for (int i = e0 + nv + tid; i < e1; i += 256) {
        int d = dstp[i];
        int b = d >> 8;
        int r = atomicAdd(&lcur[b], 1);
        if (r < CAP) pairs[(size_t)b * CAP + r] = make_int2(src[i], d & 255);
    }
}

// ================= kernels =================

// D1: weight transposes + level-1 histogram (both read only inputs)
__global__ __launch_bounds__(256) void prep_hist_kernel(
        const float* __restrict__ W1, const float* __restrict__ W2,
        _Float16* __restrict__ W1t, _Float16* __restrict__ W2t,
        const int* __restrict__ dstp, int* __restrict__ hist, int E, int NB, int CH) {
    __shared__ int lh[256];
    int bid = (int)blockIdx.x;
    if (bid < HB) {
        hist_chunk(bid, threadIdx.x, lh, dstp, hist, E, NB, CH);
        return;
    }
    prep_body(bid - HB, (int)gridDim.x - HB, threadIdx.x, W1, W2, W1t, W2t);
}

// D2: MFMA gemm1 tiles + level-1 pair scatter
__global__ __launch_bounds__(256) void gemm1_pair_kernel(
        const float* __restrict__ x, const _Float16* __restrict__ W1t,
        const float* __restrict__ a_src, const float* __restrict__ a_dst,
        _Float16* __restrict__ h1h, float* __restrict__ as1, float* __restrict__ ad1,
        int n, int gemmBlocks,
        const int* __restrict__ src, const int* __restrict__ dstp,
        const int* __restrict__ hist, int2* __restrict__ pairs, int E, int NB, int CH) {
    __shared__ __align__(16) unsigned char smem[SMEM_BYTES];
    int bid = (int)blockIdx.x;
    if (bid >= gemmBlocks) {
        pair_chunk(bid - gemmBlocks, threadIdx.x, (int*)smem, src, dstp, hist,
                   pairs, E, NB, CH);
        return;
    }
    gemm1_tile(bid, threadIdx.x, (_Float16*)smem, x, W1t, a_src, a_dst,
               h1h, as1, ad1, n);
}

// D3: level-2 per-bucket CSR build (rp + col)
__global__ __launch_bounds__(256) void csr_kernel(const int2* __restrict__ pairs,
                                                  const int* __restrict__ hist,
                                                  int* __restrict__ rp,
                                                  int* __restrict__ col,
                                                  int E, int N, int NB) {
    __shared__ int lsz[256], lstart[256];
    __shared__ int lnh[256], lnex[256], lncur[256];
    __shared__ int wsum[4], woff[4];
    int b = (int)blockIdx.x, tid = threadIdx.x;
    int lane = tid & 63, wv = tid >> 6;

    {
        int s = 0;
        if (tid < NB)
            for (int i = 0; i < HB; ++i) s += hist[i * NB + tid];
        lsz[tid] = s;
    }
    __syncthreads();
    int v = lsz[tid];
    int x = v;
#pragma unroll
    for (int o = 1; o < 64; o <<= 1) { int u = __shfl_up(x, o); if (lane >= o) x += u; }
    if (lane == 63) wsum[wv] = x;
    __syncthreads();
    if (tid == 0) { int a = 0; for (int i = 0; i < 4; ++i) { woff[i] = a; a += wsum[i]; } }
    __syncthreads();
    lstart[tid] = x - v + woff[wv];
    __syncthreads();

    if (b >= NB) { if (tid == 0) rp[N] = E; return; }
    int myStart = lstart[b];
    int S = lsz[b]; if (S > CAP) S = CAP;
    const int2* pb = pairs + (size_t)b * CAP;

    lnh[tid] = 0;
    __syncthreads();
    for (int i = tid; i < S; i += 256) atomicAdd(&lnh[pb[i].y], 1);
    __syncthreads();
    int v2 = lnh[tid];
    int x2 = v2;
#pragma unroll
    for (int o = 1; o < 64; o <<= 1) { int u = __shfl_up(x2, o); if (lane >= o) x2 += u; }
    if (lane == 63) wsum[wv] = x2;
    __syncthreads();
    if (tid == 0) { int a = 0; for (int i = 0; i < 4; ++i) { woff[i] = a; a += wsum[i]; } }
    __syncthreads();
    int ex2 = x2 - v2 + woff[wv];
    lnex[tid] = ex2;
    lncur[tid] = 0;
    int node = (b << 8) + tid;
    if (node <= N) rp[node] = myStart + ex2;
    __syncthreads();
    for (int i = tid; i < S; i += 256) {
        int2 p = pb[i];
        int r = atomicAdd(&lncur[p.y], 1);
        col[myStart + lnex[p.y] + r] = p.x;
    }
}

// D4: layer-1 softmax+aggregate, fused layer-2 GEMV (h2h, as2, ad2) -- no hph.
#define W2S 136   // sW2 row stride in halves (16B-aligned for b128 reads)

__global__ __launch_bounds__(256) void agg1_kernel(const _Float16* __restrict__ h1h,
                                                   const float4* __restrict__ as1,
                                                   const float4* __restrict__ ad1,
                                                   const int* __restrict__ rp,
                                                   const int* __restrict__ col,
                                                   const float* __restrict__ b1,
                                                   const _Float16* __restrict__ W2t,
                                                   const float* __restrict__ a_src2,
                                                   const float* __restrict__ a_dst2,
                                                   _Float16* __restrict__ h2h,
                                                   float* __restrict__ as2,
                                                   float* __restrict__ ad2, int n) {
    __shared__ float4 s_p[4][64];
    __shared__ _Float16 s_row[4][128];
    __shared__ _Float16 sW2[32 * W2S];
    int tid = threadIdx.x;
    // stage W2t -> LDS (8 KB, padded rows)
    for (int e = tid; e < 32 * 16; e += 256) {
        int c = e >> 4, k8 = e & 15;
        *(f16x8*)&sW2[c * W2S + k8 * 8] = *(const f16x8*)&W2t[c * 128 + k8 * 8];
    }
    float a2s = a_src2[tid & 31], a2d = a_dst2[tid & 31];
    __syncthreads();

    int wave = tid >> 6, lane = tid & 63;
    int nid = blockIdx.x * 4 + wave;
    if (nid >= n) return;
    float4* sp = s_p[wave];
    int start = rp[nid], end = rp[nid + 1];
    float4 adn = ad1[nid], asn = as1[nid];
    float4 psf;
    psf.x = __expf(leaky(asn.x + adn.x));
    psf.y = __expf(leaky(asn.y + adn.y));
    psf.z = __expf(leaky(asn.z + adn.z));
    psf.w = __expf(leaky(asn.w + adn.w));
    float4 dsum = make_float4(0.f, 0.f, 0.f, 0.f);
    int g = lane & 15, sub = lane >> 4;
    int head = g >> 2;
    float4 a0 = make_float4(0.f, 0.f, 0.f, 0.f);
    float4 a1 = a0;

    for (int base = start; base < end; base += 64) {
        int i = base + lane;
        int sidx = 0;
        float4 p = make_float4(0.f, 0.f, 0.f, 0.f);
        if (i < end) {
            sidx = col[i];
            float4 a = as1[sidx];
            p.x = __expf(leaky(a.x + adn.x));
            p.y = __expf(leaky(a.y + adn.y));
            p.z = __expf(leaky(a.z + adn.z));
            p.w = __expf(leaky(a.w + adn.w));
            dsum.x += p.x; dsum.y += p.y; dsum.z += p.z; dsum.w += p.w;
        }
        sp[lane] = p;
        int len = min(64, end - base);
        int steps = (len + 3) >> 2;
        for (int s = 0; s < steps; ++s) {
            int j = s * 4 + sub;
            int js = (j < len) ? j : 0;
            int rj = __shfl(sidx, js);
            if (j < len) {
                float pj = ((const float*)&sp[js])[head];
                H8 u = ((const H8*)(h1h + (size_t)rj * 128))[g];
                a0.x += (float)u.h[0].x * pj; a0.y += (float)u.h[0].y * pj;
                a0.z += (float)u.h[1].x * pj; a0.w += (float)u.h[1].y * pj;
                a1.x += (float)u.h[2].x * pj; a1.y += (float)u.h[2].y * pj;
                a1.z += (float)u.h[3].x * pj; a1.w += (float)u.h[3].y * pj;
            }
        }
    }
    if (sub == 0) {
        float pj = (head == 0) ? psf.x : (head == 1) ? psf.y : (head == 2) ? psf.z : psf.w;
        H8 u = ((const H8*)(h1h + (size_t)nid * 128))[g];
        a0.x += (float)u.h[0].x * pj; a0.y += (float)u.h[0].y * pj;
        a0.z += (float)u.h[1].x * pj; a0.w += (float)u.h[1].y * pj;
        a1.x += (float)u.h[2].x * pj; a1.y += (float)u.h[2].y * pj;
        a1.z += (float)u.h[3].x * pj; a1.w += (float)u.h[3].y * pj;
    }
    if (lane == 0) {
        dsum.x += psf.x; dsum.y += psf.y; dsum.z += psf.z; dsum.w += psf.w;
    }
#pragma unroll
    for (int o = 1; o < 64; o <<= 1) {
        dsum.x += __shfl_xor(dsum.x, o); dsum.y += __shfl_xor(dsum.y, o);
        dsum.z += __shfl_xor(dsum.z, o); dsum.w += __shfl_xor(dsum.w, o);
    }
#pragma unroll
    for (int o = 16; o < 64; o <<= 1) {
        a0.x += __shfl_xor(a0.x, o); a0.y += __shfl_xor(a0.y, o);
        a0.z += __shfl_xor(a0.z, o); a0.w += __shfl_xor(a0.w, o);
        a1.x += __shfl_xor(a1.x, o); a1.y += __shfl_xor(a1.y, o);
        a1.z += __shfl_xor(a1.z, o); a1.w += __shfl_xor(a1.w, o);
    }
    if (sub == 0) {
        float den = (head == 0) ? dsum.x : (head == 1) ? dsum.y : (head == 2) ? dsum.z : dsum.w;
        float inv = __builtin_amdgcn_rcpf(den);
        const float4* b4 = (const float4*)b1;
        float4 bb0 = b4[g * 2], bb1 = b4[g * 2 + 1];
        float4 r0 = make_float4(elu(a0.x * inv + bb0.x), elu(a0.y * inv + bb0.y),
                                elu(a0.z * inv + bb0.z), elu(a0.w * inv + bb0.w));
        float4 r1 = make_float4(elu(a1.x * inv + bb1.x), elu(a1.y * inv + bb1.y),
                                elu(a1.z * inv + bb1.z), elu(a1.w * inv + bb1.w));
        H8 o8;
        o8.h[0] = half2v{(_Float16)r0.x, (_Float16)r0.y};
        o8.h[1] = half2v{(_Float16)r0.z, (_Float16)r0.w};
        o8.h[2] = half2v{(_Float16)r1.x, (_Float16)r1.y};
        o8.h[3] = half2v{(_Float16)r1.z, (_Float16)r1.w};
        *(float4*)&s_row[wave][g * 8] = o8.f4;   // wave-local; program-order safe
    }
    // ---- fused layer-2 GEMV: out[c] = sum_k row[k]*W2t[c][k] ----
    int c = lane & 31, half = lane >> 5;
    float acc2 = 0.f;
#pragma unroll
    for (int k8 = 0; k8 < 8; ++k8) {
        HH rv, wvv;
        rv.v  = *(const f16x8*)&s_row[wave][half * 64 + k8 * 8];
        wvv.v = *(const f16x8*)&sW2[c * W2S + half * 64 + k8 * 8];
#if __has_builtin(__builtin_amdgcn_fdot2)
        acc2 = __builtin_amdgcn_fdot2(rv.h[0], wvv.h[0], acc2, false);
        acc2 = __builtin_amdgcn_fdot2(rv.h[1], wvv.h[1], acc2, false);
        acc2 = __builtin_amdgcn_fdot2(rv.h[2], wvv.h[2], acc2, false);
        acc2 = __builtin_amdgcn_fdot2(rv.h[3], wvv.h[3], acc2, false);
#else
#pragma unroll
        for (int e = 0; e < 8; ++e) acc2 += (float)rv.v[e] * (float)wvv.v[e];
#endif
    }
    acc2 += __shfl_xor(acc2, 32);          // combine k-halves; lanes c and c+32 same col
    float ps = acc2 * a2s, pd = acc2 * a2d;
#pragma unroll
    for (int o = 1; o < 32; o <<= 1) { ps += __shfl_xor(ps, o); pd += __shfl_xor(pd, o); }
    if (lane < 32) h2h[(size_t)nid * 32 + c] = (_Float16)acc2;
    if (lane == 0) { as2[nid] = ps; ad2[nid] = pd; }
}

// D5: layer-2 softmax + aggregate
__global__ __launch_bounds__(256) void agg2_kernel(const _Float16* __restrict__ h2h,
                                                   const float* __restrict__ as2,
                                                   const float* __restrict__ ad2,
                                                   const int* __restrict__ rp,
                                                   const int* __restrict__ col,
                                                   const float* __restrict__ b2,
                                                   float* __restrict__ out, int n) {
    int wave = threadIdx.x >> 6, lane = threadIdx.x & 63;
    int nid = blockIdx.x * 4 + wave;
    if (nid >= n) return;
    int start = rp[nid], end = rp[nid + 1];
    float adn = ad2[nid];
    float psf = __expf(leaky(as2[nid] + adn));
    float dsum = 0.f;
    int g = lane & 7, sub = lane >> 3;
    float4 acc = make_float4(0.f, 0.f, 0.f, 0.f);
    for (int base = start; base < end; base += 64) {
        int i = base + lane;
        int sidx = 0;
        float p = 0.f;
        if (i < end) {
            sidx = col[i];
            p = __expf(leaky(as2[sidx] + adn));
            dsum += p;
        }
        int len = min(64, end - base);
        int steps = (len + 7) >> 3;
        for (int s = 0; s < steps; ++s) {
            int j = s * 8 + sub;
            int js = (j < len) ? j : 0;
            int rj = __shfl(sidx, js);
            float pj = __shfl(p, js);
            if (j < len) {
                H4 u = ((const H4*)(h2h + (size_t)rj * 32))[g];
                acc.x += (float)u.h[0].x * pj; acc.y += (float)u.h[0].y * pj;
                acc.z += (float)u.h[1].x * pj; acc.w += (float)u.h[1].y * pj;
            }
        }
    }
    if (sub == 0) {
        H4 u = ((const H4*)(h2h + (size_t)nid * 32))[g];
        acc.x += (float)u.h[0].x * psf; acc.y += (float)u.h[0].y * psf;
        acc.z += (float)u.h[1].x * psf; acc.w += (float)u.h[1].y * psf;
    }
    if (lane == 0) dsum += psf;
#pragma unroll
    for (int o = 1; o < 64; o <<= 1) dsum += __shfl_xor(dsum, o);
#pragma unroll
    for (int o = 8; o < 64; o <<= 1) {
        acc.x += __shfl_xor(acc.x, o); acc.y += __shfl_xor(acc.y, o);
        acc.z += __shfl_xor(acc.z, o); acc.w += __shfl_xor(acc.w, o);
    }
    if (sub == 0) {
        float inv = __builtin_amdgcn_rcpf(dsum);
        float4 bb = ((const float4*)b2)[g];
        ((float4*)(out + (size_t)nid * 32))[g] =
            make_float4(acc.x * inv + bb.x, acc.y * inv + bb.y,
                        acc.z * inv + bb.z, acc.w * inv + bb.w);
    }
}

// ================= launch =================

extern "C" void kernel_launch(void* const* d_in, const int* in_sizes, int n_in,
                              void* d_out, int out_size, void* d_ws, size_t ws_size,
                              hipStream_t stream) {
    const float* x      = (const float*)d_in[0];
    const int*   ei     = (const int*)d_in[1];
    const float* W1     = (const float*)d_in[2];
    const float* a_src1 = (const float*)d_in[3];
    const float* a_dst1 = (const float*)d_in[4];
    const float* b1     = (const float*)d_in[5];
    const float* W2     = (const float*)d_in[6];
    const float* a_src2 = (const float*)d_in[7];
    const float* a_dst2 = (const float*)d_in[8];
    const float* b2     = (const float*)d_in[9];
    float* out = (float*)d_out;

    const int N = in_sizes[0] / 128;
    const int E = in_sizes[1] / 2;
    const int* src = ei;
    const int* dstp = ei + E;

    uint8_t* w = (uint8_t*)d_ws;
    auto carve = [&](size_t bytes) {
        uint8_t* p = w;
        w += (bytes + 255) & ~(size_t)255;
        return p;
    };
    _Float16* h1h = (_Float16*)carve((size_t)N * 128 * 2);
    _Float16* h2h = (_Float16*)carve((size_t)N * 32 * 2);
    _Float16* W1t = (_Float16*)carve((size_t)128 * 128 * 2);
    _Float16* W2t = (_Float16*)carve((size_t)32 * 128 * 2);
    float* as1 = (float*)carve((size_t)N * 4 * 4);
    float* ad1 = (float*)carve((size_t)N * 4 * 4);
    float* as2 = (float*)carve((size_t)N * 4);
    float* ad2 = (float*)carve((size_t)N * 4);
    int* rp    = (int*)carve((size_t)(N + 1) * 4);
    int* col   = (int*)carve((size_t)E * 4);
    int* hist  = (int*)carve((size_t)HB * 256 * 4);

    const int NB = ((N - 1) >> 8) + 1;       // coarse buckets
    const int KB = (N >> 8) + 1;             // csr blocks (covers rp[N] corner)
    int CH = (E + HB - 1) / HB;
    CH = (CH + 3) & ~3;                      // int4 alignment of chunk bases
    const int gemmBlocks = (N + 63) / 64;
    const int aggGroups = (N + 3) / 4;

    int2* pairs = (int2*)carve((size_t)NB * CAP * 8);   // 8 MB

    // D1: weight transposes + level-1 histogram
    prep_hist_kernel<<<HB + 80, 256, 0, stream>>>(W1, W2, W1t, W2t, dstp, hist, E, NB, CH);
    // D2: MFMA gemm1 + pair scatter
    gemm1_pair_kernel<<<gemmBlocks + HB, 256, 0, stream>>>(
        x, W1t, a_src1, a_dst1, h1h, as1, ad1, N, gemmBlocks,
        src, dstp, hist, pairs, E, NB, CH);
    // D3: per-bucket CSR build
    csr_kernel<<<KB, 256, 0, stream>>>(pairs, hist, rp, col, E, N, NB);
    // D4: layer-1 aggregate + fused layer-2 GEMV
    agg1_kernel<<<aggGroups, 256, 0, stream>>>(h1h, (const float4*)as1,
                                               (const float4*)ad1, rp, col, b1,
                                               W2t, a_src2, a_dst2, h2h, as2, ad2, N);
    // D5: layer-2 aggregate
    agg2_kernel<<<aggGroups, 256, 0, stream>>>(h2h, as2, ad2, rp, col, b2, out, N);
}

// Round 7
// 215.029 us; speedup vs baseline: 8.0625x; 1.0977x over previous
//
#include <hip/hip_runtime.h>
#include <cstdint>

#define NEG_SLOPE 0.2f
#define LDA 136
#define HB  128         // hist/pair chunks (hist is [NB][HB] bucket-major)
#define CAP 5120        // per-bucket pair capacity (mean 4096 + 16 sigma)
#define SMEM_BYTES (64 * LDA * 2)   // 17408 B

__device__ __forceinline__ float leaky(float v) { return v > 0.f ? v : NEG_SLOPE * v; }
__device__ __forceinline__ float elu(float v) { return v > 0.f ? v : __expf(v) - 1.f; }

typedef _Float16 half2v __attribute__((ext_vector_type(2)));
typedef _Float16 f16x8 __attribute__((ext_vector_type(8)));
typedef float f32x4 __attribute__((ext_vector_type(4)));
union H8 { float4 f4; half2v h[4]; f16x8 v8; };
union H4 { float2 f2; half2v h[2]; };
union HF2 { float2 f2; _Float16 h[4]; };
union HH { f16x8 v; half2v h[4]; };

// ================= phase bodies =================

__device__ __forceinline__ void prep_body(int bid, int G, int tid,
        const float* __restrict__ W1, const float* __restrict__ W2,
        _Float16* __restrict__ W1t, _Float16* __restrict__ W2t) {
    for (int i = bid * 256 + tid; i < 128 * 128; i += G * 256) {
        int c = i >> 7, k = i & 127;
        W1t[i] = (_Float16)W1[k * 128 + c];
    }
    for (int i = bid * 256 + tid; i < 32 * 128; i += G * 256) {
        int c = i >> 7, k = i & 127;
        W2t[i] = (_Float16)W2[k * 32 + c];
    }
}

// hist is bucket-major: hist[b * HB + c] = count of chunk c in bucket b.
__device__ __forceinline__ void hist_chunk(int c, int tid, int* lh,
        const int* __restrict__ dstp, int* __restrict__ hist, int E, int NB, int CH) {
    for (int t = tid; t < NB; t += 256) lh[t] = 0;
    __syncthreads();
    int e0 = c * CH, e1 = min(e0 + CH, E);
    int nv = (e1 - e0) & ~3;
    for (int i = e0 + tid * 4; i < e0 + nv; i += 1024) {
        int4 d = *(const int4*)(dstp + i);
        atomicAdd(&lh[d.x >> 8], 1);
        atomicAdd(&lh[d.y >> 8], 1);
        atomicAdd(&lh[d.z >> 8], 1);
        atomicAdd(&lh[d.w >> 8], 1);
    }
    for (int i = e0 + nv + tid; i < e1; i += 256)
        atomicAdd(&lh[dstp[i] >> 8], 1);
    __syncthreads();
    for (int t = tid; t < NB; t += 256) hist[t * HB + c] = lh[t];
}

__device__ __forceinline__ void gemm1_tile(int b, int tid, _Float16* Ah,
        const float* __restrict__ x, const _Float16* __restrict__ W1t,
        const float* __restrict__ a_src, const float* __restrict__ a_dst,
        _Float16* __restrict__ h1h, float* __restrict__ as1, float* __restrict__ ad1,
        int n) {
    int row0 = b * 64;
    const float4* x4 = (const float4*)x;
#pragma unroll
    for (int i = 0; i < 8; ++i) {
        int idx = tid + i * 256;          // float4 id: row*32 + c4
        int row = idx >> 5, c4 = idx & 31;
        float4 v = make_float4(0.f, 0.f, 0.f, 0.f);
        if (row0 + row < n) v = x4[(size_t)(row0 + row) * 32 + c4];
        HF2 u;
        u.h[0] = (_Float16)v.x; u.h[1] = (_Float16)v.y;
        u.h[2] = (_Float16)v.z; u.h[3] = (_Float16)v.w;
        *(float2*)&Ah[row * LDA + c4 * 4] = u.f2;
    }
    __syncthreads();

    int l = tid & 63, w = tid >> 6;
    int lr = l & 15, lg = l >> 4;
    f16x8 af[4];
#pragma unroll
    for (int kk = 0; kk < 4; ++kk)
        af[kk] = *(const f16x8*)&Ah[(w * 16 + lr) * LDA + kk * 32 + lg * 8];
    f32x4 acc[8];
#pragma unroll
    for (int t = 0; t < 8; ++t) acc[t] = (f32x4)0.f;
#pragma unroll
    for (int t = 0; t < 8; ++t) {
#pragma unroll
        for (int kk = 0; kk < 4; ++kk) {
            f16x8 bf = *(const f16x8*)&W1t[(size_t)(t * 16 + lr) * 128 + kk * 32 + lg * 8];
            acc[t] = __builtin_amdgcn_mfma_f32_16x16x32_f16(af[kk], bf, acc[t], 0, 0, 0);
        }
    }
    __syncthreads();
#pragma unroll
    for (int t = 0; t < 8; ++t)
#pragma unroll
        for (int r = 0; r < 4; ++r)
            Ah[(w * 16 + lg * 4 + r) * LDA + t * 16 + lr] = (_Float16)acc[t][r];
    __syncthreads();
    int row = tid >> 2, q = tid & 3;
    if (row0 + row < n) {
        const float* asv = a_src + q * 32;
        const float* adv = a_dst + q * 32;
        float ps = 0.f, pd = 0.f;
#pragma unroll
        for (int j = 0; j < 4; ++j) {
            f16x8 v = *(const f16x8*)&Ah[row * LDA + q * 32 + j * 8];
            *(f16x8*)&h1h[(size_t)(row0 + row) * 128 + q * 32 + j * 8] = v;
#pragma unroll
            for (int e = 0; e < 8; ++e) {
                float f = (float)v[e];
                ps += f * asv[j * 8 + e];
                pd += f * adv[j * 8 + e];
            }
        }
        as1[(row0 + row) * 4 + q] = ps;
        ad1[(row0 + row) * 4 + q] = pd;
    }
}

__device__ __forceinline__ void pair_chunk(int c, int tid, int* lcur,
        const int* __restrict__ src, const int* __restrict__ dstp,
        const int* __restrict__ hist, int2* __restrict__ pairs,
        int E, int NB, int CH) {
    // base of chunk c within bucket b = sum hist[b][0..c): contiguous row,
    // independent int4 loads (no serial chain).
    for (int b = tid; b < NB; b += 256) {
        const int4* row = (const int4*)(hist + b * HB);
        int s = 0;
        int c4 = c >> 2;
#pragma unroll 4
        for (int i = 0; i < c4; ++i) { int4 v = row[i]; s += v.x + v.y + v.z + v.w; }
        for (int i = c4 * 4; i < c; ++i) s += hist[b * HB + i];
        lcur[b] = s;
    }
    __syncthreads();
    int e0 = c * CH, e1 = min(e0 + CH, E);
    int nv = (e1 - e0) & ~3;
    for (int i = e0 + tid * 4; i < e0 + nv; i += 1024) {
        int4 d = *(const int4*)(dstp + i);
        int4 s = *(const int4*)(src + i);
        int b0 = d.x >> 8, b1 = d.y >> 8, b2 = d.z >> 8, b3 = d.w >> 8;
        int r0 = atomicAdd(&lcur[b0], 1);
        int r1 = atomicAdd(&lcur[b1], 1);
        int r2 = atomicAdd(&lcur[b2], 1);
        int r3 = atomicAdd(&lcur[b3], 1);
        if (r0 < CAP) pairs[(size_t)b0 * CAP + r0] = make_int2(s.x, d.x & 255);
        if (r1 < CAP) pairs[(size_t)b1 * CAP + r1] = make_int2(s.y, d.y & 255);
        if (r2 < CAP) pairs[(size_t)b2 * CAP + r2] = make_int2(s.z, d.z & 255);
        if (r3 < CAP) pairs[(size_t)b3 * CAP + r3] = make_int2(s.w, d.w & 255);
    }
    for (int i = e0 + nv + tid; i < e1; i += 256) {
        int d = dstp[i];
        int b = d >> 8;
        int r = atomicAdd(&lcur[b], 1);
        if (r < CAP) pairs[(size_t)b * CAP + r] = make_int2(src[i], d & 255);
    }
}

// ================= kernels =================

// D1: weight transposes + level-1 histogram (both read only inputs)
__global__ __launch_bounds__(256) void prep_hist_kernel(
        const float* __restrict__ W1, const float* __restrict__ W2,
        _Float16* __restrict__ W1t, _Float16* __restrict__ W2t,
        const int* __restrict__ dstp, int* __restrict__ hist, int E, int NB, int CH) {
    __shared__ int lh[256];
    int bid = (int)blockIdx.x;
    if (bid < HB) {
        hist_chunk(bid, threadIdx.x, lh, dstp, hist, E, NB, CH);
        return;
    }
    prep_body(bid - HB, (int)gridDim.x - HB, threadIdx.x, W1, W2, W1t, W2t);
}

// D2: pair scatter (scheduled FIRST: bid < HB) + MFMA gemm1 tiles
__global__ __launch_bounds__(256) void gemm1_pair_kernel(
        const float* __restrict__ x, const _Float16* __restrict__ W1t,
        const float* __restrict__ a_src, const float* __restrict__ a_dst,
        _Float16* __restrict__ h1h, float* __restrict__ as1, float* __restrict__ ad1,
        int n, int gemmBlocks,
        const int* __restrict__ src, const int* __restrict__ dstp,
        const int* __restrict__ hist, int2* __restrict__ pairs, int E, int NB, int CH) {
    __shared__ __align__(16) unsigned char smem[SMEM_BYTES];
    int bid = (int)blockIdx.x;
    if (bid < HB) {
        pair_chunk(bid, threadIdx.x, (int*)smem, src, dstp, hist,
                   pairs, E, NB, CH);
        return;
    }
    gemm1_tile(bid - HB, threadIdx.x, (_Float16*)smem, x, W1t, a_src, a_dst,
               h1h, as1, ad1, n);
}

// D3: level-2 per-bucket CSR build (rp + col)
__global__ __launch_bounds__(256) void csr_kernel(const int2* __restrict__ pairs,
                                                  const int* __restrict__ hist,
                                                  int* __restrict__ rp,
                                                  int* __restrict__ col,
                                                  int E, int N, int NB) {
    __shared__ int lsz[256], lstart[256];
    __shared__ int lnh[256], lnex[256], lncur[256];
    __shared__ int wsum[4], woff[4];
    int b = (int)blockIdx.x, tid = threadIdx.x;
    int lane = tid & 63, wv = tid >> 6;

    // bucket sizes: full contiguous row sum (vectorized, independent loads)
    {
        int s = 0;
        if (tid < NB) {
            const int4* row = (const int4*)(hist + tid * HB);
#pragma unroll 8
            for (int i = 0; i < HB / 4; ++i) { int4 v = row[i]; s += v.x + v.y + v.z + v.w; }
        }
        lsz[tid] = s;
    }
    __syncthreads();
    int v = lsz[tid];
    int x = v;
#pragma unroll
    for (int o = 1; o < 64; o <<= 1) { int u = __shfl_up(x, o); if (lane >= o) x += u; }
    if (lane == 63) wsum[wv] = x;
    __syncthreads();
    if (tid == 0) { int a = 0; for (int i = 0; i < 4; ++i) { woff[i] = a; a += wsum[i]; } }
    __syncthreads();
    lstart[tid] = x - v + woff[wv];
    __syncthreads();

    if (b >= NB) { if (tid == 0) rp[N] = E; return; }
    int myStart = lstart[b];
    int S = lsz[b]; if (S > CAP) S = CAP;
    const int2* pb = pairs + (size_t)b * CAP;

    lnh[tid] = 0;
    __syncthreads();
    for (int i = tid; i < S; i += 256) atomicAdd(&lnh[pb[i].y], 1);
    __syncthreads();
    int v2 = lnh[tid];
    int x2 = v2;
#pragma unroll
    for (int o = 1; o < 64; o <<= 1) { int u = __shfl_up(x2, o); if (lane >= o) x2 += u; }
    if (lane == 63) wsum[wv] = x2;
    __syncthreads();
    if (tid == 0) { int a = 0; for (int i = 0; i < 4; ++i) { woff[i] = a; a += wsum[i]; } }
    __syncthreads();
    int ex2 = x2 - v2 + woff[wv];
    lnex[tid] = ex2;
    lncur[tid] = 0;
    int node = (b << 8) + tid;
    if (node <= N) rp[node] = myStart + ex2;
    __syncthreads();
    for (int i = tid; i < S; i += 256) {
        int2 p = pb[i];
        int r = atomicAdd(&lncur[p.y], 1);
        col[myStart + lnex[p.y] + r] = p.x;
    }
}

// D4: layer-1 softmax+aggregate, fused layer-2 GEMV (h2h, as2, ad2)
#define W2S 136   // sW2 row stride in halves (16B-aligned for b128 reads)

__global__ __launch_bounds__(256) void agg1_kernel(const _Float16* __restrict__ h1h,
                                                   const float4* __restrict__ as1,
                                                   const float4* __restrict__ ad1,
                                                   const int* __restrict__ rp,
                                                   const int* __restrict__ col,
                                                   const float* __restrict__ b1,
                                                   const _Float16* __restrict__ W2t,
                                                   const float* __restrict__ a_src2,
                                                   const float* __restrict__ a_dst2,
                                                   _Float16* __restrict__ h2h,
                                                   float* __restrict__ as2,
                                                   float* __restrict__ ad2, int n) {
    __shared__ float4 s_p[4][64];
    __shared__ _Float16 s_row[4][128];
    __shared__ _Float16 sW2[32 * W2S];
    int tid = threadIdx.x;
    for (int e = tid; e < 32 * 16; e += 256) {
        int c = e >> 4, k8 = e & 15;
        *(f16x8*)&sW2[c * W2S + k8 * 8] = *(const f16x8*)&W2t[c * 128 + k8 * 8];
    }
    float a2s = a_src2[tid & 31], a2d = a_dst2[tid & 31];
    __syncthreads();

    int wave = tid >> 6, lane = tid & 63;
    int nid = blockIdx.x * 4 + wave;
    if (nid >= n) return;
    float4* sp = s_p[wave];
    int start = rp[nid], end = rp[nid + 1];
    float4 adn = ad1[nid], asn = as1[nid];
    float4 psf;
    psf.x = __expf(leaky(asn.x + adn.x));
    psf.y = __expf(leaky(asn.y + adn.y));
    psf.z = __expf(leaky(asn.z + adn.z));
    psf.w = __expf(leaky(asn.w + adn.w));
    float4 dsum = make_float4(0.f, 0.f, 0.f, 0.f);
    int g = lane & 15, sub = lane >> 4;
    int head = g >> 2;
    float4 a0 = make_float4(0.f, 0.f, 0.f, 0.f);
    float4 a1 = a0;

    for (int base = start; base < end; base += 64) {
        int i = base + lane;
        int sidx = 0;
        float4 p = make_float4(0.f, 0.f, 0.f, 0.f);
        if (i < end) {
            sidx = col[i];
            float4 a = as1[sidx];
            p.x = __expf(leaky(a.x + adn.x));
            p.y = __expf(leaky(a.y + adn.y));
            p.z = __expf(leaky(a.z + adn.z));
            p.w = __expf(leaky(a.w + adn.w));
            dsum.x += p.x; dsum.y += p.y; dsum.z += p.z; dsum.w += p.w;
        }
        sp[lane] = p;
        int len = min(64, end - base);
        int steps = (len + 3) >> 2;
        for (int s = 0; s < steps; ++s) {
            int j = s * 4 + sub;
            int js = (j < len) ? j : 0;
            int rj = __shfl(sidx, js);
            if (j < len) {
                float pj = ((const float*)&sp[js])[head];
                H8 u = ((const H8*)(h1h + (size_t)rj * 128))[g];
                a0.x += (float)u.h[0].x * pj; a0.y += (float)u.h[0].y * pj;
                a0.z += (float)u.h[1].x * pj; a0.w += (float)u.h[1].y * pj;
                a1.x += (float)u.h[2].x * pj; a1.y += (float)u.h[2].y * pj;
                a1.z += (float)u.h[3].x * pj; a1.w += (float)u.h[3].y * pj;
            }
        }
    }
    if (sub == 0) {
        float pj = (head == 0) ? psf.x : (head == 1) ? psf.y : (head == 2) ? psf.z : psf.w;
        H8 u = ((const H8*)(h1h + (size_t)nid * 128))[g];
        a0.x += (float)u.h[0].x * pj; a0.y += (float)u.h[0].y * pj;
        a0.z += (float)u.h[1].x * pj; a0.w += (float)u.h[1].y * pj;
        a1.x += (float)u.h[2].x * pj; a1.y += (float)u.h[2].y * pj;
        a1.z += (float)u.h[3].x * pj; a1.w += (float)u.h[3].y * pj;
    }
    if (lane == 0) {
        dsum.x += psf.x; dsum.y += psf.y; dsum.z += psf.z; dsum.w += psf.w;
    }
#pragma unroll
    for (int o = 1; o < 64; o <<= 1) {
        dsum.x += __shfl_xor(dsum.x, o); dsum.y += __shfl_xor(dsum.y, o);
        dsum.z += __shfl_xor(dsum.z, o); dsum.w += __shfl_xor(dsum.w, o);
    }
#pragma unroll
    for (int o = 16; o < 64; o <<= 1) {
        a0.x += __shfl_xor(a0.x, o); a0.y += __shfl_xor(a0.y, o);
        a0.z += __shfl_xor(a0.z, o); a0.w += __shfl_xor(a0.w, o);
        a1.x += __shfl_xor(a1.x, o); a1.y += __shfl_xor(a1.y, o);
        a1.z += __shfl_xor(a1.z, o); a1.w += __shfl_xor(a1.w, o);
    }
    if (sub == 0) {
        float den = (head == 0) ? dsum.x : (head == 1) ? dsum.y : (head == 2) ? dsum.z : dsum.w;
        float inv = __builtin_amdgcn_rcpf(den);
        const float4* b4 = (const float4*)b1;
        float4 bb0 = b4[g * 2], bb1 = b4[g * 2 + 1];
        float4 r0 = make_float4(elu(a0.x * inv + bb0.x), elu(a0.y * inv + bb0.y),
                                elu(a0.z * inv + bb0.z), elu(a0.w * inv + bb0.w));
        float4 r1 = make_float4(elu(a1.x * inv + bb1.x), elu(a1.y * inv + bb1.y),
                                elu(a1.z * inv + bb1.z), elu(a1.w * inv + bb1.w));
        H8 o8;
        o8.h[0] = half2v{(_Float16)r0.x, (_Float16)r0.y};
        o8.h[1] = half2v{(_Float16)r0.z, (_Float16)r0.w};
        o8.h[2] = half2v{(_Float16)r1.x, (_Float16)r1.y};
        o8.h[3] = half2v{(_Float16)r1.z, (_Float16)r1.w};
        *(float4*)&s_row[wave][g * 8] = o8.f4;
    }
    // ---- fused layer-2 GEMV ----
    int c = lane & 31, half = lane >> 5;
    float acc2 = 0.f;
#pragma unroll
    for (int k8 = 0; k8 < 8; ++k8) {
        HH rv, wvv;
        rv.v  = *(const f16x8*)&s_row[wave][half * 64 + k8 * 8];
        wvv.v = *(const f16x8*)&sW2[c * W2S + half * 64 + k8 * 8];
#if __has_builtin(__builtin_amdgcn_fdot2)
        acc2 = __builtin_amdgcn_fdot2(rv.h[0], wvv.h[0], acc2, false);
        acc2 = __builtin_amdgcn_fdot2(rv.h[1], wvv.h[1], acc2, false);
        acc2 = __builtin_amdgcn_fdot2(rv.h[2], wvv.h[2], acc2, false);
        acc2 = __builtin_amdgcn_fdot2(rv.h[3], wvv.h[3], acc2, false);
#else
#pragma unroll
        for (int e = 0; e < 8; ++e) acc2 += (float)rv.v[e] * (float)wvv.v[e];
#endif
    }
    acc2 += __shfl_xor(acc2, 32);
    float ps = acc2 * a2s, pd = acc2 * a2d;
#pragma unroll
    for (int o = 1; o < 32; o <<= 1) { ps += __shfl_xor(ps, o); pd += __shfl_xor(pd, o); }
    if (lane < 32) h2h[(size_t)nid * 32 + c] = (_Float16)acc2;
    if (lane == 0) { as2[nid] = ps; ad2[nid] = pd; }
}

// D5: layer-2 softmax + aggregate
__global__ __launch_bounds__(256) void agg2_kernel(const _Float16* __restrict__ h2h,
                                                   const float* __restrict__ as2,
                                                   const float* __restrict__ ad2,
                                                   const int* __restrict__ rp,
                                                   const int* __restrict__ col,
                                                   const float* __restrict__ b2,
                                                   float* __restrict__ out, int n) {
    int wave = threadIdx.x >> 6, lane = threadIdx.x & 63;
    int nid = blockIdx.x * 4 + wave;
    if (nid >= n) return;
    int start = rp[nid], end = rp[nid + 1];
    float adn = ad2[nid];
    float psf = __expf(leaky(as2[nid] + adn));
    float dsum = 0.f;
    int g = lane & 7, sub = lane >> 3;
    float4 acc = make_float4(0.f, 0.f, 0.f, 0.f);
    for (int base = start; base < end; base += 64) {
        int i = base + lane;
        int sidx = 0;
        float p = 0.f;
        if (i < end) {
            sidx = col[i];
            p = __expf(leaky(as2[sidx] + adn));
            dsum += p;
        }
        int len = min(64, end - base);
        int steps = (len + 7) >> 3;
        for (int s = 0; s < steps; ++s) {
            int j = s * 8 + sub;
            int js = (j < len) ? j : 0;
            int rj = __shfl(sidx, js);
            float pj = __shfl(p, js);
            if (j < len) {
                H4 u = ((const H4*)(h2h + (size_t)rj * 32))[g];
                acc.x += (float)u.h[0].x * pj; acc.y += (float)u.h[0].y * pj;
                acc.z += (float)u.h[1].x * pj; acc.w += (float)u.h[1].y * pj;
            }
        }
    }
    if (sub == 0) {
        H4 u = ((const H4*)(h2h + (size_t)nid * 32))[g];
        acc.x += (float)u.h[0].x * psf; acc.y += (float)u.h[0].y * psf;
        acc.z += (float)u.h[1].x * psf; acc.w += (float)u.h[1].y * psf;
    }
    if (lane == 0) dsum += psf;
#pragma unroll
    for (int o = 1; o < 64; o <<= 1) dsum += __shfl_xor(dsum, o);
#pragma unroll
    for (int o = 8; o < 64; o <<= 1) {
        acc.x += __shfl_xor(acc.x, o); acc.y += __shfl_xor(acc.y, o);
        acc.z += __shfl_xor(acc.z, o); acc.w += __shfl_xor(acc.w, o);
    }
    if (sub == 0) {
        float inv = __builtin_amdgcn_rcpf(dsum);
        float4 bb = ((const float4*)b2)[g];
        ((float4*)(out + (size_t)nid * 32))[g] =
            make_float4(acc.x * inv + bb.x, acc.y * inv + bb.y,
                        acc.z * inv + bb.z, acc.w * inv + bb.w);
    }
}

// ================= launch =================

extern "C" void kernel_launch(void* const* d_in, const int* in_sizes, int n_in,
                              void* d_out, int out_size, void* d_ws, size_t ws_size,
                              hipStream_t stream) {
    const float* x      = (const float*)d_in[0];
    const int*   ei     = (const int*)d_in[1];
    const float* W1     = (const float*)d_in[2];
    const float* a_src1 = (const float*)d_in[3];
    const float* a_dst1 = (const float*)d_in[4];
    const float* b1     = (const float*)d_in[5];
    const float* W2     = (const float*)d_in[6];
    const float* a_src2 = (const float*)d_in[7];
    const float* a_dst2 = (const float*)d_in[8];
    const float* b2     = (const float*)d_in[9];
    float* out = (float*)d_out;

    const int N = in_sizes[0] / 128;
    const int E = in_sizes[1] / 2;
    const int* src = ei;
    const int* dstp = ei + E;

    uint8_t* w = (uint8_t*)d_ws;
    auto carve = [&](size_t bytes) {
        uint8_t* p = w;
        w += (bytes + 255) & ~(size_t)255;
        return p;
    };
    _Float16* h1h = (_Float16*)carve((size_t)N * 128 * 2);
    _Float16* h2h = (_Float16*)carve((size_t)N * 32 * 2);
    _Float16* W1t = (_Float16*)carve((size_t)128 * 128 * 2);
    _Float16* W2t = (_Float16*)carve((size_t)32 * 128 * 2);
    float* as1 = (float*)carve((size_t)N * 4 * 4);
    float* ad1 = (float*)carve((size_t)N * 4 * 4);
    float* as2 = (float*)carve((size_t)N * 4);
    float* ad2 = (float*)carve((size_t)N * 4);
    int* rp    = (int*)carve((size_t)(N + 1) * 4);
    int* col   = (int*)carve((size_t)E * 4);
    int* hist  = (int*)carve((size_t)256 * HB * 4);   // [NB][HB] bucket-major

    const int NB = ((N - 1) >> 8) + 1;       // coarse buckets
    const int KB = (N >> 8) + 1;             // csr blocks
    int CH = (E + HB - 1) / HB;
    CH = (CH + 3) & ~3;                      // int4 alignment of chunk bases
    const int gemmBlocks = (N + 63) / 64;
    const int aggGroups = (N + 3) / 4;

    int2* pairs = (int2*)carve((size_t)NB * CAP * 8);   // 8 MB

    // D1: weight transposes + level-1 histogram
    prep_hist_kernel<<<HB + 80, 256, 0, stream>>>(W1, W2, W1t, W2t, dstp, hist, E, NB, CH);
    // D2: pair scatter (first in grid) + MFMA gemm1
    gemm1_pair_kernel<<<HB + gemmBlocks, 256, 0, stream>>>(
        x, W1t, a_src1, a_dst1, h1h, as1, ad1, N, gemmBlocks,
        src, dstp, hist, pairs, E, NB, CH);
    // D3: per-bucket CSR build
    csr_kernel<<<KB, 256, 0, stream>>>(pairs, hist, rp, col, E, N, NB);
    // D4: layer-1 aggregate + fused layer-2 GEMV
    agg1_kernel<<<aggGroups, 256, 0, stream>>>(h1h, (const float4*)as1,
                                               (const float4*)ad1, rp, col, b1,
                                               W2t, a_src2, a_dst2, h2h, as2, ad2, N);
    // D5: layer-2 aggregate
    agg2_kernel<<<aggGroups, 256, 0, stream>>>(h2h, as2, ad2, rp, col, b2, out, N);
}

// Round 8
// 206.847 us; speedup vs baseline: 8.3814x; 1.0396x over previous
//
#include <hip/hip_runtime.h>
#include <cstdint>

#define NEG_SLOPE 0.2f
#define LDA 136
#define HB  256         // hist/pair chunks (hist is [NB][HB] bucket-major)
#define CAP 5120        // per-bucket pair capacity (mean 4096 + 16 sigma)
#define SMEM_BYTES (64 * LDA * 2)   // 17408 B

__device__ __forceinline__ float leaky(float v) { return v > 0.f ? v : NEG_SLOPE * v; }
__device__ __forceinline__ float elu(float v) { return v > 0.f ? v : __expf(v) - 1.f; }

typedef _Float16 half2v __attribute__((ext_vector_type(2)));
typedef _Float16 f16x8 __attribute__((ext_vector_type(8)));
typedef float f32x4 __attribute__((ext_vector_type(4)));
union H8 { float4 f4; half2v h[4]; f16x8 v8; };
union H4 { float2 f2; half2v h[2]; };
union HF2 { float2 f2; _Float16 h[4]; };
union HH { f16x8 v; half2v h[4]; };

// ================= phase bodies =================

__device__ __forceinline__ void prep_body(int bid, int G, int tid,
        const float* __restrict__ W1, const float* __restrict__ W2,
        _Float16* __restrict__ W1t, _Float16* __restrict__ W2t) {
    for (int i = bid * 256 + tid; i < 128 * 128; i += G * 256) {
        int c = i >> 7, k = i & 127;
        W1t[i] = (_Float16)W1[k * 128 + c];
    }
    for (int i = bid * 256 + tid; i < 32 * 128; i += G * 256) {
        int c = i >> 7, k = i & 127;
        W2t[i] = (_Float16)W2[k * 32 + c];
    }
}

// hist is bucket-major: hist[b * HB + c] = count of chunk c in bucket b.
__device__ __forceinline__ void hist_chunk(int c, int tid, int* lh,
        const int* __restrict__ dstp, int* __restrict__ hist, int E, int NB, int CH) {
    for (int t = tid; t < NB; t += 256) lh[t] = 0;
    __syncthreads();
    int e0 = c * CH, e1 = min(e0 + CH, E);
    int nv = (e1 - e0) & ~3;
    for (int i = e0 + tid * 4; i < e0 + nv; i += 1024) {
        int4 d = *(const int4*)(dstp + i);
        atomicAdd(&lh[d.x >> 8], 1);
        atomicAdd(&lh[d.y >> 8], 1);
        atomicAdd(&lh[d.z >> 8], 1);
        atomicAdd(&lh[d.w >> 8], 1);
    }
    for (int i = e0 + nv + tid; i < e1; i += 256)
        atomicAdd(&lh[dstp[i] >> 8], 1);
    __syncthreads();
    for (int t = tid; t < NB; t += 256) hist[t * HB + c] = lh[t];
}

__device__ __forceinline__ void pair_chunk(int c, int tid, int* lcur,
        const int* __restrict__ src, const int* __restrict__ dstp,
        const int* __restrict__ hist, int2* __restrict__ pairs,
        int E, int NB, int CH) {
    // base of chunk c within bucket b = sum hist[b][0..c): contiguous row,
    // independent int4 loads (no serial chain).
    for (int b = tid; b < NB; b += 256) {
        const int4* row = (const int4*)(hist + b * HB);
        int s = 0;
        int c4 = c >> 2;
#pragma unroll 4
        for (int i = 0; i < c4; ++i) { int4 v = row[i]; s += v.x + v.y + v.z + v.w; }
        for (int i = c4 * 4; i < c; ++i) s += hist[b * HB + i];
        lcur[b] = s;
    }
    __syncthreads();
    int e0 = c * CH, e1 = min(e0 + CH, E);
    int nv = (e1 - e0) & ~3;
    for (int i = e0 + tid * 4; i < e0 + nv; i += 1024) {
        int4 d = *(const int4*)(dstp + i);
        int4 s = *(const int4*)(src + i);
        int b0 = d.x >> 8, b1 = d.y >> 8, b2 = d.z >> 8, b3 = d.w >> 8;
        int r0 = atomicAdd(&lcur[b0], 1);
        int r1 = atomicAdd(&lcur[b1], 1);
        int r2 = atomicAdd(&lcur[b2], 1);
        int r3 = atomicAdd(&lcur[b3], 1);
        if (r0 < CAP) pairs[(size_t)b0 * CAP + r0] = make_int2(s.x, d.x & 255);
        if (r1 < CAP) pairs[(size_t)b1 * CAP + r1] = make_int2(s.y, d.y & 255);
        if (r2 < CAP) pairs[(size_t)b2 * CAP + r2] = make_int2(s.z, d.z & 255);
        if (r3 < CAP) pairs[(size_t)b3 * CAP + r3] = make_int2(s.w, d.w & 255);
    }
    for (int i = e0 + nv + tid; i < e1; i += 256) {
        int d = dstp[i];
        int b = d >> 8;
        int r = atomicAdd(&lcur[b], 1);
        if (r < CAP) pairs[(size_t)b * CAP + r] = make_int2(src[i], d & 255);
    }
}

__device__ __forceinline__ void gemm1_tile(int b, int tid, _Float16* Ah,
        const float* __restrict__ x, const _Float16* __restrict__ W1t,
        const float* __restrict__ a_src, const float* __restrict__ a_dst,
        _Float16* __restrict__ h1h, float* __restrict__ as1, float* __restrict__ ad1,
        int n) {
    int row0 = b * 64;
    const float4* x4 = (const float4*)x;
#pragma unroll
    for (int i = 0; i < 8; ++i) {
        int idx = tid + i * 256;          // float4 id: row*32 + c4
        int row = idx >> 5, c4 = idx & 31;
        float4 v = make_float4(0.f, 0.f, 0.f, 0.f);
        if (row0 + row < n) v = x4[(size_t)(row0 + row) * 32 + c4];
        HF2 u;
        u.h[0] = (_Float16)v.x; u.h[1] = (_Float16)v.y;
        u.h[2] = (_Float16)v.z; u.h[3] = (_Float16)v.w;
        *(float2*)&Ah[row * LDA + c4 * 4] = u.f2;
    }
    __syncthreads();

    int l = tid & 63, w = tid >> 6;
    int lr = l & 15, lg = l >> 4;
    f16x8 af[4];
#pragma unroll
    for (int kk = 0; kk < 4; ++kk)
        af[kk] = *(const f16x8*)&Ah[(w * 16 + lr) * LDA + kk * 32 + lg * 8];
    f32x4 acc[8];
#pragma unroll
    for (int t = 0; t < 8; ++t) acc[t] = (f32x4)0.f;
#pragma unroll
    for (int t = 0; t < 8; ++t) {
#pragma unroll
        for (int kk = 0; kk < 4; ++kk) {
            f16x8 bf = *(const f16x8*)&W1t[(size_t)(t * 16 + lr) * 128 + kk * 32 + lg * 8];
            acc[t] = __builtin_amdgcn_mfma_f32_16x16x32_f16(af[kk], bf, acc[t], 0, 0, 0);
        }
    }
    __syncthreads();
#pragma unroll
    for (int t = 0; t < 8; ++t)
#pragma unroll
        for (int r = 0; r < 4; ++r)
            Ah[(w * 16 + lg * 4 + r) * LDA + t * 16 + lr] = (_Float16)acc[t][r];
    __syncthreads();
    int row = tid >> 2, q = tid & 3;
    if (row0 + row < n) {
        const float* asv = a_src + q * 32;
        const float* adv = a_dst + q * 32;
        float ps = 0.f, pd = 0.f;
#pragma unroll
        for (int j = 0; j < 4; ++j) {
            f16x8 v = *(const f16x8*)&Ah[row * LDA + q * 32 + j * 8];
            *(f16x8*)&h1h[(size_t)(row0 + row) * 128 + q * 32 + j * 8] = v;
#pragma unroll
            for (int e = 0; e < 8; ++e) {
                float f = (float)v[e];
                ps += f * asv[j * 8 + e];
                pd += f * adv[j * 8 + e];
            }
        }
        as1[(row0 + row) * 4 + q] = ps;
        ad1[(row0 + row) * 4 + q] = pd;
    }
}

__device__ __forceinline__ void csr_bucket(int b, int tid, unsigned char* smem,
        const int2* __restrict__ pairs, const int* __restrict__ hist,
        int* __restrict__ rp, int* __restrict__ col, int E, int N, int NB) {
    int* lsz    = (int*)smem;
    int* lstart = lsz + 256;
    int* lnh    = lstart + 256;
    int* lnex   = lnh + 256;
    int* lncur  = lnex + 256;
    int* wsum   = lncur + 256;
    int* woff   = wsum + 4;
    int lane = tid & 63, wv = tid >> 6;

    // bucket sizes: full contiguous row sum (vectorized, independent loads)
    {
        int s = 0;
        if (tid < NB) {
            const int4* row = (const int4*)(hist + tid * HB);
#pragma unroll 8
            for (int i = 0; i < HB / 4; ++i) { int4 v = row[i]; s += v.x + v.y + v.z + v.w; }
        }
        lsz[tid] = s;
    }
    __syncthreads();
    int v = lsz[tid];
    int x = v;
#pragma unroll
    for (int o = 1; o < 64; o <<= 1) { int u = __shfl_up(x, o); if (lane >= o) x += u; }
    if (lane == 63) wsum[wv] = x;
    __syncthreads();
    if (tid == 0) { int a = 0; for (int i = 0; i < 4; ++i) { woff[i] = a; a += wsum[i]; } }
    __syncthreads();
    lstart[tid] = x - v + woff[wv];
    __syncthreads();

    if (b >= NB) { if (tid == 0) rp[N] = E; return; }
    int myStart = lstart[b];
    int S = lsz[b]; if (S > CAP) S = CAP;
    const int2* pb = pairs + (size_t)b * CAP;

    lnh[tid] = 0;
    __syncthreads();
    for (int i = tid; i < S; i += 256) atomicAdd(&lnh[pb[i].y], 1);
    __syncthreads();
    int v2 = lnh[tid];
    int x2 = v2;
#pragma unroll
    for (int o = 1; o < 64; o <<= 1) { int u = __shfl_up(x2, o); if (lane >= o) x2 += u; }
    if (lane == 63) wsum[wv] = x2;
    __syncthreads();
    if (tid == 0) { int a = 0; for (int i = 0; i < 4; ++i) { woff[i] = a; a += wsum[i]; } }
    __syncthreads();
    int ex2 = x2 - v2 + woff[wv];
    lnex[tid] = ex2;
    lncur[tid] = 0;
    int node = (b << 8) + tid;
    if (node <= N) rp[node] = myStart + ex2;
    __syncthreads();
    for (int i = tid; i < S; i += 256) {
        int2 p = pb[i];
        int r = atomicAdd(&lncur[p.y], 1);
        col[myStart + lnex[p.y] + r] = p.x;
    }
}

// ================= kernels =================

// D1: weight transposes + level-1 histogram (both read only inputs)
__global__ __launch_bounds__(256) void prep_hist_kernel(
        const float* __restrict__ W1, const float* __restrict__ W2,
        _Float16* __restrict__ W1t, _Float16* __restrict__ W2t,
        const int* __restrict__ dstp, int* __restrict__ hist, int E, int NB, int CH) {
    __shared__ int lh[256];
    int bid = (int)blockIdx.x;
    if (bid < HB) {
        hist_chunk(bid, threadIdx.x, lh, dstp, hist, E, NB, CH);
        return;
    }
    prep_body(bid - HB, (int)gridDim.x - HB, threadIdx.x, W1, W2, W1t, W2t);
}

// D2: level-1 pair scatter (256 blocks, fills machine)
__global__ __launch_bounds__(256) void pair_kernel(const int* __restrict__ src,
                                                   const int* __restrict__ dstp,
                                                   const int* __restrict__ hist,
                                                   int2* __restrict__ pairs,
                                                   int E, int NB, int CH) {
    __shared__ int lcur[256];
    pair_chunk(blockIdx.x, threadIdx.x, lcur, src, dstp, hist, pairs, E, NB, CH);
}

// D3: csr buckets (first KB blocks) + MFMA gemm1 tiles (independent; gemm
// fills the machine while csr's ~200 blocks run -> csr hidden)
__global__ __launch_bounds__(256) void csr_gemm_kernel(
        const int2* __restrict__ pairs, const int* __restrict__ hist,
        int* __restrict__ rp, int* __restrict__ col, int E, int N, int NB, int KB,
        const float* __restrict__ x, const _Float16* __restrict__ W1t,
        const float* __restrict__ a_src, const float* __restrict__ a_dst,
        _Float16* __restrict__ h1h, float* __restrict__ as1, float* __restrict__ ad1) {
    __shared__ __align__(16) unsigned char smem[SMEM_BYTES];
    int bid = (int)blockIdx.x;
    if (bid < KB) {
        csr_bucket(bid, threadIdx.x, smem, pairs, hist, rp, col, E, N, NB);
        return;
    }
    gemm1_tile(bid - KB, threadIdx.x, (_Float16*)smem, x, W1t, a_src, a_dst,
               h1h, as1, ad1, N);
}

// D4: layer-1 softmax+aggregate, fused layer-2 GEMV.
// Denominator is accumulated DURING the gather (lane (g,sub) sums pj over its
// edge subset; the existing o=16,32 sub-reduce completes it) -- no 64-lane
// butterfly needed.
#define W2S 136   // sW2 row stride in halves (16B-aligned for b128 reads)

__global__ __launch_bounds__(256) void agg1_kernel(const _Float16* __restrict__ h1h,
                                                   const float4* __restrict__ as1,
                                                   const float4* __restrict__ ad1,
                                                   const int* __restrict__ rp,
                                                   const int* __restrict__ col,
                                                   const float* __restrict__ b1,
                                                   const _Float16* __restrict__ W2t,
                                                   const float* __restrict__ a_src2,
                                                   const float* __restrict__ a_dst2,
                                                   _Float16* __restrict__ h2h,
                                                   float* __restrict__ as2,
                                                   float* __restrict__ ad2, int n) {
    __shared__ float4 s_p[4][64];
    __shared__ _Float16 s_row[4][128];
    __shared__ _Float16 sW2[32 * W2S];
    int tid = threadIdx.x;
    for (int e = tid; e < 32 * 16; e += 256) {
        int c = e >> 4, k8 = e & 15;
        *(f16x8*)&sW2[c * W2S + k8 * 8] = *(const f16x8*)&W2t[c * 128 + k8 * 8];
    }
    float a2s = a_src2[tid & 31], a2d = a_dst2[tid & 31];
    __syncthreads();

    int wave = tid >> 6, lane = tid & 63;
    int nid = blockIdx.x * 4 + wave;
    if (nid >= n) return;
    float4* sp = s_p[wave];
    int start = rp[nid], end = rp[nid + 1];
    float4 adn = ad1[nid], asn = as1[nid];
    int g = lane & 15, sub = lane >> 4;
    int head = g >> 2;
    // self-loop score for THIS lane's head only (1 exp instead of 4)
    float sv = (head == 0) ? asn.x + adn.x : (head == 1) ? asn.y + adn.y
             : (head == 2) ? asn.z + adn.z : asn.w + adn.w;
    float psf_h = __expf(leaky(sv));
    float dnum = 0.f;                      // per-lane partial denominator (its head)
    float4 a0 = make_float4(0.f, 0.f, 0.f, 0.f);
    float4 a1 = a0;

    for (int base = start; base < end; base += 64) {
        int i = base + lane;
        int sidx = 0;
        float4 p = make_float4(0.f, 0.f, 0.f, 0.f);
        if (i < end) {
            sidx = col[i];
            float4 a = as1[sidx];
            p.x = __expf(leaky(a.x + adn.x));
            p.y = __expf(leaky(a.y + adn.y));
            p.z = __expf(leaky(a.z + adn.z));
            p.w = __expf(leaky(a.w + adn.w));
        }
        sp[lane] = p;
        int len = min(64, end - base);
        int steps = (len + 3) >> 2;
        for (int s = 0; s < steps; ++s) {
            int j = s * 4 + sub;
            int js = (j < len) ? j : 0;
            int rj = __shfl(sidx, js);
            if (j < len) {
                float pj = ((const float*)&sp[js])[head];
                dnum += pj;
                H8 u = ((const H8*)(h1h + (size_t)rj * 128))[g];
                a0.x += (float)u.h[0].x * pj; a0.y += (float)u.h[0].y * pj;
                a0.z += (float)u.h[1].x * pj; a0.w += (float)u.h[1].y * pj;
                a1.x += (float)u.h[2].x * pj; a1.y += (float)u.h[2].y * pj;
                a1.z += (float)u.h[3].x * pj; a1.w += (float)u.h[3].y * pj;
            }
        }
    }
    // self loop (one edge-subset adds it)
    if (sub == 0) {
        H8 u = ((const H8*)(h1h + (size_t)nid * 128))[g];
        dnum += psf_h;
        a0.x += (float)u.h[0].x * psf_h; a0.y += (float)u.h[0].y * psf_h;
        a0.z += (float)u.h[1].x * psf_h; a0.w += (float)u.h[1].y * psf_h;
        a1.x += (float)u.h[2].x * psf_h; a1.y += (float)u.h[2].y * psf_h;
        a1.z += (float)u.h[3].x * psf_h; a1.w += (float)u.h[3].y * psf_h;
    }
#pragma unroll
    for (int o = 16; o < 64; o <<= 1) {   // reduce over 4 edge subsets (same g)
        a0.x += __shfl_xor(a0.x, o); a0.y += __shfl_xor(a0.y, o);
        a0.z += __shfl_xor(a0.z, o); a0.w += __shfl_xor(a0.w, o);
        a1.x += __shfl_xor(a1.x, o); a1.y += __shfl_xor(a1.y, o);
        a1.z += __shfl_xor(a1.z, o); a1.w += __shfl_xor(a1.w, o);
        dnum += __shfl_xor(dnum, o);
    }
    if (sub == 0) {
        float inv = __builtin_amdgcn_rcpf(dnum);
        const float4* b4 = (const float4*)b1;
        float4 bb0 = b4[g * 2], bb1 = b4[g * 2 + 1];
        float4 r0 = make_float4(elu(a0.x * inv + bb0.x), elu(a0.y * inv + bb0.y),
                                elu(a0.z * inv + bb0.z), elu(a0.w * inv + bb0.w));
        float4 r1 = make_float4(elu(a1.x * inv + bb1.x), elu(a1.y * inv + bb1.y),
                                elu(a1.z * inv + bb1.z), elu(a1.w * inv + bb1.w));
        H8 o8;
        o8.h[0] = half2v{(_Float16)r0.x, (_Float16)r0.y};
        o8.h[1] = half2v{(_Float16)r0.z, (_Float16)r0.w};
        o8.h[2] = half2v{(_Float16)r1.x, (_Float16)r1.y};
        o8.h[3] = half2v{(_Float16)r1.z, (_Float16)r1.w};
        *(float4*)&s_row[wave][g * 8] = o8.f4;
    }
    // ---- fused layer-2 GEMV ----
    int c = lane & 31, half = lane >> 5;
    float acc2 = 0.f;
#pragma unroll
    for (int k8 = 0; k8 < 8; ++k8) {
        HH rv, wvv;
        rv.v  = *(const f16x8*)&s_row[wave][half * 64 + k8 * 8];
        wvv.v = *(const f16x8*)&sW2[c * W2S + half * 64 + k8 * 8];
#if __has_builtin(__builtin_amdgcn_fdot2)
        acc2 = __builtin_amdgcn_fdot2(rv.h[0], wvv.h[0], acc2, false);
        acc2 = __builtin_amdgcn_fdot2(rv.h[1], wvv.h[1], acc2, false);
        acc2 = __builtin_amdgcn_fdot2(rv.h[2], wvv.h[2], acc2, false);
        acc2 = __builtin_amdgcn_fdot2(rv.h[3], wvv.h[3], acc2, false);
#else
#pragma unroll
        for (int e = 0; e < 8; ++e) acc2 += (float)rv.v[e] * (float)wvv.v[e];
#endif
    }
    acc2 += __shfl_xor(acc2, 32);
    float ps = acc2 * a2s, pd = acc2 * a2d;
#pragma unroll
    for (int o = 1; o < 32; o <<= 1) { ps += __shfl_xor(ps, o); pd += __shfl_xor(pd, o); }
    if (lane < 32) h2h[(size_t)nid * 32 + c] = (_Float16)acc2;
    if (lane == 0) { as2[nid] = ps; ad2[nid] = pd; }
}

// D5: layer-2 softmax + aggregate (denominator folded into sub-reduce)
__global__ __launch_bounds__(256) void agg2_kernel(const _Float16* __restrict__ h2h,
                                                   const float* __restrict__ as2,
                                                   const float* __restrict__ ad2,
                                                   const int* __restrict__ rp,
                                                   const int* __restrict__ col,
                                                   const float* __restrict__ b2,
                                                   float* __restrict__ out, int n) {
    int wave = threadIdx.x >> 6, lane = threadIdx.x & 63;
    int nid = blockIdx.x * 4 + wave;
    if (nid >= n) return;
    int start = rp[nid], end = rp[nid + 1];
    float adn = ad2[nid];
    float psf = __expf(leaky(as2[nid] + adn));
    int g = lane & 7, sub = lane >> 3;
    float dnum = 0.f;
    float4 acc = make_float4(0.f, 0.f, 0.f, 0.f);
    for (int base = start; base < end; base += 64) {
        int i = base + lane;
        int sidx = 0;
        float p = 0.f;
        if (i < end) {
            sidx = col[i];
            p = __expf(leaky(as2[sidx] + adn));
        }
        int len = min(64, end - base);
        int steps = (len + 7) >> 3;
        for (int s = 0; s < steps; ++s) {
            int j = s * 8 + sub;
            int js = (j < len) ? j : 0;
            int rj = __shfl(sidx, js);
            float pj = __shfl(p, js);
            if (j < len) {
                dnum += pj;
                H4 u = ((const H4*)(h2h + (size_t)rj * 32))[g];
                acc.x += (float)u.h[0].x * pj; acc.y += (float)u.h[0].y * pj;
                acc.z += (float)u.h[1].x * pj; acc.w += (float)u.h[1].y * pj;
            }
        }
    }
    if (sub == 0) {
        H4 u = ((const H4*)(h2h + (size_t)nid * 32))[g];
        dnum += psf;
        acc.x += (float)u.h[0].x * psf; acc.y += (float)u.h[0].y * psf;
        acc.z += (float)u.h[1].x * psf; acc.w += (float)u.h[1].y * psf;
    }
#pragma unroll
    for (int o = 8; o < 64; o <<= 1) {
        acc.x += __shfl_xor(acc.x, o); acc.y += __shfl_xor(acc.y, o);
        acc.z += __shfl_xor(acc.z, o); acc.w += __shfl_xor(acc.w, o);
        dnum += __shfl_xor(dnum, o);
    }
    if (sub == 0) {
        float inv = __builtin_amdgcn_rcpf(dnum);
        float4 bb = ((const float4*)b2)[g];
        ((float4*)(out + (size_t)nid * 32))[g] =
            make_float4(acc.x * inv + bb.x, acc.y * inv + bb.y,
                        acc.z * inv + bb.z, acc.w * inv + bb.w);
    }
}

// ================= launch =================

extern "C" void kernel_launch(void* const* d_in, const int* in_sizes, int n_in,
                              void* d_out, int out_size, void* d_ws, size_t ws_size,
                              hipStream_t stream) {
    const float* x      = (const float*)d_in[0];
    const int*   ei     = (const int*)d_in[1];
    const float* W1     = (const float*)d_in[2];
    const float* a_src1 = (const float*)d_in[3];
    const float* a_dst1 = (const float*)d_in[4];
    const float* b1     = (const float*)d_in[5];
    const float* W2     = (const float*)d_in[6];
    const float* a_src2 = (const float*)d_in[7];
    const float* a_dst2 = (const float*)d_in[8];
    const float* b2     = (const float*)d_in[9];
    float* out = (float*)d_out;

    const int N = in_sizes[0] / 128;
    const int E = in_sizes[1] / 2;
    const int* src = ei;
    const int* dstp = ei + E;

    uint8_t* w = (uint8_t*)d_ws;
    auto carve = [&](size_t bytes) {
        uint8_t* p = w;
        w += (bytes + 255) & ~(size_t)255;
        return p;
    };
    _Float16* h1h = (_Float16*)carve((size_t)N * 128 * 2);
    _Float16* h2h = (_Float16*)carve((size_t)N * 32 * 2);
    _Float16* W1t = (_Float16*)carve((size_t)128 * 128 * 2);
    _Float16* W2t = (_Float16*)carve((size_t)32 * 128 * 2);
    float* as1 = (float*)carve((size_t)N * 4 * 4);
    float* ad1 = (float*)carve((size_t)N * 4 * 4);
    float* as2 = (float*)carve((size_t)N * 4);
    float* ad2 = (float*)carve((size_t)N * 4);
    int* rp    = (int*)carve((size_t)(N + 1) * 4);
    int* col   = (int*)carve((size_t)E * 4);
    int* hist  = (int*)carve((size_t)256 * HB * 4);   // [NB][HB] bucket-major

    const int NB = ((N - 1) >> 8) + 1;       // coarse buckets
    const int KB = (N >> 8) + 1;             // csr blocks (covers rp[N] corner)
    int CH = (E + HB - 1) / HB;
    CH = (CH + 3) & ~3;                      // int4 alignment of chunk bases
    const int gemmBlocks = (N + 63) / 64;
    const int aggGroups = (N + 3) / 4;

    int2* pairs = (int2*)carve((size_t)NB * CAP * 8);   // 8 MB

    // D1: weight transposes + level-1 histogram
    prep_hist_kernel<<<HB + 80, 256, 0, stream>>>(W1, W2, W1t, W2t, dstp, hist, E, NB, CH);
    // D2: level-1 pair scatter
    pair_kernel<<<HB, 256, 0, stream>>>(src, dstp, hist, pairs, E, NB, CH);
    // D3: csr buckets + MFMA gemm1 (independent; csr hides under gemm)
    csr_gemm_kernel<<<KB + gemmBlocks, 256, 0, stream>>>(
        pairs, hist, rp, col, E, N, NB, KB,
        x, W1t, a_src1, a_dst1, h1h, as1, ad1);
    // D4: layer-1 aggregate + fused layer-2 GEMV
    agg1_kernel<<<aggGroups, 256, 0, stream>>>(h1h, (const float4*)as1,
                                               (const float4*)ad1, rp, col, b1,
                                               W2t, a_src2, a_dst2, h2h, as2, ad2, N);
    // D5: layer-2 aggregate
    agg2_kernel<<<aggGroups, 256, 0, stream>>>(h2h, as2, ad2, rp, col, b2, out, N);
}

// Round 9
// 205.473 us; speedup vs baseline: 8.4374x; 1.0067x over previous
//
#include <hip/hip_runtime.h>
#include <cstdint>

#define NEG_SLOPE 0.2f
#define LDA 136
#define HB  256         // hist/pair chunks (hist is [NB][HB] bucket-major)
#define CAP 5120        // per-bucket pair capacity (mean 4096 + 16 sigma)
#define SMEM_BYTES (64 * LDA * 2)   // 17408 B

__device__ __forceinline__ float leaky(float v) { return v > 0.f ? v : NEG_SLOPE * v; }
__device__ __forceinline__ float elu(float v) { return v > 0.f ? v : __expf(v) - 1.f; }

typedef _Float16 half2v __attribute__((ext_vector_type(2)));
typedef _Float16 f16x8 __attribute__((ext_vector_type(8)));
typedef float f32x4 __attribute__((ext_vector_type(4)));
union H8 { float4 f4; half2v h[4]; f16x8 v8; };
union H4 { float2 f2; half2v h[2]; };
union HF2 { float2 f2; _Float16 h[4]; };
union HH { f16x8 v; half2v h[4]; };

// ================= phase bodies =================

__device__ __forceinline__ void prep_body(int bid, int G, int tid,
        const float* __restrict__ W1, const float* __restrict__ W2,
        _Float16* __restrict__ W1t, _Float16* __restrict__ W2t) {
    for (int i = bid * 256 + tid; i < 128 * 128; i += G * 256) {
        int c = i >> 7, k = i & 127;
        W1t[i] = (_Float16)W1[k * 128 + c];
    }
    for (int i = bid * 256 + tid; i < 32 * 128; i += G * 256) {
        int c = i >> 7, k = i & 127;
        W2t[i] = (_Float16)W2[k * 32 + c];
    }
}

// hist is bucket-major: hist[b * HB + c] = count of chunk c in bucket b.
__device__ __forceinline__ void hist_chunk(int c, int tid, int* lh,
        const int* __restrict__ dstp, int* __restrict__ hist, int E, int NB, int CH) {
    for (int t = tid; t < NB; t += 256) lh[t] = 0;
    __syncthreads();
    int e0 = c * CH, e1 = min(e0 + CH, E);
    int nv = (e1 - e0) & ~3;
    for (int i = e0 + tid * 4; i < e0 + nv; i += 1024) {
        int4 d = *(const int4*)(dstp + i);
        atomicAdd(&lh[d.x >> 8], 1);
        atomicAdd(&lh[d.y >> 8], 1);
        atomicAdd(&lh[d.z >> 8], 1);
        atomicAdd(&lh[d.w >> 8], 1);
    }
    for (int i = e0 + nv + tid; i < e1; i += 256)
        atomicAdd(&lh[dstp[i] >> 8], 1);
    __syncthreads();
    for (int t = tid; t < NB; t += 256) hist[t * HB + c] = lh[t];
}

__device__ __forceinline__ void pair_chunk(int c, int tid, int* lcur,
        const int* __restrict__ src, const int* __restrict__ dstp,
        const int* __restrict__ hist, int2* __restrict__ pairs,
        int E, int NB, int CH) {
    for (int b = tid; b < NB; b += 256) {
        const int4* row = (const int4*)(hist + b * HB);
        int s = 0;
        int c4 = c >> 2;
#pragma unroll 4
        for (int i = 0; i < c4; ++i) { int4 v = row[i]; s += v.x + v.y + v.z + v.w; }
        for (int i = c4 * 4; i < c; ++i) s += hist[b * HB + i];
        lcur[b] = s;
    }
    __syncthreads();
    int e0 = c * CH, e1 = min(e0 + CH, E);
    int nv = (e1 - e0) & ~3;
    for (int i = e0 + tid * 4; i < e0 + nv; i += 1024) {
        int4 d = *(const int4*)(dstp + i);
        int4 s = *(const int4*)(src + i);
        int b0 = d.x >> 8, b1 = d.y >> 8, b2 = d.z >> 8, b3 = d.w >> 8;
        int r0 = atomicAdd(&lcur[b0], 1);
        int r1 = atomicAdd(&lcur[b1], 1);
        int r2 = atomicAdd(&lcur[b2], 1);
        int r3 = atomicAdd(&lcur[b3], 1);
        if (r0 < CAP) pairs[(size_t)b0 * CAP + r0] = make_int2(s.x, d.x & 255);
        if (r1 < CAP) pairs[(size_t)b1 * CAP + r1] = make_int2(s.y, d.y & 255);
        if (r2 < CAP) pairs[(size_t)b2 * CAP + r2] = make_int2(s.z, d.z & 255);
        if (r3 < CAP) pairs[(size_t)b3 * CAP + r3] = make_int2(s.w, d.w & 255);
    }
    for (int i = e0 + nv + tid; i < e1; i += 256) {
        int d = dstp[i];
        int b = d >> 8;
        int r = atomicAdd(&lcur[b], 1);
        if (r < CAP) pairs[(size_t)b * CAP + r] = make_int2(src[i], d & 255);
    }
}

__device__ __forceinline__ void gemm1_tile(int b, int tid, _Float16* Ah,
        const float* __restrict__ x, const _Float16* __restrict__ W1t,
        const float* __restrict__ a_src, const float* __restrict__ a_dst,
        _Float16* __restrict__ h1h, float* __restrict__ as1, float* __restrict__ ad1,
        int n) {
    int row0 = b * 64;
    const float4* x4 = (const float4*)x;
#pragma unroll
    for (int i = 0; i < 8; ++i) {
        int idx = tid + i * 256;          // float4 id: row*32 + c4
        int row = idx >> 5, c4 = idx & 31;
        float4 v = make_float4(0.f, 0.f, 0.f, 0.f);
        if (row0 + row < n) v = x4[(size_t)(row0 + row) * 32 + c4];
        HF2 u;
        u.h[0] = (_Float16)v.x; u.h[1] = (_Float16)v.y;
        u.h[2] = (_Float16)v.z; u.h[3] = (_Float16)v.w;
        *(float2*)&Ah[row * LDA + c4 * 4] = u.f2;
    }
    __syncthreads();

    int l = tid & 63, w = tid >> 6;
    int lr = l & 15, lg = l >> 4;
    f16x8 af[4];
#pragma unroll
    for (int kk = 0; kk < 4; ++kk)
        af[kk] = *(const f16x8*)&Ah[(w * 16 + lr) * LDA + kk * 32 + lg * 8];
    f32x4 acc[8];
#pragma unroll
    for (int t = 0; t < 8; ++t) acc[t] = (f32x4)0.f;
#pragma unroll
    for (int t = 0; t < 8; ++t) {
#pragma unroll
        for (int kk = 0; kk < 4; ++kk) {
            f16x8 bf = *(const f16x8*)&W1t[(size_t)(t * 16 + lr) * 128 + kk * 32 + lg * 8];
            acc[t] = __builtin_amdgcn_mfma_f32_16x16x32_f16(af[kk], bf, acc[t], 0, 0, 0);
        }
    }
    __syncthreads();
#pragma unroll
    for (int t = 0; t < 8; ++t)
#pragma unroll
        for (int r = 0; r < 4; ++r)
            Ah[(w * 16 + lg * 4 + r) * LDA + t * 16 + lr] = (_Float16)acc[t][r];
    __syncthreads();
    int row = tid >> 2, q = tid & 3;
    if (row0 + row < n) {
        const float* asv = a_src + q * 32;
        const float* adv = a_dst + q * 32;
        float ps = 0.f, pd = 0.f;
#pragma unroll
        for (int j = 0; j < 4; ++j) {
            f16x8 v = *(const f16x8*)&Ah[row * LDA + q * 32 + j * 8];
            *(f16x8*)&h1h[(size_t)(row0 + row) * 128 + q * 32 + j * 8] = v;
#pragma unroll
            for (int e = 0; e < 8; ++e) {
                float f = (float)v[e];
                ps += f * asv[j * 8 + e];
                pd += f * adv[j * 8 + e];
            }
        }
        as1[(row0 + row) * 4 + q] = ps;
        ad1[(row0 + row) * 4 + q] = pd;
    }
}

__device__ __forceinline__ void csr_bucket(int b, int tid, unsigned char* smem,
        const int2* __restrict__ pairs, const int* __restrict__ hist,
        int* __restrict__ rp, int* __restrict__ col, int E, int N, int NB) {
    int* lsz    = (int*)smem;
    int* lstart = lsz + 256;
    int* lnh    = lstart + 256;
    int* lnex   = lnh + 256;
    int* lncur  = lnex + 256;
    int* wsum   = lncur + 256;
    int* woff   = wsum + 4;
    int lane = tid & 63, wv = tid >> 6;

    {
        int s = 0;
        if (tid < NB) {
            const int4* row = (const int4*)(hist + tid * HB);
#pragma unroll 8
            for (int i = 0; i < HB / 4; ++i) { int4 v = row[i]; s += v.x + v.y + v.z + v.w; }
        }
        lsz[tid] = s;
    }
    __syncthreads();
    int v = lsz[tid];
    int x = v;
#pragma unroll
    for (int o = 1; o < 64; o <<= 1) { int u = __shfl_up(x, o); if (lane >= o) x += u; }
    if (lane == 63) wsum[wv] = x;
    __syncthreads();
    if (tid == 0) { int a = 0; for (int i = 0; i < 4; ++i) { woff[i] = a; a += wsum[i]; } }
    __syncthreads();
    lstart[tid] = x - v + woff[wv];
    __syncthreads();

    if (b >= NB) { if (tid == 0) rp[N] = E; return; }
    int myStart = lstart[b];
    int S = lsz[b]; if (S > CAP) S = CAP;
    const int2* pb = pairs + (size_t)b * CAP;

    lnh[tid] = 0;
    __syncthreads();
    for (int i = tid; i < S; i += 256) atomicAdd(&lnh[pb[i].y], 1);
    __syncthreads();
    int v2 = lnh[tid];
    int x2 = v2;
#pragma unroll
    for (int o = 1; o < 64; o <<= 1) { int u = __shfl_up(x2, o); if (lane >= o) x2 += u; }
    if (lane == 63) wsum[wv] = x2;
    __syncthreads();
    if (tid == 0) { int a = 0; for (int i = 0; i < 4; ++i) { woff[i] = a; a += wsum[i]; } }
    __syncthreads();
    int ex2 = x2 - v2 + woff[wv];
    lnex[tid] = ex2;
    lncur[tid] = 0;
    int node = (b << 8) + tid;
    if (node <= N) rp[node] = myStart + ex2;
    __syncthreads();
    for (int i = tid; i < S; i += 256) {
        int2 p = pb[i];
        int r = atomicAdd(&lncur[p.y], 1);
        col[myStart + lnex[p.y] + r] = p.x;
    }
}

// ================= kernels =================

// D1: weight transposes + level-1 histogram
__global__ __launch_bounds__(256) void prep_hist_kernel(
        const float* __restrict__ W1, const float* __restrict__ W2,
        _Float16* __restrict__ W1t, _Float16* __restrict__ W2t,
        const int* __restrict__ dstp, int* __restrict__ hist, int E, int NB, int CH) {
    __shared__ int lh[256];
    int bid = (int)blockIdx.x;
    if (bid < HB) {
        hist_chunk(bid, threadIdx.x, lh, dstp, hist, E, NB, CH);
        return;
    }
    prep_body(bid - HB, (int)gridDim.x - HB, threadIdx.x, W1, W2, W1t, W2t);
}

// D2: level-1 pair scatter
__global__ __launch_bounds__(256) void pair_kernel(const int* __restrict__ src,
                                                   const int* __restrict__ dstp,
                                                   const int* __restrict__ hist,
                                                   int2* __restrict__ pairs,
                                                   int E, int NB, int CH) {
    __shared__ int lcur[256];
    pair_chunk(blockIdx.x, threadIdx.x, lcur, src, dstp, hist, pairs, E, NB, CH);
}

// D3: csr buckets (first KB blocks) + MFMA gemm1 tiles
__global__ __launch_bounds__(256) void csr_gemm_kernel(
        const int2* __restrict__ pairs, const int* __restrict__ hist,
        int* __restrict__ rp, int* __restrict__ col, int E, int N, int NB, int KB,
        const float* __restrict__ x, const _Float16* __restrict__ W1t,
        const float* __restrict__ a_src, const float* __restrict__ a_dst,
        _Float16* __restrict__ h1h, float* __restrict__ as1, float* __restrict__ ad1) {
    __shared__ __align__(16) unsigned char smem[SMEM_BYTES];
    int bid = (int)blockIdx.x;
    if (bid < KB) {
        csr_bucket(bid, threadIdx.x, smem, pairs, hist, rp, col, E, N, NB);
        return;
    }
    gemm1_tile(bid - KB, threadIdx.x, (_Float16*)smem, x, W1t, a_src, a_dst,
               h1h, as1, ad1, N);
}

// D4: layer-1 softmax+aggregate, fused layer-2 GEMV.
// Gather loop is BRANCHLESS (pj=0 for pad edges; loads always execute with a
// clamped valid address) and unrolled x4 so 4 independent 16B gathers stay in
// flight per wave (was 1 -- the latency serialization seen in round 8).
#define W2S 136   // sW2 row stride in halves (16B-aligned for b128 reads)

__global__ __launch_bounds__(256) void agg1_kernel(const _Float16* __restrict__ h1h,
                                                   const float4* __restrict__ as1,
                                                   const float4* __restrict__ ad1,
                                                   const int* __restrict__ rp,
                                                   const int* __restrict__ col,
                                                   const float* __restrict__ b1,
                                                   const _Float16* __restrict__ W2t,
                                                   const float* __restrict__ a_src2,
                                                   const float* __restrict__ a_dst2,
                                                   _Float16* __restrict__ h2h,
                                                   float* __restrict__ as2,
                                                   float* __restrict__ ad2, int n) {
    __shared__ float4 s_p[4][64];
    __shared__ _Float16 s_row[4][128];
    __shared__ _Float16 sW2[32 * W2S];
    int tid = threadIdx.x;
    for (int e = tid; e < 32 * 16; e += 256) {
        int c = e >> 4, k8 = e & 15;
        *(f16x8*)&sW2[c * W2S + k8 * 8] = *(const f16x8*)&W2t[c * 128 + k8 * 8];
    }
    float a2s = a_src2[tid & 31], a2d = a_dst2[tid & 31];
    __syncthreads();

    int wave = tid >> 6, lane = tid & 63;
    int nid = blockIdx.x * 4 + wave;
    if (nid >= n) return;
    float4* sp = s_p[wave];
    int start = rp[nid], end = rp[nid + 1];
    float4 adn = ad1[nid], asn = as1[nid];
    int g = lane & 15, sub = lane >> 4;
    int head = g >> 2;
    float sv = (head == 0) ? asn.x + adn.x : (head == 1) ? asn.y + adn.y
             : (head == 2) ? asn.z + adn.z : asn.w + adn.w;
    float psf_h = __expf(leaky(sv));
    float dnum = 0.f;
    float4 a0 = make_float4(0.f, 0.f, 0.f, 0.f);
    float4 a1 = a0;

    for (int base = start; base < end; base += 64) {
        int i = base + lane;
        int sidx = 0;
        float4 p = make_float4(0.f, 0.f, 0.f, 0.f);
        if (i < end) {
            sidx = col[i];
            float4 a = as1[sidx];
            p.x = __expf(leaky(a.x + adn.x));
            p.y = __expf(leaky(a.y + adn.y));
            p.z = __expf(leaky(a.z + adn.z));
            p.w = __expf(leaky(a.w + adn.w));
        }
        sp[lane] = p;
        int len = min(64, end - base);
        int steps = (len + 3) >> 2;
#pragma unroll 4
        for (int s = 0; s < steps; ++s) {
            int j = s * 4 + sub;
            bool valid = j < len;
            int js = valid ? j : 0;
            int rj = __shfl(sidx, js);                      // always valid address
            float pj = ((const float*)&sp[js])[head];
            pj = valid ? pj : 0.f;                          // pad edges contribute 0
            H8 u = ((const H8*)(h1h + (size_t)rj * 128))[g];
            dnum += pj;
            a0.x += (float)u.h[0].x * pj; a0.y += (float)u.h[0].y * pj;
            a0.z += (float)u.h[1].x * pj; a0.w += (float)u.h[1].y * pj;
            a1.x += (float)u.h[2].x * pj; a1.y += (float)u.h[2].y * pj;
            a1.z += (float)u.h[3].x * pj; a1.w += (float)u.h[3].y * pj;
        }
    }
    if (sub == 0) {
        H8 u = ((const H8*)(h1h + (size_t)nid * 128))[g];
        dnum += psf_h;
        a0.x += (float)u.h[0].x * psf_h; a0.y += (float)u.h[0].y * psf_h;
        a0.z += (float)u.h[1].x * psf_h; a0.w += (float)u.h[1].y * psf_h;
        a1.x += (float)u.h[2].x * psf_h; a1.y += (float)u.h[2].y * psf_h;
        a1.z += (float)u.h[3].x * psf_h; a1.w += (float)u.h[3].y * psf_h;
    }
#pragma unroll
    for (int o = 16; o < 64; o <<= 1) {
        a0.x += __shfl_xor(a0.x, o); a0.y += __shfl_xor(a0.y, o);
        a0.z += __shfl_xor(a0.z, o); a0.w += __shfl_xor(a0.w, o);
        a1.x += __shfl_xor(a1.x, o); a1.y += __shfl_xor(a1.y, o);
        a1.z += __shfl_xor(a1.z, o); a1.w += __shfl_xor(a1.w, o);
        dnum += __shfl_xor(dnum, o);
    }
    if (sub == 0) {
        float inv = __builtin_amdgcn_rcpf(dnum);
        const float4* b4 = (const float4*)b1;
        float4 bb0 = b4[g * 2], bb1 = b4[g * 2 + 1];
        float4 r0 = make_float4(elu(a0.x * inv + bb0.x), elu(a0.y * inv + bb0.y),
                                elu(a0.z * inv + bb0.z), elu(a0.w * inv + bb0.w));
        float4 r1 = make_float4(elu(a1.x * inv + bb1.x), elu(a1.y * inv + bb1.y),
                                elu(a1.z * inv + bb1.z), elu(a1.w * inv + bb1.w));
        H8 o8;
        o8.h[0] = half2v{(_Float16)r0.x, (_Float16)r0.y};
        o8.h[1] = half2v{(_Float16)r0.z, (_Float16)r0.w};
        o8.h[2] = half2v{(_Float16)r1.x, (_Float16)r1.y};
        o8.h[3] = half2v{(_Float16)r1.z, (_Float16)r1.w};
        *(float4*)&s_row[wave][g * 8] = o8.f4;
    }
    // ---- fused layer-2 GEMV ----
    int c = lane & 31, half = lane >> 5;
    float acc2 = 0.f;
#pragma unroll
    for (int k8 = 0; k8 < 8; ++k8) {
        HH rv, wvv;
        rv.v  = *(const f16x8*)&s_row[wave][half * 64 + k8 * 8];
        wvv.v = *(const f16x8*)&sW2[c * W2S + half * 64 + k8 * 8];
#if __has_builtin(__builtin_amdgcn_fdot2)
        acc2 = __builtin_amdgcn_fdot2(rv.h[0], wvv.h[0], acc2, false);
        acc2 = __builtin_amdgcn_fdot2(rv.h[1], wvv.h[1], acc2, false);
        acc2 = __builtin_amdgcn_fdot2(rv.h[2], wvv.h[2], acc2, false);
        acc2 = __builtin_amdgcn_fdot2(rv.h[3], wvv.h[3], acc2, false);
#else
#pragma unroll
        for (int e = 0; e < 8; ++e) acc2 += (float)rv.v[e] * (float)wvv.v[e];
#endif
    }
    acc2 += __shfl_xor(acc2, 32);
    float ps = acc2 * a2s, pd = acc2 * a2d;
#pragma unroll
    for (int o = 1; o < 32; o <<= 1) { ps += __shfl_xor(ps, o); pd += __shfl_xor(pd, o); }
    if (lane < 32) h2h[(size_t)nid * 32 + c] = (_Float16)acc2;
    if (lane == 0) { as2[nid] = ps; ad2[nid] = pd; }
}

// D5: layer-2 softmax + aggregate (branchless gather, unrolled x4)
__global__ __launch_bounds__(256) void agg2_kernel(const _Float16* __restrict__ h2h,
                                                   const float* __restrict__ as2,
                                                   const float* __restrict__ ad2,
                                                   const int* __restrict__ rp,
                                                   const int* __restrict__ col,
                                                   const float* __restrict__ b2,
                                                   float* __restrict__ out, int n) {
    int wave = threadIdx.x >> 6, lane = threadIdx.x & 63;
    int nid = blockIdx.x * 4 + wave;
    if (nid >= n) return;
    int start = rp[nid], end = rp[nid + 1];
    float adn = ad2[nid];
    float psf = __expf(leaky(as2[nid] + adn));
    int g = lane & 7, sub = lane >> 3;
    float dnum = 0.f;
    float4 acc = make_float4(0.f, 0.f, 0.f, 0.f);
    for (int base = start; base < end; base += 64) {
        int i = base + lane;
        int sidx = 0;
        float p = 0.f;
        if (i < end) {
            sidx = col[i];
            p = __expf(leaky(as2[sidx] + adn));
        }
        int len = min(64, end - base);
        int steps = (len + 7) >> 3;
#pragma unroll 4
        for (int s = 0; s < steps; ++s) {
            int j = s * 8 + sub;
            bool valid = j < len;
            int js = valid ? j : 0;
            int rj = __shfl(sidx, js);
            float pj = __shfl(p, js);
            pj = valid ? pj : 0.f;
            H4 u = ((const H4*)(h2h + (size_t)rj * 32))[g];
            dnum += pj;
            acc.x += (float)u.h[0].x * pj; acc.y += (float)u.h[0].y * pj;
            acc.z += (float)u.h[1].x * pj; acc.w += (float)u.h[1].y * pj;
        }
    }
    if (sub == 0) {
        H4 u = ((const H4*)(h2h + (size_t)nid * 32))[g];
        dnum += psf;
        acc.x += (float)u.h[0].x * psf; acc.y += (float)u.h[0].y * psf;
        acc.z += (float)u.h[1].x * psf; acc.w += (float)u.h[1].y * psf;
    }
#pragma unroll
    for (int o = 8; o < 64; o <<= 1) {
        acc.x += __shfl_xor(acc.x, o); acc.y += __shfl_xor(acc.y, o);
        acc.z += __shfl_xor(acc.z, o); acc.w += __shfl_xor(acc.w, o);
        dnum += __shfl_xor(dnum, o);
    }
    if (sub == 0) {
        float inv = __builtin_amdgcn_rcpf(dnum);
        float4 bb = ((const float4*)b2)[g];
        ((float4*)(out + (size_t)nid * 32))[g] =
            make_float4(acc.x * inv + bb.x, acc.y * inv + bb.y,
                        acc.z * inv + bb.z, acc.w * inv + bb.w);
    }
}

// ================= launch =================

extern "C" void kernel_launch(void* const* d_in, const int* in_sizes, int n_in,
                              void* d_out, int out_size, void* d_ws, size_t ws_size,
                              hipStream_t stream) {
    const float* x      = (const float*)d_in[0];
    const int*   ei     = (const int*)d_in[1];
    const float* W1     = (const float*)d_in[2];
    const float* a_src1 = (const float*)d_in[3];
    const float* a_dst1 = (const float*)d_in[4];
    const float* b1     = (const float*)d_in[5];
    const float* W2     = (const float*)d_in[6];
    const float* a_src2 = (const float*)d_in[7];
    const float* a_dst2 = (const float*)d_in[8];
    const float* b2     = (const float*)d_in[9];
    float* out = (float*)d_out;

    const int N = in_sizes[0] / 128;
    const int E = in_sizes[1] / 2;
    const int* src = ei;
    const int* dstp = ei + E;

    uint8_t* w = (uint8_t*)d_ws;
    auto carve = [&](size_t bytes) {
        uint8_t* p = w;
        w += (bytes + 255) & ~(size_t)255;
        return p;
    };
    _Float16* h1h = (_Float16*)carve((size_t)N * 128 * 2);
    _Float16* h2h = (_Float16*)carve((size_t)N * 32 * 2);
    _Float16* W1t = (_Float16*)carve((size_t)128 * 128 * 2);
    _Float16* W2t = (_Float16*)carve((size_t)32 * 128 * 2);
    float* as1 = (float*)carve((size_t)N * 4 * 4);
    float* ad1 = (float*)carve((size_t)N * 4 * 4);
    float* as2 = (float*)carve((size_t)N * 4);
    float* ad2 = (float*)carve((size_t)N * 4);
    int* rp    = (int*)carve((size_t)(N + 1) * 4);
    int* col   = (int*)carve((size_t)E * 4);
    int* hist  = (int*)carve((size_t)256 * HB * 4);   // [NB][HB] bucket-major

    const int NB = ((N - 1) >> 8) + 1;       // coarse buckets
    const int KB = (N >> 8) + 1;             // csr blocks (covers rp[N] corner)
    int CH = (E + HB - 1) / HB;
    CH = (CH + 3) & ~3;                      // int4 alignment of chunk bases
    const int gemmBlocks = (N + 63) / 64;
    const int aggGroups = (N + 3) / 4;

    int2* pairs = (int2*)carve((size_t)NB * CAP * 8);   // 8 MB

    // D1: weight transposes + level-1 histogram
    prep_hist_kernel<<<HB + 80, 256, 0, stream>>>(W1, W2, W1t, W2t, dstp, hist, E, NB, CH);
    // D2: level-1 pair scatter
    pair_kernel<<<HB, 256, 0, stream>>>(src, dstp, hist, pairs, E, NB, CH);
    // D3: csr buckets + MFMA gemm1 (independent; csr hides under gemm)
    csr_gemm_kernel<<<KB + gemmBlocks, 256, 0, stream>>>(
        pairs, hist, rp, col, E, N, NB, KB,
        x, W1t, a_src1, a_dst1, h1h, as1, ad1);
    // D4: layer-1 aggregate + fused layer-2 GEMV
    agg1_kernel<<<aggGroups, 256, 0, stream>>>(h1h, (const float4*)as1,
                                               (const float4*)ad1, rp, col, b1,
                                               W2t, a_src2, a_dst2, h2h, as2, ad2, N);
    // D5: layer-2 aggregate
    agg2_kernel<<<aggGroups, 256, 0, stream>>>(h2h, as2, ad2, rp, col, b2, out, N);
}

// Round 10
// 193.065 us; speedup vs baseline: 8.9797x; 1.0643x over previous
//
#include <hip/hip_runtime.h>
#include <cstdint>

#define NEG_SLOPE 0.2f
#define LDA 136
#define HB  256         // hist/pair chunks (hist is [NB][HB] bucket-major)
#define CAP 5120        // per-bucket pair capacity (mean 4096 + 16 sigma)
#define SMEM_BYTES (64 * LDA * 2)   // 17408 B

__device__ __forceinline__ float leaky(float v) { return v > 0.f ? v : NEG_SLOPE * v; }
__device__ __forceinline__ float elu(float v) { return v > 0.f ? v : __expf(v) - 1.f; }

typedef _Float16 half2v __attribute__((ext_vector_type(2)));
typedef _Float16 f16x8 __attribute__((ext_vector_type(8)));
typedef float f32x4 __attribute__((ext_vector_type(4)));
union H8 { float4 f4; half2v h[4]; f16x8 v8; };
union H4 { float2 f2; half2v h[2]; };
union HF2 { float2 f2; _Float16 h[4]; };
union HH { f16x8 v; half2v h[4]; };

// ================= phase bodies =================

__device__ __forceinline__ void prep_body(int bid, int G, int tid,
        const float* __restrict__ W1, const float* __restrict__ W2,
        _Float16* __restrict__ W1t, _Float16* __restrict__ W2t) {
    for (int i = bid * 256 + tid; i < 128 * 128; i += G * 256) {
        int c = i >> 7, k = i & 127;
        W1t[i] = (_Float16)W1[k * 128 + c];
    }
    for (int i = bid * 256 + tid; i < 32 * 128; i += G * 256) {
        int c = i >> 7, k = i & 127;
        W2t[i] = (_Float16)W2[k * 32 + c];
    }
}

// hist is bucket-major: hist[b * HB + c] = count of chunk c in bucket b.
__device__ __forceinline__ void hist_chunk(int c, int tid, int* lh,
        const int* __restrict__ dstp, int* __restrict__ hist, int E, int NB, int CH) {
    for (int t = tid; t < NB; t += 256) lh[t] = 0;
    __syncthreads();
    int e0 = c * CH, e1 = min(e0 + CH, E);
    int nv = (e1 - e0) & ~3;
    for (int i = e0 + tid * 4; i < e0 + nv; i += 1024) {
        int4 d = *(const int4*)(dstp + i);
        atomicAdd(&lh[d.x >> 8], 1);
        atomicAdd(&lh[d.y >> 8], 1);
        atomicAdd(&lh[d.z >> 8], 1);
        atomicAdd(&lh[d.w >> 8], 1);
    }
    for (int i = e0 + nv + tid; i < e1; i += 256)
        atomicAdd(&lh[dstp[i] >> 8], 1);
    __syncthreads();
    for (int t = tid; t < NB; t += 256) hist[t * HB + c] = lh[t];
}

__device__ __forceinline__ void pair_chunk(int c, int tid, int* lcur,
        const int* __restrict__ src, const int* __restrict__ dstp,
        const int* __restrict__ hist, int2* __restrict__ pairs,
        int E, int NB, int CH) {
    for (int b = tid; b < NB; b += 256) {
        const int4* row = (const int4*)(hist + b * HB);
        int s = 0;
        int c4 = c >> 2;
#pragma unroll 4
        for (int i = 0; i < c4; ++i) { int4 v = row[i]; s += v.x + v.y + v.z + v.w; }
        for (int i = c4 * 4; i < c; ++i) s += hist[b * HB + i];
        lcur[b] = s;
    }
    __syncthreads();
    int e0 = c * CH, e1 = min(e0 + CH, E);
    int nv = (e1 - e0) & ~3;
    for (int i = e0 + tid * 4; i < e0 + nv; i += 1024) {
        int4 d = *(const int4*)(dstp + i);
        int4 s = *(const int4*)(src + i);
        int b0 = d.x >> 8, b1 = d.y >> 8, b2 = d.z >> 8, b3 = d.w >> 8;
        int r0 = atomicAdd(&lcur[b0], 1);
        int r1 = atomicAdd(&lcur[b1], 1);
        int r2 = atomicAdd(&lcur[b2], 1);
        int r3 = atomicAdd(&lcur[b3], 1);
        if (r0 < CAP) pairs[(size_t)b0 * CAP + r0] = make_int2(s.x, d.x & 255);
        if (r1 < CAP) pairs[(size_t)b1 * CAP + r1] = make_int2(s.y, d.y & 255);
        if (r2 < CAP) pairs[(size_t)b2 * CAP + r2] = make_int2(s.z, d.z & 255);
        if (r3 < CAP) pairs[(size_t)b3 * CAP + r3] = make_int2(s.w, d.w & 255);
    }
    for (int i = e0 + nv + tid; i < e1; i += 256) {
        int d = dstp[i];
        int b = d >> 8;
        int r = atomicAdd(&lcur[b], 1);
        if (r < CAP) pairs[(size_t)b * CAP + r] = make_int2(src[i], d & 255);
    }
}

__device__ __forceinline__ void gemm1_tile(int b, int tid, _Float16* Ah,
        const float* __restrict__ x, const _Float16* __restrict__ W1t,
        const float* __restrict__ a_src, const float* __restrict__ a_dst,
        _Float16* __restrict__ h1h, float* __restrict__ as1, float* __restrict__ ad1,
        int n) {
    int row0 = b * 64;
    const float4* x4 = (const float4*)x;
#pragma unroll
    for (int i = 0; i < 8; ++i) {
        int idx = tid + i * 256;          // float4 id: row*32 + c4
        int row = idx >> 5, c4 = idx & 31;
        float4 v = make_float4(0.f, 0.f, 0.f, 0.f);
        if (row0 + row < n) v = x4[(size_t)(row0 + row) * 32 + c4];
        HF2 u;
        u.h[0] = (_Float16)v.x; u.h[1] = (_Float16)v.y;
        u.h[2] = (_Float16)v.z; u.h[3] = (_Float16)v.w;
        *(float2*)&Ah[row * LDA + c4 * 4] = u.f2;
    }
    __syncthreads();

    int l = tid & 63, w = tid >> 6;
    int lr = l & 15, lg = l >> 4;
    f16x8 af[4];
#pragma unroll
    for (int kk = 0; kk < 4; ++kk)
        af[kk] = *(const f16x8*)&Ah[(w * 16 + lr) * LDA + kk * 32 + lg * 8];
    f32x4 acc[8];
#pragma unroll
    for (int t = 0; t < 8; ++t) acc[t] = (f32x4)0.f;
#pragma unroll
    for (int t = 0; t < 8; ++t) {
#pragma unroll
        for (int kk = 0; kk < 4; ++kk) {
            f16x8 bf = *(const f16x8*)&W1t[(size_t)(t * 16 + lr) * 128 + kk * 32 + lg * 8];
            acc[t] = __builtin_amdgcn_mfma_f32_16x16x32_f16(af[kk], bf, acc[t], 0, 0, 0);
        }
    }
    __syncthreads();
#pragma unroll
    for (int t = 0; t < 8; ++t)
#pragma unroll
        for (int r = 0; r < 4; ++r)
            Ah[(w * 16 + lg * 4 + r) * LDA + t * 16 + lr] = (_Float16)acc[t][r];
    __syncthreads();
    int row = tid >> 2, q = tid & 3;
    if (row0 + row < n) {
        const float* asv = a_src + q * 32;
        const float* adv = a_dst + q * 32;
        float ps = 0.f, pd = 0.f;
#pragma unroll
        for (int j = 0; j < 4; ++j) {
            f16x8 v = *(const f16x8*)&Ah[row * LDA + q * 32 + j * 8];
            *(f16x8*)&h1h[(size_t)(row0 + row) * 128 + q * 32 + j * 8] = v;
#pragma unroll
            for (int e = 0; e < 8; ++e) {
                float f = (float)v[e];
                ps += f * asv[j * 8 + e];
                pd += f * adv[j * 8 + e];
            }
        }
        as1[(row0 + row) * 4 + q] = ps;
        ad1[(row0 + row) * 4 + q] = pd;
    }
}

__device__ __forceinline__ void csr_bucket(int b, int tid, unsigned char* smem,
        const int2* __restrict__ pairs, const int* __restrict__ hist,
        int* __restrict__ rp, int* __restrict__ col, int E, int N, int NB) {
    int* lsz    = (int*)smem;
    int* lstart = lsz + 256;
    int* lnh    = lstart + 256;
    int* lnex   = lnh + 256;
    int* lncur  = lnex + 256;
    int* wsum   = lncur + 256;
    int* woff   = wsum + 4;
    int lane = tid & 63, wv = tid >> 6;

    {
        int s = 0;
        if (tid < NB) {
            const int4* row = (const int4*)(hist + tid * HB);
#pragma unroll 8
            for (int i = 0; i < HB / 4; ++i) { int4 v = row[i]; s += v.x + v.y + v.z + v.w; }
        }
        lsz[tid] = s;
    }
    __syncthreads();
    int v = lsz[tid];
    int x = v;
#pragma unroll
    for (int o = 1; o < 64; o <<= 1) { int u = __shfl_up(x, o); if (lane >= o) x += u; }
    if (lane == 63) wsum[wv] = x;
    __syncthreads();
    if (tid == 0) { int a = 0; for (int i = 0; i < 4; ++i) { woff[i] = a; a += wsum[i]; } }
    __syncthreads();
    lstart[tid] = x - v + woff[wv];
    __syncthreads();

    if (b >= NB) { if (tid == 0) rp[N] = E; return; }
    int myStart = lstart[b];
    int S = lsz[b]; if (S > CAP) S = CAP;
    const int2* pb = pairs + (size_t)b * CAP;

    lnh[tid] = 0;
    __syncthreads();
    for (int i = tid; i < S; i += 256) atomicAdd(&lnh[pb[i].y], 1);
    __syncthreads();
    int v2 = lnh[tid];
    int x2 = v2;
#pragma unroll
    for (int o = 1; o < 64; o <<= 1) { int u = __shfl_up(x2, o); if (lane >= o) x2 += u; }
    if (lane == 63) wsum[wv] = x2;
    __syncthreads();
    if (tid == 0) { int a = 0; for (int i = 0; i < 4; ++i) { woff[i] = a; a += wsum[i]; } }
    __syncthreads();
    int ex2 = x2 - v2 + woff[wv];
    lnex[tid] = ex2;
    lncur[tid] = 0;
    int node = (b << 8) + tid;
    if (node <= N) rp[node] = myStart + ex2;
    __syncthreads();
    for (int i = tid; i < S; i += 256) {
        int2 p = pb[i];
        int r = atomicAdd(&lncur[p.y], 1);
        col[myStart + lnex[p.y] + r] = p.x;
    }
}

// ================= kernels =================

// D1: weight transposes + level-1 histogram
__global__ __launch_bounds__(256) void prep_hist_kernel(
        const float* __restrict__ W1, const float* __restrict__ W2,
        _Float16* __restrict__ W1t, _Float16* __restrict__ W2t,
        const int* __restrict__ dstp, int* __restrict__ hist, int E, int NB, int CH) {
    __shared__ int lh[256];
    int bid = (int)blockIdx.x;
    if (bid < HB) {
        hist_chunk(bid, threadIdx.x, lh, dstp, hist, E, NB, CH);
        return;
    }
    prep_body(bid - HB, (int)gridDim.x - HB, threadIdx.x, W1, W2, W1t, W2t);
}

// D2: level-1 pair scatter
__global__ __launch_bounds__(256) void pair_kernel(const int* __restrict__ src,
                                                   const int* __restrict__ dstp,
                                                   const int* __restrict__ hist,
                                                   int2* __restrict__ pairs,
                                                   int E, int NB, int CH) {
    __shared__ int lcur[256];
    pair_chunk(blockIdx.x, threadIdx.x, lcur, src, dstp, hist, pairs, E, NB, CH);
}

// D3: csr buckets (first KB blocks) + MFMA gemm1 tiles
__global__ __launch_bounds__(256) void csr_gemm_kernel(
        const int2* __restrict__ pairs, const int* __restrict__ hist,
        int* __restrict__ rp, int* __restrict__ col, int E, int N, int NB, int KB,
        const float* __restrict__ x, const _Float16* __restrict__ W1t,
        const float* __restrict__ a_src, const float* __restrict__ a_dst,
        _Float16* __restrict__ h1h, float* __restrict__ as1, float* __restrict__ ad1) {
    __shared__ __align__(16) unsigned char smem[SMEM_BYTES];
    int bid = (int)blockIdx.x;
    if (bid < KB) {
        csr_bucket(bid, threadIdx.x, smem, pairs, hist, rp, col, E, N, NB);
        return;
    }
    gemm1_tile(bid - KB, threadIdx.x, (_Float16*)smem, x, W1t, a_src, a_dst,
               h1h, as1, ad1, N);
}

// D4: layer-1 softmax+aggregate + fused layer-2 GEMV.
// TWO NODES PER WAVE: half-wave (32 lanes) per node = 16 ch-groups x 2 edge
// subsets. Avg degree 16 -> p-phase lane utilization doubles, two independent
// per-node load chains interleave (2x MLP), sub-reduce is 1 round (o=16).
#define W2S 136   // sW2 row stride in halves (16B-aligned for b128 reads)

__global__ __launch_bounds__(256) void agg1_kernel(const _Float16* __restrict__ h1h,
                                                   const float4* __restrict__ as1,
                                                   const float4* __restrict__ ad1,
                                                   const int* __restrict__ rp,
                                                   const int* __restrict__ col,
                                                   const float* __restrict__ b1,
                                                   const _Float16* __restrict__ W2t,
                                                   const float* __restrict__ a_src2,
                                                   const float* __restrict__ a_dst2,
                                                   _Float16* __restrict__ h2h,
                                                   float* __restrict__ as2,
                                                   float* __restrict__ ad2, int n) {
    __shared__ float4 s_p[4][64];
    __shared__ _Float16 s_row[4][2][128];
    __shared__ _Float16 sW2[32 * W2S];
    int tid = threadIdx.x;
    for (int e = tid; e < 32 * 16; e += 256) {
        int c = e >> 4, k8 = e & 15;
        *(f16x8*)&sW2[c * W2S + k8 * 8] = *(const f16x8*)&W2t[c * 128 + k8 * 8];
    }
    float a2s = a_src2[tid & 31], a2d = a_dst2[tid & 31];
    __syncthreads();

    int wave = tid >> 6, lane = tid & 63;
    int h = lane >> 5, l5 = lane & 31;        // node half, lane-in-half
    int g = l5 & 15, sub = l5 >> 4;           // ch-group, edge subset (2)
    int head = g >> 2;
    int nid = blockIdx.x * 8 + wave * 2 + h;
    bool vn = nid < n;
    int nc = vn ? nid : 0;
    float4* sp = s_p[wave];
    int start = rp[nc];
    int end = vn ? rp[nc + 1] : start;
    float4 adn = ad1[nc], asn = as1[nc];
    float sv = (head == 0) ? asn.x + adn.x : (head == 1) ? asn.y + adn.y
             : (head == 2) ? asn.z + adn.z : asn.w + adn.w;
    float psf_h = vn ? __expf(leaky(sv)) : 0.f;
    float dnum = 0.f;
    float4 a0 = make_float4(0.f, 0.f, 0.f, 0.f);
    float4 a1 = a0;

    for (int base = start; base < end; base += 32) {
        int i = base + l5;
        int sidx = 0;
        float4 p = make_float4(0.f, 0.f, 0.f, 0.f);
        if (i < end) {
            sidx = col[i];
            float4 a = as1[sidx];
            p.x = __expf(leaky(a.x + adn.x));
            p.y = __expf(leaky(a.y + adn.y));
            p.z = __expf(leaky(a.z + adn.z));
            p.w = __expf(leaky(a.w + adn.w));
        }
        sp[lane] = p;
        int len = min(32, end - base);
        int steps = (len + 1) >> 1;
#pragma unroll 4
        for (int s = 0; s < steps; ++s) {
            int j = s * 2 + sub;
            bool valid = j < len;
            int js = valid ? j : 0;
            int sl = (h << 5) + js;
            int rj = __shfl(sidx, sl);
            float pj = ((const float*)&sp[sl])[head];
            pj = valid ? pj : 0.f;
            H8 u = ((const H8*)(h1h + (size_t)rj * 128))[g];
            dnum += pj;
            a0.x += (float)u.h[0].x * pj; a0.y += (float)u.h[0].y * pj;
            a0.z += (float)u.h[1].x * pj; a0.w += (float)u.h[1].y * pj;
            a1.x += (float)u.h[2].x * pj; a1.y += (float)u.h[2].y * pj;
            a1.z += (float)u.h[3].x * pj; a1.w += (float)u.h[3].y * pj;
        }
    }
    if (sub == 0) {
        H8 u = ((const H8*)(h1h + (size_t)nc * 128))[g];
        dnum += psf_h;
        a0.x += (float)u.h[0].x * psf_h; a0.y += (float)u.h[0].y * psf_h;
        a0.z += (float)u.h[1].x * psf_h; a0.w += (float)u.h[1].y * psf_h;
        a1.x += (float)u.h[2].x * psf_h; a1.y += (float)u.h[2].y * psf_h;
        a1.z += (float)u.h[3].x * psf_h; a1.w += (float)u.h[3].y * psf_h;
    }
    // single-round reduce over the 2 edge subsets (stays within the half)
    a0.x += __shfl_xor(a0.x, 16); a0.y += __shfl_xor(a0.y, 16);
    a0.z += __shfl_xor(a0.z, 16); a0.w += __shfl_xor(a0.w, 16);
    a1.x += __shfl_xor(a1.x, 16); a1.y += __shfl_xor(a1.y, 16);
    a1.z += __shfl_xor(a1.z, 16); a1.w += __shfl_xor(a1.w, 16);
    dnum += __shfl_xor(dnum, 16);
    if (sub == 0 && vn) {
        float inv = __builtin_amdgcn_rcpf(dnum);
        const float4* b4 = (const float4*)b1;
        float4 bb0 = b4[g * 2], bb1 = b4[g * 2 + 1];
        float4 r0 = make_float4(elu(a0.x * inv + bb0.x), elu(a0.y * inv + bb0.y),
                                elu(a0.z * inv + bb0.z), elu(a0.w * inv + bb0.w));
        float4 r1 = make_float4(elu(a1.x * inv + bb1.x), elu(a1.y * inv + bb1.y),
                                elu(a1.z * inv + bb1.z), elu(a1.w * inv + bb1.w));
        H8 o8;
        o8.h[0] = half2v{(_Float16)r0.x, (_Float16)r0.y};
        o8.h[1] = half2v{(_Float16)r0.z, (_Float16)r0.w};
        o8.h[2] = half2v{(_Float16)r1.x, (_Float16)r1.y};
        o8.h[3] = half2v{(_Float16)r1.z, (_Float16)r1.w};
        *(float4*)&s_row[wave][h][g * 8] = o8.f4;
    }
    // ---- fused layer-2 GEMV: half-wave computes its node's 32 outputs ----
    int c = l5;
    float acc2 = 0.f;
#pragma unroll
    for (int k8 = 0; k8 < 16; ++k8) {
        HH rv, wvv;
        rv.v  = *(const f16x8*)&s_row[wave][h][k8 * 8];
        wvv.v = *(const f16x8*)&sW2[c * W2S + k8 * 8];
#if __has_builtin(__builtin_amdgcn_fdot2)
        acc2 = __builtin_amdgcn_fdot2(rv.h[0], wvv.h[0], acc2, false);
        acc2 = __builtin_amdgcn_fdot2(rv.h[1], wvv.h[1], acc2, false);
        acc2 = __builtin_amdgcn_fdot2(rv.h[2], wvv.h[2], acc2, false);
        acc2 = __builtin_amdgcn_fdot2(rv.h[3], wvv.h[3], acc2, false);
#else
#pragma unroll
        for (int e = 0; e < 8; ++e) acc2 += (float)rv.v[e] * (float)wvv.v[e];
#endif
    }
    float ps = acc2 * a2s, pd = acc2 * a2d;
#pragma unroll
    for (int o = 1; o < 32; o <<= 1) { ps += __shfl_xor(ps, o); pd += __shfl_xor(pd, o); }
    if (vn) {
        h2h[(size_t)nid * 32 + c] = (_Float16)acc2;
        if (l5 == 0) { as2[nid] = ps; ad2[nid] = pd; }
    }
}

// D5: layer-2 softmax + aggregate. TWO NODES PER WAVE: 8 ch-groups x 4 subsets.
__global__ __launch_bounds__(256) void agg2_kernel(const _Float16* __restrict__ h2h,
                                                   const float* __restrict__ as2,
                                                   const float* __restrict__ ad2,
                                                   const int* __restrict__ rp,
                                                   const int* __restrict__ col,
                                                   const float* __restrict__ b2,
                                                   float* __restrict__ out, int n) {
    int wave = threadIdx.x >> 6, lane = threadIdx.x & 63;
    int h = lane >> 5, l5 = lane & 31;
    int g = l5 & 7, sub = l5 >> 3;            // ch-group (8), edge subset (4)
    int nid = blockIdx.x * 8 + wave * 2 + h;
    bool vn = nid < n;
    int nc = vn ? nid : 0;
    int start = rp[nc];
    int end = vn ? rp[nc + 1] : start;
    float adn = ad2[nc];
    float psf = vn ? __expf(leaky(as2[nc] + adn)) : 0.f;
    float dnum = 0.f;
    float4 acc = make_float4(0.f, 0.f, 0.f, 0.f);
    for (int base = start; base < end; base += 32) {
        int i = base + l5;
        int sidx = 0;
        float p = 0.f;
        if (i < end) {
            sidx = col[i];
            p = __expf(leaky(as2[sidx] + adn));
        }
        int len = min(32, end - base);
        int steps = (len + 3) >> 2;
#pragma unroll 4
        for (int s = 0; s < steps; ++s) {
            int j = s * 4 + sub;
            bool valid = j < len;
            int js = valid ? j : 0;
            int sl = (h << 5) + js;
            int rj = __shfl(sidx, sl);
            float pj = __shfl(p, sl);
            pj = valid ? pj : 0.f;
            H4 u = ((const H4*)(h2h + (size_t)rj * 32))[g];
            dnum += pj;
            acc.x += (float)u.h[0].x * pj; acc.y += (float)u.h[0].y * pj;
            acc.z += (float)u.h[1].x * pj; acc.w += (float)u.h[1].y * pj;
        }
    }
    if (sub == 0) {
        H4 u = ((const H4*)(h2h + (size_t)nc * 32))[g];
        dnum += psf;
        acc.x += (float)u.h[0].x * psf; acc.y += (float)u.h[0].y * psf;
        acc.z += (float)u.h[1].x * psf; acc.w += (float)u.h[1].y * psf;
    }
#pragma unroll
    for (int o = 8; o < 32; o <<= 1) {        // reduce over 4 subsets, within half
        acc.x += __shfl_xor(acc.x, o); acc.y += __shfl_xor(acc.y, o);
        acc.z += __shfl_xor(acc.z, o); acc.w += __shfl_xor(acc.w, o);
        dnum += __shfl_xor(dnum, o);
    }
    if (sub == 0 && vn) {
        float inv = __builtin_amdgcn_rcpf(dnum);
        float4 bb = ((const float4*)b2)[g];
        ((float4*)(out + (size_t)nid * 32))[g] =
            make_float4(acc.x * inv + bb.x, acc.y * inv + bb.y,
                        acc.z * inv + bb.z, acc.w * inv + bb.w);
    }
}

// ================= launch =================

extern "C" void kernel_launch(void* const* d_in, const int* in_sizes, int n_in,
                              void* d_out, int out_size, void* d_ws, size_t ws_size,
                              hipStream_t stream) {
    const float* x      = (const float*)d_in[0];
    const int*   ei     = (const int*)d_in[1];
    const float* W1     = (const float*)d_in[2];
    const float* a_src1 = (const float*)d_in[3];
    const float* a_dst1 = (const float*)d_in[4];
    const float* b1     = (const float*)d_in[5];
    const float* W2     = (const float*)d_in[6];
    const float* a_src2 = (const float*)d_in[7];
    const float* a_dst2 = (const float*)d_in[8];
    const float* b2     = (const float*)d_in[9];
    float* out = (float*)d_out;

    const int N = in_sizes[0] / 128;
    const int E = in_sizes[1] / 2;
    const int* src = ei;
    const int* dstp = ei + E;

    uint8_t* w = (uint8_t*)d_ws;
    auto carve = [&](size_t bytes) {
        uint8_t* p = w;
        w += (bytes + 255) & ~(size_t)255;
        return p;
    };
    _Float16* h1h = (_Float16*)carve((size_t)N * 128 * 2);
    _Float16* h2h = (_Float16*)carve((size_t)N * 32 * 2);
    _Float16* W1t = (_Float16*)carve((size_t)128 * 128 * 2);
    _Float16* W2t = (_Float16*)carve((size_t)32 * 128 * 2);
    float* as1 = (float*)carve((size_t)N * 4 * 4);
    float* ad1 = (float*)carve((size_t)N * 4 * 4);
    float* as2 = (float*)carve((size_t)N * 4);
    float* ad2 = (float*)carve((size_t)N * 4);
    int* rp    = (int*)carve((size_t)(N + 1) * 4);
    int* col   = (int*)carve((size_t)E * 4);
    int* hist  = (int*)carve((size_t)256 * HB * 4);   // [NB][HB] bucket-major

    const int NB = ((N - 1) >> 8) + 1;       // coarse buckets
    const int KB = (N >> 8) + 1;             // csr blocks (covers rp[N] corner)
    int CH = (E + HB - 1) / HB;
    CH = (CH + 3) & ~3;                      // int4 alignment of chunk bases
    const int gemmBlocks = (N + 63) / 64;
    const int aggGroups = (N + 7) / 8;       // 8 nodes per block (2 per wave)

    int2* pairs = (int2*)carve((size_t)NB * CAP * 8);   // 8 MB

    // D1: weight transposes + level-1 histogram
    prep_hist_kernel<<<HB + 80, 256, 0, stream>>>(W1, W2, W1t, W2t, dstp, hist, E, NB, CH);
    // D2: level-1 pair scatter
    pair_kernel<<<HB, 256, 0, stream>>>(src, dstp, hist, pairs, E, NB, CH);
    // D3: csr buckets + MFMA gemm1 (independent; csr hides under gemm)
    csr_gemm_kernel<<<KB + gemmBlocks, 256, 0, stream>>>(
        pairs, hist, rp, col, E, N, NB, KB,
        x, W1t, a_src1, a_dst1, h1h, as1, ad1);
    // D4: layer-1 aggregate + fused layer-2 GEMV (2 nodes/wave)
    agg1_kernel<<<aggGroups, 256, 0, stream>>>(h1h, (const float4*)as1,
                                               (const float4*)ad1, rp, col, b1,
                                               W2t, a_src2, a_dst2, h2h, as2, ad2, N);
    // D5: layer-2 aggregate (2 nodes/wave)
    agg2_kernel<<<aggGroups, 256, 0, stream>>>(h2h, as2, ad2, rp, col, b2, out, N);
}

// Round 11
// 189.648 us; speedup vs baseline: 9.1415x; 1.0180x over previous
//
#include <hip/hip_runtime.h>
#include <cstdint>

#define NEG_SLOPE 0.2f
#define LDA 136
#define PB  256         // pair chunks
#define CAP 5120        // per-bucket pair capacity (mean 4096 + 16 sigma)
#define SMEM_BYTES (64 * LDA * 2)   // 17408 B

__device__ __forceinline__ float leaky(float v) { return v > 0.f ? v : NEG_SLOPE * v; }
__device__ __forceinline__ float elu(float v) { return v > 0.f ? v : __expf(v) - 1.f; }

typedef _Float16 half2v __attribute__((ext_vector_type(2)));
typedef _Float16 f16x8 __attribute__((ext_vector_type(8)));
typedef float f32x4 __attribute__((ext_vector_type(4)));
union H8 { float4 f4; half2v h[4]; f16x8 v8; };
union H4 { float2 f2; half2v h[2]; };
union HF2 { float2 f2; _Float16 h[4]; };
union HH { f16x8 v; half2v h[4]; };

// ================= phase bodies =================

__device__ __forceinline__ void prep_body(int bid, int G, int tid,
        const float* __restrict__ W1, const float* __restrict__ W2,
        _Float16* __restrict__ W1t, _Float16* __restrict__ W2t) {
    for (int i = bid * 256 + tid; i < 128 * 128; i += G * 256) {
        int c = i >> 7, k = i & 127;
        W1t[i] = (_Float16)W1[k * 128 + c];
    }
    for (int i = bid * 256 + tid; i < 32 * 128; i += G * 256) {
        int c = i >> 7, k = i & 127;
        W2t[i] = (_Float16)W2[k * 32 + c];
    }
}

__device__ __forceinline__ void gemm1_tile(int b, int tid, _Float16* Ah,
        const float* __restrict__ x, const _Float16* __restrict__ W1t,
        const float* __restrict__ a_src, const float* __restrict__ a_dst,
        _Float16* __restrict__ h1h, float* __restrict__ as1, float* __restrict__ ad1,
        int n) {
    int row0 = b * 64;
    const float4* x4 = (const float4*)x;
#pragma unroll
    for (int i = 0; i < 8; ++i) {
        int idx = tid + i * 256;          // float4 id: row*32 + c4
        int row = idx >> 5, c4 = idx & 31;
        float4 v = make_float4(0.f, 0.f, 0.f, 0.f);
        if (row0 + row < n) v = x4[(size_t)(row0 + row) * 32 + c4];
        HF2 u;
        u.h[0] = (_Float16)v.x; u.h[1] = (_Float16)v.y;
        u.h[2] = (_Float16)v.z; u.h[3] = (_Float16)v.w;
        *(float2*)&Ah[row * LDA + c4 * 4] = u.f2;
    }
    __syncthreads();

    int l = tid & 63, w = tid >> 6;
    int lr = l & 15, lg = l >> 4;
    f16x8 af[4];
#pragma unroll
    for (int kk = 0; kk < 4; ++kk)
        af[kk] = *(const f16x8*)&Ah[(w * 16 + lr) * LDA + kk * 32 + lg * 8];
    f32x4 acc[8];
#pragma unroll
    for (int t = 0; t < 8; ++t) acc[t] = (f32x4)0.f;
#pragma unroll
    for (int t = 0; t < 8; ++t) {
#pragma unroll
        for (int kk = 0; kk < 4; ++kk) {
            f16x8 bf = *(const f16x8*)&W1t[(size_t)(t * 16 + lr) * 128 + kk * 32 + lg * 8];
            acc[t] = __builtin_amdgcn_mfma_f32_16x16x32_f16(af[kk], bf, acc[t], 0, 0, 0);
        }
    }
    __syncthreads();
#pragma unroll
    for (int t = 0; t < 8; ++t)
#pragma unroll
        for (int r = 0; r < 4; ++r)
            Ah[(w * 16 + lg * 4 + r) * LDA + t * 16 + lr] = (_Float16)acc[t][r];
    __syncthreads();
    int row = tid >> 2, q = tid & 3;
    if (row0 + row < n) {
        const float* asv = a_src + q * 32;
        const float* adv = a_dst + q * 32;
        float ps = 0.f, pd = 0.f;
#pragma unroll
        for (int j = 0; j < 4; ++j) {
            f16x8 v = *(const f16x8*)&Ah[row * LDA + q * 32 + j * 8];
            *(f16x8*)&h1h[(size_t)(row0 + row) * 128 + q * 32 + j * 8] = v;
#pragma unroll
            for (int e = 0; e < 8; ++e) {
                float f = (float)v[e];
                ps += f * asv[j * 8 + e];
                pd += f * adv[j * 8 + e];
            }
        }
        as1[(row0 + row) * 4 + q] = ps;
        ad1[(row0 + row) * 4 + q] = pd;
    }
}

// ================= kernels =================

// D1: pair scatter with cursor-reserved bases (no global hist, no prefix
// sums) + weight transposes. Each pair block: LDS-histogram its own chunk,
// reserve per-bucket space via ~196 returning global atomicAdds (50K total,
// spread over 196 addresses), scatter. Order within a bucket is
// nondeterministic; csr ranks by node so only fp sum order varies.
__global__ __launch_bounds__(256) void pairprep_kernel(
        const int* __restrict__ src, const int* __restrict__ dstp,
        int* __restrict__ bcur, int2* __restrict__ pairs,
        int E, int NB, int CH,
        const float* __restrict__ W1, const float* __restrict__ W2,
        _Float16* __restrict__ W1t, _Float16* __restrict__ W2t) {
    int bid = (int)blockIdx.x, tid = threadIdx.x;
    if (bid >= PB) {
        prep_body(bid - PB, (int)gridDim.x - PB, tid, W1, W2, W1t, W2t);
        return;
    }
    __shared__ int lh[256];
    for (int t = tid; t < NB; t += 256) lh[t] = 0;
    __syncthreads();
    int e0 = bid * CH, e1 = min(e0 + CH, E);
    int nv = (e1 - e0) & ~3;
    // pass 1: chunk histogram (LDS atomics only)
    for (int i = e0 + tid * 4; i < e0 + nv; i += 1024) {
        int4 d = *(const int4*)(dstp + i);
        atomicAdd(&lh[d.x >> 8], 1);
        atomicAdd(&lh[d.y >> 8], 1);
        atomicAdd(&lh[d.z >> 8], 1);
        atomicAdd(&lh[d.w >> 8], 1);
    }
    for (int i = e0 + nv + tid; i < e1; i += 256)
        atomicAdd(&lh[dstp[i] >> 8], 1);
    __syncthreads();
    // reserve bases: one returning atomic per non-empty bucket
    for (int t = tid; t < NB; t += 256) {
        int c = lh[t];
        lh[t] = (c > 0) ? atomicAdd(&bcur[t], c) : 0;
    }
    __syncthreads();
    // pass 2: scatter at base+rank (LDS cursor continues from base)
    for (int i = e0 + tid * 4; i < e0 + nv; i += 1024) {
        int4 d = *(const int4*)(dstp + i);
        int4 s = *(const int4*)(src + i);
        int b0 = d.x >> 8, b1 = d.y >> 8, b2 = d.z >> 8, b3 = d.w >> 8;
        int r0 = atomicAdd(&lh[b0], 1);
        int r1 = atomicAdd(&lh[b1], 1);
        int r2 = atomicAdd(&lh[b2], 1);
        int r3 = atomicAdd(&lh[b3], 1);
        if (r0 < CAP) pairs[(size_t)b0 * CAP + r0] = make_int2(s.x, d.x & 255);
        if (r1 < CAP) pairs[(size_t)b1 * CAP + r1] = make_int2(s.y, d.y & 255);
        if (r2 < CAP) pairs[(size_t)b2 * CAP + r2] = make_int2(s.z, d.z & 255);
        if (r3 < CAP) pairs[(size_t)b3 * CAP + r3] = make_int2(s.w, d.w & 255);
    }
    for (int i = e0 + nv + tid; i < e1; i += 256) {
        int d = dstp[i];
        int b = d >> 8;
        int r = atomicAdd(&lh[b], 1);
        if (r < CAP) pairs[(size_t)b * CAP + r] = make_int2(src[i], d & 255);
    }
}

// D2: csr buckets (first KB blocks; sizes read directly from bcur) +
// MFMA gemm1 tiles (gemm fills machine while csr runs)
__device__ __forceinline__ void csr_bucket(int b, int tid, unsigned char* smem,
        const int2* __restrict__ pairs, const int* __restrict__ bcur,
        int* __restrict__ rp, int* __restrict__ col, int E, int N, int NB) {
    int* lsz    = (int*)smem;
    int* lstart = lsz + 256;
    int* lnh    = lstart + 256;
    int* lnex   = lnh + 256;
    int* lncur  = lnex + 256;
    int* wsum   = lncur + 256;
    int* woff   = wsum + 4;
    int lane = tid & 63, wv = tid >> 6;

    lsz[tid] = (tid < NB) ? bcur[tid] : 0;   // true bucket sizes (sum = E)
    __syncthreads();
    int v = lsz[tid];
    int x = v;
#pragma unroll
    for (int o = 1; o < 64; o <<= 1) { int u = __shfl_up(x, o); if (lane >= o) x += u; }
    if (lane == 63) wsum[wv] = x;
    __syncthreads();
    if (tid == 0) { int a = 0; for (int i = 0; i < 4; ++i) { woff[i] = a; a += wsum[i]; } }
    __syncthreads();
    lstart[tid] = x - v + woff[wv];
    __syncthreads();

    if (b >= NB) { if (tid == 0) rp[N] = E; return; }
    int myStart = lstart[b];
    int S = lsz[b]; if (S > CAP) S = CAP;
    const int2* pb = pairs + (size_t)b * CAP;

    lnh[tid] = 0;
    __syncthreads();
    for (int i = tid; i < S; i += 256) atomicAdd(&lnh[pb[i].y], 1);
    __syncthreads();
    int v2 = lnh[tid];
    int x2 = v2;
#pragma unroll
    for (int o = 1; o < 64; o <<= 1) { int u = __shfl_up(x2, o); if (lane >= o) x2 += u; }
    if (lane == 63) wsum[wv] = x2;
    __syncthreads();
    if (tid == 0) { int a = 0; for (int i = 0; i < 4; ++i) { woff[i] = a; a += wsum[i]; } }
    __syncthreads();
    int ex2 = x2 - v2 + woff[wv];
    lnex[tid] = ex2;
    lncur[tid] = 0;
    int node = (b << 8) + tid;
    if (node <= N) rp[node] = myStart + ex2;
    __syncthreads();
    for (int i = tid; i < S; i += 256) {
        int2 p = pb[i];
        int r = atomicAdd(&lncur[p.y], 1);
        col[myStart + lnex[p.y] + r] = p.x;
    }
}

__global__ __launch_bounds__(256) void csr_gemm_kernel(
        const int2* __restrict__ pairs, const int* __restrict__ bcur,
        int* __restrict__ rp, int* __restrict__ col, int E, int N, int NB, int KB,
        const float* __restrict__ x, const _Float16* __restrict__ W1t,
        const float* __restrict__ a_src, const float* __restrict__ a_dst,
        _Float16* __restrict__ h1h, float* __restrict__ as1, float* __restrict__ ad1) {
    __shared__ __align__(16) unsigned char smem[SMEM_BYTES];
    int bid = (int)blockIdx.x;
    if (bid < KB) {
        csr_bucket(bid, threadIdx.x, smem, pairs, bcur, rp, col, E, N, NB);
        return;
    }
    gemm1_tile(bid - KB, threadIdx.x, (_Float16*)smem, x, W1t, a_src, a_dst,
               h1h, as1, ad1, N);
}

// D3: layer-1 softmax+aggregate + fused layer-2 GEMV (2 nodes/wave).
#define W2S 136   // sW2 row stride in halves (16B-aligned for b128 reads)

__global__ __launch_bounds__(256) void agg1_kernel(const _Float16* __restrict__ h1h,
                                                   const float4* __restrict__ as1,
                                                   const float4* __restrict__ ad1,
                                                   const int* __restrict__ rp,
                                                   const int* __restrict__ col,
                                                   const float* __restrict__ b1,
                                                   const _Float16* __restrict__ W2t,
                                                   const float* __restrict__ a_src2,
                                                   const float* __restrict__ a_dst2,
                                                   _Float16* __restrict__ h2h,
                                                   float* __restrict__ as2,
                                                   float* __restrict__ ad2, int n) {
    __shared__ float4 s_p[4][64];
    __shared__ _Float16 s_row[4][2][128];
    __shared__ _Float16 sW2[32 * W2S];
    int tid = threadIdx.x;
    for (int e = tid; e < 32 * 16; e += 256) {
        int c = e >> 4, k8 = e & 15;
        *(f16x8*)&sW2[c * W2S + k8 * 8] = *(const f16x8*)&W2t[c * 128 + k8 * 8];
    }
    float a2s = a_src2[tid & 31], a2d = a_dst2[tid & 31];
    __syncthreads();

    int wave = tid >> 6, lane = tid & 63;
    int h = lane >> 5, l5 = lane & 31;        // node half, lane-in-half
    int g = l5 & 15, sub = l5 >> 4;           // ch-group, edge subset (2)
    int head = g >> 2;
    int nid = blockIdx.x * 8 + wave * 2 + h;
    bool vn = nid < n;
    int nc = vn ? nid : 0;
    float4* sp = s_p[wave];
    int start = rp[nc];
    int end = vn ? rp[nc + 1] : start;
    float4 adn = ad1[nc], asn = as1[nc];
    float sv = (head == 0) ? asn.x + adn.x : (head == 1) ? asn.y + adn.y
             : (head == 2) ? asn.z + adn.z : asn.w + adn.w;
    float psf_h = vn ? __expf(leaky(sv)) : 0.f;
    float dnum = 0.f;
    float4 a0 = make_float4(0.f, 0.f, 0.f, 0.f);
    float4 a1 = a0;

    for (int base = start; base < end; base += 32) {
        int i = base + l5;
        int sidx = 0;
        float4 p = make_float4(0.f, 0.f, 0.f, 0.f);
        if (i < end) {
            sidx = col[i];
            float4 a = as1[sidx];
            p.x = __expf(leaky(a.x + adn.x));
            p.y = __expf(leaky(a.y + adn.y));
            p.z = __expf(leaky(a.z + adn.z));
            p.w = __expf(leaky(a.w + adn.w));
        }
        sp[lane] = p;
        int len = min(32, end - base);
        int steps = (len + 1) >> 1;
#pragma unroll 4
        for (int s = 0; s < steps; ++s) {
            int j = s * 2 + sub;
            bool valid = j < len;
            int js = valid ? j : 0;
            int sl = (h << 5) + js;
            int rj = __shfl(sidx, sl);
            float pj = ((const float*)&sp[sl])[head];
            pj = valid ? pj : 0.f;
            H8 u = ((const H8*)(h1h + (size_t)rj * 128))[g];
            dnum += pj;
            a0.x += (float)u.h[0].x * pj; a0.y += (float)u.h[0].y * pj;
            a0.z += (float)u.h[1].x * pj; a0.w += (float)u.h[1].y * pj;
            a1.x += (float)u.h[2].x * pj; a1.y += (float)u.h[2].y * pj;
            a1.z += (float)u.h[3].x * pj; a1.w += (float)u.h[3].y * pj;
        }
    }
    if (sub == 0) {
        H8 u = ((const H8*)(h1h + (size_t)nc * 128))[g];
        dnum += psf_h;
        a0.x += (float)u.h[0].x * psf_h; a0.y += (float)u.h[0].y * psf_h;
        a0.z += (float)u.h[1].x * psf_h; a0.w += (float)u.h[1].y * psf_h;
        a1.x += (float)u.h[2].x * psf_h; a1.y += (float)u.h[2].y * psf_h;
        a1.z += (float)u.h[3].x * psf_h; a1.w += (float)u.h[3].y * psf_h;
    }
    // single-round reduce over the 2 edge subsets (stays within the half)
    a0.x += __shfl_xor(a0.x, 16); a0.y += __shfl_xor(a0.y, 16);
    a0.z += __shfl_xor(a0.z, 16); a0.w += __shfl_xor(a0.w, 16);
    a1.x += __shfl_xor(a1.x, 16); a1.y += __shfl_xor(a1.y, 16);
    a1.z += __shfl_xor(a1.z, 16); a1.w += __shfl_xor(a1.w, 16);
    dnum += __shfl_xor(dnum, 16);
    if (sub == 0 && vn) {
        float inv = __builtin_amdgcn_rcpf(dnum);
        const float4* b4 = (const float4*)b1;
        float4 bb0 = b4[g * 2], bb1 = b4[g * 2 + 1];
        float4 r0 = make_float4(elu(a0.x * inv + bb0.x), elu(a0.y * inv + bb0.y),
                                elu(a0.z * inv + bb0.z), elu(a0.w * inv + bb0.w));
        float4 r1 = make_float4(elu(a1.x * inv + bb1.x), elu(a1.y * inv + bb1.y),
                                elu(a1.z * inv + bb1.z), elu(a1.w * inv + bb1.w));
        H8 o8;
        o8.h[0] = half2v{(_Float16)r0.x, (_Float16)r0.y};
        o8.h[1] = half2v{(_Float16)r0.z, (_Float16)r0.w};
        o8.h[2] = half2v{(_Float16)r1.x, (_Float16)r1.y};
        o8.h[3] = half2v{(_Float16)r1.z, (_Float16)r1.w};
        *(float4*)&s_row[wave][h][g * 8] = o8.f4;
    }
    // ---- fused layer-2 GEMV: half-wave computes its node's 32 outputs ----
    int c = l5;
    float acc2 = 0.f;
#pragma unroll
    for (int k8 = 0; k8 < 16; ++k8) {
        HH rv, wvv;
        rv.v  = *(const f16x8*)&s_row[wave][h][k8 * 8];
        wvv.v = *(const f16x8*)&sW2[c * W2S + k8 * 8];
#if __has_builtin(__builtin_amdgcn_fdot2)
        acc2 = __builtin_amdgcn_fdot2(rv.h[0], wvv.h[0], acc2, false);
        acc2 = __builtin_amdgcn_fdot2(rv.h[1], wvv.h[1], acc2, false);
        acc2 = __builtin_amdgcn_fdot2(rv.h[2], wvv.h[2], acc2, false);
        acc2 = __builtin_amdgcn_fdot2(rv.h[3], wvv.h[3], acc2, false);
#else
#pragma unroll
        for (int e = 0; e < 8; ++e) acc2 += (float)rv.v[e] * (float)wvv.v[e];
#endif
    }
    float ps = acc2 * a2s, pd = acc2 * a2d;
#pragma unroll
    for (int o = 1; o < 32; o <<= 1) { ps += __shfl_xor(ps, o); pd += __shfl_xor(pd, o); }
    if (vn) {
        h2h[(size_t)nid * 32 + c] = (_Float16)acc2;
        if (l5 == 0) { as2[nid] = ps; ad2[nid] = pd; }
    }
}

// D4: layer-2 softmax + aggregate (2 nodes/wave: 8 ch-groups x 4 subsets)
__global__ __launch_bounds__(256) void agg2_kernel(const _Float16* __restrict__ h2h,
                                                   const float* __restrict__ as2,
                                                   const float* __restrict__ ad2,
                                                   const int* __restrict__ rp,
                                                   const int* __restrict__ col,
                                                   const float* __restrict__ b2,
                                                   float* __restrict__ out, int n) {
    int wave = threadIdx.x >> 6, lane = threadIdx.x & 63;
    int h = lane >> 5, l5 = lane & 31;
    int g = l5 & 7, sub = l5 >> 3;            // ch-group (8), edge subset (4)
    int nid = blockIdx.x * 8 + wave * 2 + h;
    bool vn = nid < n;
    int nc = vn ? nid : 0;
    int start = rp[nc];
    int end = vn ? rp[nc + 1] : start;
    float adn = ad2[nc];
    float psf = vn ? __expf(leaky(as2[nc] + adn)) : 0.f;
    float dnum = 0.f;
    float4 acc = make_float4(0.f, 0.f, 0.f, 0.f);
    for (int base = start; base < end; base += 32) {
        int i = base + l5;
        int sidx = 0;
        float p = 0.f;
        if (i < end) {
            sidx = col[i];
            p = __expf(leaky(as2[sidx] + adn));
        }
        int len = min(32, end - base);
        int steps = (len + 3) >> 2;
#pragma unroll 4
        for (int s = 0; s < steps; ++s) {
            int j = s * 4 + sub;
            bool valid = j < len;
            int js = valid ? j : 0;
            int sl = (h << 5) + js;
            int rj = __shfl(sidx, sl);
            float pj = __shfl(p, sl);
            pj = valid ? pj : 0.f;
            H4 u = ((const H4*)(h2h + (size_t)rj * 32))[g];
            dnum += pj;
            acc.x += (float)u.h[0].x * pj; acc.y += (float)u.h[0].y * pj;
            acc.z += (float)u.h[1].x * pj; acc.w += (float)u.h[1].y * pj;
        }
    }
    if (sub == 0) {
        H4 u = ((const H4*)(h2h + (size_t)nc * 32))[g];
        dnum += psf;
        acc.x += (float)u.h[0].x * psf; acc.y += (float)u.h[0].y * psf;
        acc.z += (float)u.h[1].x * psf; acc.w += (float)u.h[1].y * psf;
    }
#pragma unroll
    for (int o = 8; o < 32; o <<= 1) {        // reduce over 4 subsets, within half
        acc.x += __shfl_xor(acc.x, o); acc.y += __shfl_xor(acc.y, o);
        acc.z += __shfl_xor(acc.z, o); acc.w += __shfl_xor(acc.w, o);
        dnum += __shfl_xor(dnum, o);
    }
    if (sub == 0 && vn) {
        float inv = __builtin_amdgcn_rcpf(dnum);
        float4 bb = ((const float4*)b2)[g];
        ((float4*)(out + (size_t)nid * 32))[g] =
            make_float4(acc.x * inv + bb.x, acc.y * inv + bb.y,
                        acc.z * inv + bb.z, acc.w * inv + bb.w);
    }
}

// ================= launch =================

extern "C" void kernel_launch(void* const* d_in, const int* in_sizes, int n_in,
                              void* d_out, int out_size, void* d_ws, size_t ws_size,
                              hipStream_t stream) {
    const float* x      = (const float*)d_in[0];
    const int*   ei     = (const int*)d_in[1];
    const float* W1     = (const float*)d_in[2];
    const float* a_src1 = (const float*)d_in[3];
    const float* a_dst1 = (const float*)d_in[4];
    const float* b1     = (const float*)d_in[5];
    const float* W2     = (const float*)d_in[6];
    const float* a_src2 = (const float*)d_in[7];
    const float* a_dst2 = (const float*)d_in[8];
    const float* b2     = (const float*)d_in[9];
    float* out = (float*)d_out;

    const int N = in_sizes[0] / 128;
    const int E = in_sizes[1] / 2;
    const int* src = ei;
    const int* dstp = ei + E;

    uint8_t* w = (uint8_t*)d_ws;
    auto carve = [&](size_t bytes) {
        uint8_t* p = w;
        w += (bytes + 255) & ~(size_t)255;
        return p;
    };
    _Float16* h1h = (_Float16*)carve((size_t)N * 128 * 2);
    _Float16* h2h = (_Float16*)carve((size_t)N * 32 * 2);
    _Float16* W1t = (_Float16*)carve((size_t)128 * 128 * 2);
    _Float16* W2t = (_Float16*)carve((size_t)32 * 128 * 2);
    float* as1 = (float*)carve((size_t)N * 4 * 4);
    float* ad1 = (float*)carve((size_t)N * 4 * 4);
    float* as2 = (float*)carve((size_t)N * 4);
    float* ad2 = (float*)carve((size_t)N * 4);
    int* rp    = (int*)carve((size_t)(N + 1) * 4);
    int* col   = (int*)carve((size_t)E * 4);
    int* bcur  = (int*)carve(256 * 4);       // per-bucket cursors

    const int NB = ((N - 1) >> 8) + 1;       // coarse buckets
    const int KB = (N >> 8) + 1;             // csr blocks (covers rp[N] corner)
    int CH = (E + PB - 1) / PB;
    CH = (CH + 3) & ~3;                      // int4 alignment of chunk bases
    const int gemmBlocks = (N + 63) / 64;
    const int aggGroups = (N + 7) / 8;       // 8 nodes per block (2 per wave)

    int2* pairs = (int2*)carve((size_t)NB * CAP * 8);   // 8 MB

    // D0: zero bucket cursors (1 KB)
    hipMemsetAsync(bcur, 0, 256 * 4, stream);
    // D1: pair scatter (cursor-reserved bases) + weight transposes
    pairprep_kernel<<<PB + 80, 256, 0, stream>>>(src, dstp, bcur, pairs,
                                                 E, NB, CH, W1, W2, W1t, W2t);
    // D2: csr buckets + MFMA gemm1 (independent; csr hides under gemm)
    csr_gemm_kernel<<<KB + gemmBlocks, 256, 0, stream>>>(
        pairs, bcur, rp, col, E, N, NB, KB,
        x, W1t, a_src1, a_dst1, h1h, as1, ad1);
    // D3: layer-1 aggregate + fused layer-2 GEMV (2 nodes/wave)
    agg1_kernel<<<aggGroups, 256, 0, stream>>>(h1h, (const float4*)as1,
                                               (const float4*)ad1, rp, col, b1,
                                               W2t, a_src2, a_dst2, h2h, as2, ad2, N);
    // D4: layer-2 aggregate (2 nodes/wave)
    agg2_kernel<<<aggGroups, 256, 0, stream>>>(h2h, as2, ad2, rp, col, b2, out, N);
}

// Round 12
// 184.387 us; speedup vs baseline: 9.4023x; 1.0285x over previous
//
#include <hip/hip_runtime.h>
#include <cstdint>

#define NEG_SLOPE 0.2f
#define LDA 136
#define PB  256         // pair chunks
#define CAP 5120        // per-bucket pair capacity (mean 4096 + 16 sigma)
#define SMEM_BYTES (64 * LDA * 2)   // 17408 B

__device__ __forceinline__ float leaky(float v) { return v > 0.f ? v : NEG_SLOPE * v; }
__device__ __forceinline__ float elu(float v) { return v > 0.f ? v : __expf(v) - 1.f; }

typedef _Float16 half2v __attribute__((ext_vector_type(2)));
typedef _Float16 f16x8 __attribute__((ext_vector_type(8)));
typedef float f32x4 __attribute__((ext_vector_type(4)));
union H8 { float4 f4; half2v h[4]; f16x8 v8; };
union H4 { float2 f2; half2v h[2]; };
union HF2 { float2 f2; _Float16 h[4]; };
union HH { f16x8 v; half2v h[4]; };

// ================= phase bodies =================

__device__ __forceinline__ void prep_body(int bid, int G, int tid,
        const float* __restrict__ W1, const float* __restrict__ W2,
        _Float16* __restrict__ W1t, _Float16* __restrict__ W2t) {
    for (int i = bid * 256 + tid; i < 128 * 128; i += G * 256) {
        int c = i >> 7, k = i & 127;
        W1t[i] = (_Float16)W1[k * 128 + c];
    }
    for (int i = bid * 256 + tid; i < 32 * 128; i += G * 256) {
        int c = i >> 7, k = i & 127;
        W2t[i] = (_Float16)W2[k * 32 + c];
    }
}

__device__ __forceinline__ void gemm1_tile(int b, int tid, _Float16* Ah,
        const float* __restrict__ x, const _Float16* __restrict__ W1t,
        const float* __restrict__ a_src, const float* __restrict__ a_dst,
        _Float16* __restrict__ h1h, float* __restrict__ as1, float* __restrict__ ad1,
        int n) {
    int row0 = b * 64;
    const float4* x4 = (const float4*)x;
#pragma unroll
    for (int i = 0; i < 8; ++i) {
        int idx = tid + i * 256;          // float4 id: row*32 + c4
        int row = idx >> 5, c4 = idx & 31;
        float4 v = make_float4(0.f, 0.f, 0.f, 0.f);
        if (row0 + row < n) v = x4[(size_t)(row0 + row) * 32 + c4];
        HF2 u;
        u.h[0] = (_Float16)v.x; u.h[1] = (_Float16)v.y;
        u.h[2] = (_Float16)v.z; u.h[3] = (_Float16)v.w;
        *(float2*)&Ah[row * LDA + c4 * 4] = u.f2;
    }
    __syncthreads();

    int l = tid & 63, w = tid >> 6;
    int lr = l & 15, lg = l >> 4;
    f16x8 af[4];
#pragma unroll
    for (int kk = 0; kk < 4; ++kk)
        af[kk] = *(const f16x8*)&Ah[(w * 16 + lr) * LDA + kk * 32 + lg * 8];
    f32x4 acc[8];
#pragma unroll
    for (int t = 0; t < 8; ++t) acc[t] = (f32x4)0.f;
#pragma unroll
    for (int t = 0; t < 8; ++t) {
#pragma unroll
        for (int kk = 0; kk < 4; ++kk) {
            f16x8 bf = *(const f16x8*)&W1t[(size_t)(t * 16 + lr) * 128 + kk * 32 + lg * 8];
            acc[t] = __builtin_amdgcn_mfma_f32_16x16x32_f16(af[kk], bf, acc[t], 0, 0, 0);
        }
    }
    __syncthreads();
#pragma unroll
    for (int t = 0; t < 8; ++t)
#pragma unroll
        for (int r = 0; r < 4; ++r)
            Ah[(w * 16 + lg * 4 + r) * LDA + t * 16 + lr] = (_Float16)acc[t][r];
    __syncthreads();
    int row = tid >> 2, q = tid & 3;
    if (row0 + row < n) {
        const float* asv = a_src + q * 32;
        const float* adv = a_dst + q * 32;
        float ps = 0.f, pd = 0.f;
#pragma unroll
        for (int j = 0; j < 4; ++j) {
            f16x8 v = *(const f16x8*)&Ah[row * LDA + q * 32 + j * 8];
            *(f16x8*)&h1h[(size_t)(row0 + row) * 128 + q * 32 + j * 8] = v;
#pragma unroll
            for (int e = 0; e < 8; ++e) {
                float f = (float)v[e];
                ps += f * asv[j * 8 + e];
                pd += f * adv[j * 8 + e];
            }
        }
        as1[(row0 + row) * 4 + q] = ps;
        ad1[(row0 + row) * 4 + q] = pd;
    }
}

// ================= kernels =================

// D1: pair scatter with cursor-reserved bases + weight transposes.
__global__ __launch_bounds__(256) void pairprep_kernel(
        const int* __restrict__ src, const int* __restrict__ dstp,
        int* __restrict__ bcur, int2* __restrict__ pairs,
        int E, int NB, int CH,
        const float* __restrict__ W1, const float* __restrict__ W2,
        _Float16* __restrict__ W1t, _Float16* __restrict__ W2t) {
    int bid = (int)blockIdx.x, tid = threadIdx.x;
    if (bid >= PB) {
        prep_body(bid - PB, (int)gridDim.x - PB, tid, W1, W2, W1t, W2t);
        return;
    }
    __shared__ int lh[256];
    for (int t = tid; t < NB; t += 256) lh[t] = 0;
    __syncthreads();
    int e0 = bid * CH, e1 = min(e0 + CH, E);
    int nv = (e1 - e0) & ~3;
    // pass 1: chunk histogram (LDS atomics only)
    for (int i = e0 + tid * 4; i < e0 + nv; i += 1024) {
        int4 d = *(const int4*)(dstp + i);
        atomicAdd(&lh[d.x >> 8], 1);
        atomicAdd(&lh[d.y >> 8], 1);
        atomicAdd(&lh[d.z >> 8], 1);
        atomicAdd(&lh[d.w >> 8], 1);
    }
    for (int i = e0 + nv + tid; i < e1; i += 256)
        atomicAdd(&lh[dstp[i] >> 8], 1);
    __syncthreads();
    // reserve bases: one returning atomic per non-empty bucket
    for (int t = tid; t < NB; t += 256) {
        int c = lh[t];
        lh[t] = (c > 0) ? atomicAdd(&bcur[t], c) : 0;
    }
    __syncthreads();
    // pass 2: scatter at base+rank (LDS cursor continues from base)
    for (int i = e0 + tid * 4; i < e0 + nv; i += 1024) {
        int4 d = *(const int4*)(dstp + i);
        int4 s = *(const int4*)(src + i);
        int b0 = d.x >> 8, b1 = d.y >> 8, b2 = d.z >> 8, b3 = d.w >> 8;
        int r0 = atomicAdd(&lh[b0], 1);
        int r1 = atomicAdd(&lh[b1], 1);
        int r2 = atomicAdd(&lh[b2], 1);
        int r3 = atomicAdd(&lh[b3], 1);
        if (r0 < CAP) pairs[(size_t)b0 * CAP + r0] = make_int2(s.x, d.x & 255);
        if (r1 < CAP) pairs[(size_t)b1 * CAP + r1] = make_int2(s.y, d.y & 255);
        if (r2 < CAP) pairs[(size_t)b2 * CAP + r2] = make_int2(s.z, d.z & 255);
        if (r3 < CAP) pairs[(size_t)b3 * CAP + r3] = make_int2(s.w, d.w & 255);
    }
    for (int i = e0 + nv + tid; i < e1; i += 256) {
        int d = dstp[i];
        int b = d >> 8;
        int r = atomicAdd(&lh[b], 1);
        if (r < CAP) pairs[(size_t)b * CAP + r] = make_int2(src[i], d & 255);
    }
}

// D2: csr buckets + MFMA gemm1 tiles
__device__ __forceinline__ void csr_bucket(int b, int tid, unsigned char* smem,
        const int2* __restrict__ pairs, const int* __restrict__ bcur,
        int* __restrict__ rp, int* __restrict__ col, int E, int N, int NB) {
    int* lsz    = (int*)smem;
    int* lstart = lsz + 256;
    int* lnh    = lstart + 256;
    int* lnex   = lnh + 256;
    int* lncur  = lnex + 256;
    int* wsum   = lncur + 256;
    int* woff   = wsum + 4;
    int lane = tid & 63, wv = tid >> 6;

    lsz[tid] = (tid < NB) ? bcur[tid] : 0;   // true bucket sizes (sum = E)
    __syncthreads();
    int v = lsz[tid];
    int x = v;
#pragma unroll
    for (int o = 1; o < 64; o <<= 1) { int u = __shfl_up(x, o); if (lane >= o) x += u; }
    if (lane == 63) wsum[wv] = x;
    __syncthreads();
    if (tid == 0) { int a = 0; for (int i = 0; i < 4; ++i) { woff[i] = a; a += wsum[i]; } }
    __syncthreads();
    lstart[tid] = x - v + woff[wv];
    __syncthreads();

    if (b >= NB) { if (tid == 0) rp[N] = E; return; }
    int myStart = lstart[b];
    int S = lsz[b]; if (S > CAP) S = CAP;
    const int2* pb = pairs + (size_t)b * CAP;

    lnh[tid] = 0;
    __syncthreads();
    for (int i = tid; i < S; i += 256) atomicAdd(&lnh[pb[i].y], 1);
    __syncthreads();
    int v2 = lnh[tid];
    int x2 = v2;
#pragma unroll
    for (int o = 1; o < 64; o <<= 1) { int u = __shfl_up(x2, o); if (lane >= o) x2 += u; }
    if (lane == 63) wsum[wv] = x2;
    __syncthreads();
    if (tid == 0) { int a = 0; for (int i = 0; i < 4; ++i) { woff[i] = a; a += wsum[i]; } }
    __syncthreads();
    int ex2 = x2 - v2 + woff[wv];
    lnex[tid] = ex2;
    lncur[tid] = 0;
    int node = (b << 8) + tid;
    if (node <= N) rp[node] = myStart + ex2;
    __syncthreads();
    for (int i = tid; i < S; i += 256) {
        int2 p = pb[i];
        int r = atomicAdd(&lncur[p.y], 1);
        col[myStart + lnex[p.y] + r] = p.x;
    }
}

__global__ __launch_bounds__(256) void csr_gemm_kernel(
        const int2* __restrict__ pairs, const int* __restrict__ bcur,
        int* __restrict__ rp, int* __restrict__ col, int E, int N, int NB, int KB,
        const float* __restrict__ x, const _Float16* __restrict__ W1t,
        const float* __restrict__ a_src, const float* __restrict__ a_dst,
        _Float16* __restrict__ h1h, float* __restrict__ as1, float* __restrict__ ad1) {
    __shared__ __align__(16) unsigned char smem[SMEM_BYTES];
    int bid = (int)blockIdx.x;
    if (bid < KB) {
        csr_bucket(bid, threadIdx.x, smem, pairs, bcur, rp, col, E, N, NB);
        return;
    }
    gemm1_tile(bid - KB, threadIdx.x, (_Float16*)smem, x, W1t, a_src, a_dst,
               h1h, as1, ad1, N);
}

// D3: layer-1 softmax+aggregate + fused layer-2 GEMV.
// FOUR NODES PER WAVE (16 lanes/node = 16 ch-groups x 1 edge subset):
// steps = len exactly (no pad lanes), NO cross-lane reductions (each lane
// accumulates full dnum + its 8 channels over all edges), 4 independent
// gather chains per wave (2x MLP vs round 11).
#define W2S 136   // sW2 row stride in halves (16B-aligned for b128 reads)

__global__ __launch_bounds__(256) void agg1_kernel(const _Float16* __restrict__ h1h,
                                                   const float4* __restrict__ as1,
                                                   const float4* __restrict__ ad1,
                                                   const int* __restrict__ rp,
                                                   const int* __restrict__ col,
                                                   const float* __restrict__ b1,
                                                   const _Float16* __restrict__ W2t,
                                                   const float* __restrict__ a_src2,
                                                   const float* __restrict__ a_dst2,
                                                   _Float16* __restrict__ h2h,
                                                   float* __restrict__ as2,
                                                   float* __restrict__ ad2, int n) {
    __shared__ float4 s_p[4][64];
    __shared__ _Float16 s_row[4][4][128];
    __shared__ _Float16 sW2[32 * W2S];
    int tid = threadIdx.x;
    for (int e = tid; e < 32 * 16; e += 256) {
        int c = e >> 4, k8 = e & 15;
        *(f16x8*)&sW2[c * W2S + k8 * 8] = *(const f16x8*)&W2t[c * 128 + k8 * 8];
    }
    __syncthreads();

    int wave = tid >> 6, lane = tid & 63;
    int q4 = lane >> 4, l4 = lane & 15;       // node quarter, lane-in-quarter
    int g = l4;                               // ch-group (8 ch each)
    int head = g >> 2;
    int nid = blockIdx.x * 16 + wave * 4 + q4;
    bool vn = nid < n;
    int nc = vn ? nid : 0;
    float4* sp = s_p[wave];
    int start = rp[nc];
    int end = vn ? rp[nc + 1] : start;
    float4 adn = ad1[nc], asn = as1[nc];
    float sv = (head == 0) ? asn.x + adn.x : (head == 1) ? asn.y + adn.y
             : (head == 2) ? asn.z + adn.z : asn.w + adn.w;
    float psf_h = vn ? __expf(leaky(sv)) : 0.f;
    float dnum = 0.f;
    float4 a0 = make_float4(0.f, 0.f, 0.f, 0.f);
    float4 a1 = a0;

    for (int base = start; base < end; base += 16) {
        int i = base + l4;
        int sidx = 0;
        float4 p = make_float4(0.f, 0.f, 0.f, 0.f);
        if (i < end) {
            sidx = col[i];
            float4 a = as1[sidx];
            p.x = __expf(leaky(a.x + adn.x));
            p.y = __expf(leaky(a.y + adn.y));
            p.z = __expf(leaky(a.z + adn.z));
            p.w = __expf(leaky(a.w + adn.w));
        }
        sp[lane] = p;
        int len = min(16, end - base);        // steps = len, all iterations real
#pragma unroll 4
        for (int s = 0; s < len; ++s) {
            int sl = (lane & 48) + s;         // source lane within this node's 16
            int rj = __shfl(sidx, sl);
            float pj = ((const float*)&sp[sl])[head];
            H8 u = ((const H8*)(h1h + (size_t)rj * 128))[g];
            dnum += pj;
            a0.x += (float)u.h[0].x * pj; a0.y += (float)u.h[0].y * pj;
            a0.z += (float)u.h[1].x * pj; a0.w += (float)u.h[1].y * pj;
            a1.x += (float)u.h[2].x * pj; a1.y += (float)u.h[2].y * pj;
            a1.z += (float)u.h[3].x * pj; a1.w += (float)u.h[3].y * pj;
        }
    }
    // self loop (every lane: its own 8 channels)
    {
        H8 u = ((const H8*)(h1h + (size_t)nc * 128))[g];
        dnum += psf_h;
        a0.x += (float)u.h[0].x * psf_h; a0.y += (float)u.h[0].y * psf_h;
        a0.z += (float)u.h[1].x * psf_h; a0.w += (float)u.h[1].y * psf_h;
        a1.x += (float)u.h[2].x * psf_h; a1.y += (float)u.h[2].y * psf_h;
        a1.z += (float)u.h[3].x * psf_h; a1.w += (float)u.h[3].y * psf_h;
    }
    // dnum and a0/a1 are COMPLETE per lane -- no reduction needed.
    if (vn) {
        float inv = __builtin_amdgcn_rcpf(dnum);
        const float4* b4 = (const float4*)b1;
        float4 bb0 = b4[g * 2], bb1 = b4[g * 2 + 1];
        float4 r0 = make_float4(elu(a0.x * inv + bb0.x), elu(a0.y * inv + bb0.y),
                                elu(a0.z * inv + bb0.z), elu(a0.w * inv + bb0.w));
        float4 r1 = make_float4(elu(a1.x * inv + bb1.x), elu(a1.y * inv + bb1.y),
                                elu(a1.z * inv + bb1.z), elu(a1.w * inv + bb1.w));
        H8 o8;
        o8.h[0] = half2v{(_Float16)r0.x, (_Float16)r0.y};
        o8.h[1] = half2v{(_Float16)r0.z, (_Float16)r0.w};
        o8.h[2] = half2v{(_Float16)r1.x, (_Float16)r1.y};
        o8.h[3] = half2v{(_Float16)r1.z, (_Float16)r1.w};
        *(float4*)&s_row[wave][q4][g * 8] = o8.f4;
    }
    // ---- fused layer-2 GEMV: 16 lanes/node, 2 output cols per lane ----
    int c0 = l4, c1 = l4 + 16;
    float acc2a = 0.f, acc2b = 0.f;
#pragma unroll
    for (int k8 = 0; k8 < 16; ++k8) {
        HH rv, w0, w1;
        rv.v = *(const f16x8*)&s_row[wave][q4][k8 * 8];
        w0.v = *(const f16x8*)&sW2[c0 * W2S + k8 * 8];
        w1.v = *(const f16x8*)&sW2[c1 * W2S + k8 * 8];
#if __has_builtin(__builtin_amdgcn_fdot2)
        acc2a = __builtin_amdgcn_fdot2(rv.h[0], w0.h[0], acc2a, false);
        acc2a = __builtin_amdgcn_fdot2(rv.h[1], w0.h[1], acc2a, false);
        acc2a = __builtin_amdgcn_fdot2(rv.h[2], w0.h[2], acc2a, false);
        acc2a = __builtin_amdgcn_fdot2(rv.h[3], w0.h[3], acc2a, false);
        acc2b = __builtin_amdgcn_fdot2(rv.h[0], w1.h[0], acc2b, false);
        acc2b = __builtin_amdgcn_fdot2(rv.h[1], w1.h[1], acc2b, false);
        acc2b = __builtin_amdgcn_fdot2(rv.h[2], w1.h[2], acc2b, false);
        acc2b = __builtin_amdgcn_fdot2(rv.h[3], w1.h[3], acc2b, false);
#else
#pragma unroll
        for (int e = 0; e < 8; ++e) {
            acc2a += (float)rv.v[e] * (float)w0.v[e];
            acc2b += (float)rv.v[e] * (float)w1.v[e];
        }
#endif
    }
    float ps = acc2a * a_src2[c0] + acc2b * a_src2[c1];
    float pd = acc2a * a_dst2[c0] + acc2b * a_dst2[c1];
#pragma unroll
    for (int o = 1; o < 16; o <<= 1) { ps += __shfl_xor(ps, o); pd += __shfl_xor(pd, o); }
    if (vn) {
        h2h[(size_t)nid * 32 + c0] = (_Float16)acc2a;
        h2h[(size_t)nid * 32 + c1] = (_Float16)acc2b;
        if (l4 == 0) { as2[nid] = ps; ad2[nid] = pd; }
    }
}

// D4: layer-2 softmax + aggregate. EIGHT NODES PER WAVE (8 lanes/node =
// 8 ch-groups x 1 subset): no reductions at all, 8 chains/wave.
__global__ __launch_bounds__(256) void agg2_kernel(const _Float16* __restrict__ h2h,
                                                   const float* __restrict__ as2,
                                                   const float* __restrict__ ad2,
                                                   const int* __restrict__ rp,
                                                   const int* __restrict__ col,
                                                   const float* __restrict__ b2,
                                                   float* __restrict__ out, int n) {
    int wave = threadIdx.x >> 6, lane = threadIdx.x & 63;
    int q8 = lane >> 3, l3 = lane & 7;
    int g = l3;                               // ch-group (4 ch each)
    int nid = blockIdx.x * 32 + wave * 8 + q8;
    bool vn = nid < n;
    int nc = vn ? nid : 0;
    int start = rp[nc];
    int end = vn ? rp[nc + 1] : start;
    float adn = ad2[nc];
    float psf = vn ? __expf(leaky(as2[nc] + adn)) : 0.f;
    float dnum = 0.f;
    float4 acc = make_float4(0.f, 0.f, 0.f, 0.f);
    for (int base = start; base < end; base += 8) {
        int i = base + l3;
        int sidx = 0;
        float p = 0.f;
        if (i < end) {
            sidx = col[i];
            p = __expf(leaky(as2[sidx] + adn));
        }
        int len = min(8, end - base);         // steps = len, all real
#pragma unroll 4
        for (int s = 0; s < len; ++s) {
            int sl = (lane & 56) + s;
            int rj = __shfl(sidx, sl);
            float pj = __shfl(p, sl);
            H4 u = ((const H4*)(h2h + (size_t)rj * 32))[g];
            dnum += pj;
            acc.x += (float)u.h[0].x * pj; acc.y += (float)u.h[0].y * pj;
            acc.z += (float)u.h[1].x * pj; acc.w += (float)u.h[1].y * pj;
        }
    }
    {
        H4 u = ((const H4*)(h2h + (size_t)nc * 32))[g];
        dnum += psf;
        acc.x += (float)u.h[0].x * psf; acc.y += (float)u.h[0].y * psf;
        acc.z += (float)u.h[1].x * psf; acc.w += (float)u.h[1].y * psf;
    }
    // dnum and acc complete per lane -- direct store.
    if (vn) {
        float inv = __builtin_amdgcn_rcpf(dnum);
        float4 bb = ((const float4*)b2)[g];
        ((float4*)(out + (size_t)nid * 32))[g] =
            make_float4(acc.x * inv + bb.x, acc.y * inv + bb.y,
                        acc.z * inv + bb.z, acc.w * inv + bb.w);
    }
}

// ================= launch =================

extern "C" void kernel_launch(void* const* d_in, const int* in_sizes, int n_in,
                              void* d_out, int out_size, void* d_ws, size_t ws_size,
                              hipStream_t stream) {
    const float* x      = (const float*)d_in[0];
    const int*   ei     = (const int*)d_in[1];
    const float* W1     = (const float*)d_in[2];
    const float* a_src1 = (const float*)d_in[3];
    const float* a_dst1 = (const float*)d_in[4];
    const float* b1     = (const float*)d_in[5];
    const float* W2     = (const float*)d_in[6];
    const float* a_src2 = (const float*)d_in[7];
    const float* a_dst2 = (const float*)d_in[8];
    const float* b2     = (const float*)d_in[9];
    float* out = (float*)d_out;

    const int N = in_sizes[0] / 128;
    const int E = in_sizes[1] / 2;
    const int* src = ei;
    const int* dstp = ei + E;

    uint8_t* w = (uint8_t*)d_ws;
    auto carve = [&](size_t bytes) {
        uint8_t* p = w;
        w += (bytes + 255) & ~(size_t)255;
        return p;
    };
    _Float16* h1h = (_Float16*)carve((size_t)N * 128 * 2);
    _Float16* h2h = (_Float16*)carve((size_t)N * 32 * 2);
    _Float16* W1t = (_Float16*)carve((size_t)128 * 128 * 2);
    _Float16* W2t = (_Float16*)carve((size_t)32 * 128 * 2);
    float* as1 = (float*)carve((size_t)N * 4 * 4);
    float* ad1 = (float*)carve((size_t)N * 4 * 4);
    float* as2 = (float*)carve((size_t)N * 4);
    float* ad2 = (float*)carve((size_t)N * 4);
    int* rp    = (int*)carve((size_t)(N + 1) * 4);
    int* col   = (int*)carve((size_t)E * 4);
    int* bcur  = (int*)carve(256 * 4);       // per-bucket cursors

    const int NB = ((N - 1) >> 8) + 1;       // coarse buckets
    const int KB = (N >> 8) + 1;             // csr blocks (covers rp[N] corner)
    int CH = (E + PB - 1) / PB;
    CH = (CH + 3) & ~3;                      // int4 alignment of chunk bases
    const int gemmBlocks = (N + 63) / 64;
    const int agg1Groups = (N + 15) / 16;    // 16 nodes per block (4 per wave)
    const int agg2Groups = (N + 31) / 32;    // 32 nodes per block (8 per wave)

    int2* pairs = (int2*)carve((size_t)NB * CAP * 8);   // 8 MB

    // D0: zero bucket cursors (1 KB)
    hipMemsetAsync(bcur, 0, 256 * 4, stream);
    // D1: pair scatter (cursor-reserved bases) + weight transposes
    pairprep_kernel<<<PB + 80, 256, 0, stream>>>(src, dstp, bcur, pairs,
                                                 E, NB, CH, W1, W2, W1t, W2t);
    // D2: csr buckets + MFMA gemm1 (independent; csr hides under gemm)
    csr_gemm_kernel<<<KB + gemmBlocks, 256, 0, stream>>>(
        pairs, bcur, rp, col, E, N, NB, KB,
        x, W1t, a_src1, a_dst1, h1h, as1, ad1);
    // D3: layer-1 aggregate + fused layer-2 GEMV (4 nodes/wave)
    agg1_kernel<<<agg1Groups, 256, 0, stream>>>(h1h, (const float4*)as1,
                                                (const float4*)ad1, rp, col, b1,
                                                W2t, a_src2, a_dst2, h2h, as2, ad2, N);
    // D4: layer-2 aggregate (8 nodes/wave)
    agg2_kernel<<<agg2Groups, 256, 0, stream>>>(h2h, as2, ad2, rp, col, b2, out, N);
}

// Round 13
// 180.081 us; speedup vs baseline: 9.6271x; 1.0239x over previous
//
#include <hip/hip_runtime.h>
#include <cstdint>

#define NEG_SLOPE 0.2f
#define LDA 136
#define PB  256         // pair chunks
#define CAP 5120        // per-bucket pair capacity (mean 4096 + 16 sigma)
#define SMEM_BYTES (64 * LDA * 2)   // 17408 B

__device__ __forceinline__ float leaky(float v) { return v > 0.f ? v : NEG_SLOPE * v; }
__device__ __forceinline__ float elu(float v) { return v > 0.f ? v : __expf(v) - 1.f; }

typedef _Float16 half2v __attribute__((ext_vector_type(2)));
typedef _Float16 f16x8 __attribute__((ext_vector_type(8)));
typedef float f32x4 __attribute__((ext_vector_type(4)));
union H8 { float4 f4; half2v h[4]; f16x8 v8; };
union H4 { float2 f2; half2v h[2]; };
union HF2 { float2 f2; _Float16 h[4]; };
union HH { f16x8 v; half2v h[4]; };

// ================= phase bodies =================

__device__ __forceinline__ void prep_body(int bid, int G, int tid,
        const float* __restrict__ W1, const float* __restrict__ W2,
        _Float16* __restrict__ W1t, _Float16* __restrict__ W2t) {
    for (int i = bid * 256 + tid; i < 128 * 128; i += G * 256) {
        int c = i >> 7, k = i & 127;
        W1t[i] = (_Float16)W1[k * 128 + c];
    }
    for (int i = bid * 256 + tid; i < 32 * 128; i += G * 256) {
        int c = i >> 7, k = i & 127;
        W2t[i] = (_Float16)W2[k * 32 + c];
    }
}

__device__ __forceinline__ void gemm1_tile(int b, int tid, _Float16* Ah,
        const float* __restrict__ x, const _Float16* __restrict__ W1t,
        const float* __restrict__ a_src, const float* __restrict__ a_dst,
        _Float16* __restrict__ h1h, float* __restrict__ as1, float* __restrict__ ad1,
        int n) {
    int row0 = b * 64;
    const float4* x4 = (const float4*)x;
#pragma unroll
    for (int i = 0; i < 8; ++i) {
        int idx = tid + i * 256;          // float4 id: row*32 + c4
        int row = idx >> 5, c4 = idx & 31;
        float4 v = make_float4(0.f, 0.f, 0.f, 0.f);
        if (row0 + row < n) v = x4[(size_t)(row0 + row) * 32 + c4];
        HF2 u;
        u.h[0] = (_Float16)v.x; u.h[1] = (_Float16)v.y;
        u.h[2] = (_Float16)v.z; u.h[3] = (_Float16)v.w;
        *(float2*)&Ah[row * LDA + c4 * 4] = u.f2;
    }
    __syncthreads();

    int l = tid & 63, w = tid >> 6;
    int lr = l & 15, lg = l >> 4;
    f16x8 af[4];
#pragma unroll
    for (int kk = 0; kk < 4; ++kk)
        af[kk] = *(const f16x8*)&Ah[(w * 16 + lr) * LDA + kk * 32 + lg * 8];
    f32x4 acc[8];
#pragma unroll
    for (int t = 0; t < 8; ++t) acc[t] = (f32x4)0.f;
#pragma unroll
    for (int t = 0; t < 8; ++t) {
#pragma unroll
        for (int kk = 0; kk < 4; ++kk) {
            f16x8 bf = *(const f16x8*)&W1t[(size_t)(t * 16 + lr) * 128 + kk * 32 + lg * 8];
            acc[t] = __builtin_amdgcn_mfma_f32_16x16x32_f16(af[kk], bf, acc[t], 0, 0, 0);
        }
    }
    __syncthreads();
#pragma unroll
    for (int t = 0; t < 8; ++t)
#pragma unroll
        for (int r = 0; r < 4; ++r)
            Ah[(w * 16 + lg * 4 + r) * LDA + t * 16 + lr] = (_Float16)acc[t][r];
    __syncthreads();
    int row = tid >> 2, q = tid & 3;
    if (row0 + row < n) {
        const float* asv = a_src + q * 32;
        const float* adv = a_dst + q * 32;
        float ps = 0.f, pd = 0.f;
#pragma unroll
        for (int j = 0; j < 4; ++j) {
            f16x8 v = *(const f16x8*)&Ah[row * LDA + q * 32 + j * 8];
            *(f16x8*)&h1h[(size_t)(row0 + row) * 128 + q * 32 + j * 8] = v;
#pragma unroll
            for (int e = 0; e < 8; ++e) {
                float f = (float)v[e];
                ps += f * asv[j * 8 + e];
                pd += f * adv[j * 8 + e];
            }
        }
        as1[(row0 + row) * 4 + q] = ps;
        ad1[(row0 + row) * 4 + q] = pd;
    }
}

// ================= kernels =================

// D1: pair scatter with cursor-reserved bases + weight transposes.
__global__ __launch_bounds__(256) void pairprep_kernel(
        const int* __restrict__ src, const int* __restrict__ dstp,
        int* __restrict__ bcur, int2* __restrict__ pairs,
        int E, int NB, int CH,
        const float* __restrict__ W1, const float* __restrict__ W2,
        _Float16* __restrict__ W1t, _Float16* __restrict__ W2t) {
    int bid = (int)blockIdx.x, tid = threadIdx.x;
    if (bid >= PB) {
        prep_body(bid - PB, (int)gridDim.x - PB, tid, W1, W2, W1t, W2t);
        return;
    }
    __shared__ int lh[256];
    for (int t = tid; t < NB; t += 256) lh[t] = 0;
    __syncthreads();
    int e0 = bid * CH, e1 = min(e0 + CH, E);
    int nv = (e1 - e0) & ~3;
    // pass 1: chunk histogram (LDS atomics only)
    for (int i = e0 + tid * 4; i < e0 + nv; i += 1024) {
        int4 d = *(const int4*)(dstp + i);
        atomicAdd(&lh[d.x >> 8], 1);
        atomicAdd(&lh[d.y >> 8], 1);
        atomicAdd(&lh[d.z >> 8], 1);
        atomicAdd(&lh[d.w >> 8], 1);
    }
    for (int i = e0 + nv + tid; i < e1; i += 256)
        atomicAdd(&lh[dstp[i] >> 8], 1);
    __syncthreads();
    // reserve bases: one returning atomic per non-empty bucket
    for (int t = tid; t < NB; t += 256) {
        int c = lh[t];
        lh[t] = (c > 0) ? atomicAdd(&bcur[t], c) : 0;
    }
    __syncthreads();
    // pass 2: scatter at base+rank (LDS cursor continues from base)
    for (int i = e0 + tid * 4; i < e0 + nv; i += 1024) {
        int4 d = *(const int4*)(dstp + i);
        int4 s = *(const int4*)(src + i);
        int b0 = d.x >> 8, b1 = d.y >> 8, b2 = d.z >> 8, b3 = d.w >> 8;
        int r0 = atomicAdd(&lh[b0], 1);
        int r1 = atomicAdd(&lh[b1], 1);
        int r2 = atomicAdd(&lh[b2], 1);
        int r3 = atomicAdd(&lh[b3], 1);
        if (r0 < CAP) pairs[(size_t)b0 * CAP + r0] = make_int2(s.x, d.x & 255);
        if (r1 < CAP) pairs[(size_t)b1 * CAP + r1] = make_int2(s.y, d.y & 255);
        if (r2 < CAP) pairs[(size_t)b2 * CAP + r2] = make_int2(s.z, d.z & 255);
        if (r3 < CAP) pairs[(size_t)b3 * CAP + r3] = make_int2(s.w, d.w & 255);
    }
    for (int i = e0 + nv + tid; i < e1; i += 256) {
        int d = dstp[i];
        int b = d >> 8;
        int r = atomicAdd(&lh[b], 1);
        if (r < CAP) pairs[(size_t)b * CAP + r] = make_int2(src[i], d & 255);
    }
}

// D2: csr buckets + MFMA gemm1 tiles
__device__ __forceinline__ void csr_bucket(int b, int tid, unsigned char* smem,
        const int2* __restrict__ pairs, const int* __restrict__ bcur,
        int* __restrict__ rp, int* __restrict__ col, int E, int N, int NB) {
    int* lsz    = (int*)smem;
    int* lstart = lsz + 256;
    int* lnh    = lstart + 256;
    int* lnex   = lnh + 256;
    int* lncur  = lnex + 256;
    int* wsum   = lncur + 256;
    int* woff   = wsum + 4;
    int lane = tid & 63, wv = tid >> 6;

    lsz[tid] = (tid < NB) ? bcur[tid] : 0;   // true bucket sizes (sum = E)
    __syncthreads();
    int v = lsz[tid];
    int x = v;
#pragma unroll
    for (int o = 1; o < 64; o <<= 1) { int u = __shfl_up(x, o); if (lane >= o) x += u; }
    if (lane == 63) wsum[wv] = x;
    __syncthreads();
    if (tid == 0) { int a = 0; for (int i = 0; i < 4; ++i) { woff[i] = a; a += wsum[i]; } }
    __syncthreads();
    lstart[tid] = x - v + woff[wv];
    __syncthreads();

    if (b >= NB) { if (tid == 0) rp[N] = E; return; }
    int myStart = lstart[b];
    int S = lsz[b]; if (S > CAP) S = CAP;
    const int2* pb = pairs + (size_t)b * CAP;

    lnh[tid] = 0;
    __syncthreads();
    for (int i = tid; i < S; i += 256) atomicAdd(&lnh[pb[i].y], 1);
    __syncthreads();
    int v2 = lnh[tid];
    int x2 = v2;
#pragma unroll
    for (int o = 1; o < 64; o <<= 1) { int u = __shfl_up(x2, o); if (lane >= o) x2 += u; }
    if (lane == 63) wsum[wv] = x2;
    __syncthreads();
    if (tid == 0) { int a = 0; for (int i = 0; i < 4; ++i) { woff[i] = a; a += wsum[i]; } }
    __syncthreads();
    int ex2 = x2 - v2 + woff[wv];
    lnex[tid] = ex2;
    lncur[tid] = 0;
    int node = (b << 8) + tid;
    if (node <= N) rp[node] = myStart + ex2;
    __syncthreads();
    for (int i = tid; i < S; i += 256) {
        int2 p = pb[i];
        int r = atomicAdd(&lncur[p.y], 1);
        col[myStart + lnex[p.y] + r] = p.x;
    }
}

__global__ __launch_bounds__(256) void csr_gemm_kernel(
        const int2* __restrict__ pairs, const int* __restrict__ bcur,
        int* __restrict__ rp, int* __restrict__ col, int E, int N, int NB, int KB,
        const float* __restrict__ x, const _Float16* __restrict__ W1t,
        const float* __restrict__ a_src, const float* __restrict__ a_dst,
        _Float16* __restrict__ h1h, float* __restrict__ as1, float* __restrict__ ad1) {
    __shared__ __align__(16) unsigned char smem[SMEM_BYTES];
    int bid = (int)blockIdx.x;
    if (bid < KB) {
        csr_bucket(bid, threadIdx.x, smem, pairs, bcur, rp, col, E, N, NB);
        return;
    }
    gemm1_tile(bid - KB, threadIdx.x, (_Float16*)smem, x, W1t, a_src, a_dst,
               h1h, as1, ad1, N);
}

// D3: layer-1 softmax+aggregate + fused layer-2 GEMV (4 nodes/wave).
// Gather inner loop: EXPLICITLY BATCHED x4 -- four h1h rows loaded into
// named registers before any FMA, forcing >=4 in-flight 16B gathers per
// thread (VGPR 28 -> ~48; round-12's compiler schedule was near-serial).
#define W2S 136   // sW2 row stride in halves (16B-aligned for b128 reads)

__global__ __launch_bounds__(256) void agg1_kernel(const _Float16* __restrict__ h1h,
                                                   const float4* __restrict__ as1,
                                                   const float4* __restrict__ ad1,
                                                   const int* __restrict__ rp,
                                                   const int* __restrict__ col,
                                                   const float* __restrict__ b1,
                                                   const _Float16* __restrict__ W2t,
                                                   const float* __restrict__ a_src2,
                                                   const float* __restrict__ a_dst2,
                                                   _Float16* __restrict__ h2h,
                                                   float* __restrict__ as2,
                                                   float* __restrict__ ad2, int n) {
    __shared__ float4 s_p[4][64];
    __shared__ _Float16 s_row[4][4][128];
    __shared__ _Float16 sW2[32 * W2S];
    int tid = threadIdx.x;
    for (int e = tid; e < 32 * 16; e += 256) {
        int c = e >> 4, k8 = e & 15;
        *(f16x8*)&sW2[c * W2S + k8 * 8] = *(const f16x8*)&W2t[c * 128 + k8 * 8];
    }
    __syncthreads();

    int wave = tid >> 6, lane = tid & 63;
    int q4 = lane >> 4, l4 = lane & 15;       // node quarter, lane-in-quarter
    int g = l4;                               // ch-group (8 ch each)
    int head = g >> 2;
    int nid = blockIdx.x * 16 + wave * 4 + q4;
    bool vn = nid < n;
    int nc = vn ? nid : 0;
    float4* sp = s_p[wave];
    int start = rp[nc];
    int end = vn ? rp[nc + 1] : start;
    float4 adn = ad1[nc], asn = as1[nc];
    float sv = (head == 0) ? asn.x + adn.x : (head == 1) ? asn.y + adn.y
             : (head == 2) ? asn.z + adn.z : asn.w + adn.w;
    float psf_h = vn ? __expf(leaky(sv)) : 0.f;
    float dnum = 0.f;
    float4 a0 = make_float4(0.f, 0.f, 0.f, 0.f);
    float4 a1 = a0;
    int lb = lane & 48;

    for (int base = start; base < end; base += 16) {
        int i = base + l4;
        int sidx = 0;
        float4 p = make_float4(0.f, 0.f, 0.f, 0.f);
        if (i < end) {
            sidx = col[i];
            float4 a = as1[sidx];
            p.x = __expf(leaky(a.x + adn.x));
            p.y = __expf(leaky(a.y + adn.y));
            p.z = __expf(leaky(a.z + adn.z));
            p.w = __expf(leaky(a.w + adn.w));
        }
        sp[lane] = p;
        int len = min(16, end - base);
        for (int s = 0; s < len; s += 4) {
            int rem = len - s;                // >= 1
            // ---- issue 4 gathers into named registers (all in flight) ----
            int sl0 = lb + s;
            int rj0 = __shfl(sidx, sl0);
            float pj0 = ((const float*)&sp[sl0])[head];
            H8 u0 = ((const H8*)(h1h + (size_t)rj0 * 128))[g];

            int sl1 = lb + ((1 < rem) ? s + 1 : s);
            int rj1 = __shfl(sidx, sl1);
            float pj1 = (1 < rem) ? ((const float*)&sp[sl1])[head] : 0.f;
            H8 u1 = ((const H8*)(h1h + (size_t)rj1 * 128))[g];

            int sl2 = lb + ((2 < rem) ? s + 2 : s);
            int rj2 = __shfl(sidx, sl2);
            float pj2 = (2 < rem) ? ((const float*)&sp[sl2])[head] : 0.f;
            H8 u2 = ((const H8*)(h1h + (size_t)rj2 * 128))[g];

            int sl3 = lb + ((3 < rem) ? s + 3 : s);
            int rj3 = __shfl(sidx, sl3);
            float pj3 = (3 < rem) ? ((const float*)&sp[sl3])[head] : 0.f;
            H8 u3 = ((const H8*)(h1h + (size_t)rj3 * 128))[g];

            // ---- consume ----
            dnum += pj0; dnum += pj1; dnum += pj2; dnum += pj3;
            a0.x += (float)u0.h[0].x * pj0; a0.y += (float)u0.h[0].y * pj0;
            a0.z += (float)u0.h[1].x * pj0; a0.w += (float)u0.h[1].y * pj0;
            a1.x += (float)u0.h[2].x * pj0; a1.y += (float)u0.h[2].y * pj0;
            a1.z += (float)u0.h[3].x * pj0; a1.w += (float)u0.h[3].y * pj0;

            a0.x += (float)u1.h[0].x * pj1; a0.y += (float)u1.h[0].y * pj1;
            a0.z += (float)u1.h[1].x * pj1; a0.w += (float)u1.h[1].y * pj1;
            a1.x += (float)u1.h[2].x * pj1; a1.y += (float)u1.h[2].y * pj1;
            a1.z += (float)u1.h[3].x * pj1; a1.w += (float)u1.h[3].y * pj1;

            a0.x += (float)u2.h[0].x * pj2; a0.y += (float)u2.h[0].y * pj2;
            a0.z += (float)u2.h[1].x * pj2; a0.w += (float)u2.h[1].y * pj2;
            a1.x += (float)u2.h[2].x * pj2; a1.y += (float)u2.h[2].y * pj2;
            a1.z += (float)u2.h[3].x * pj2; a1.w += (float)u2.h[3].y * pj2;

            a0.x += (float)u3.h[0].x * pj3; a0.y += (float)u3.h[0].y * pj3;
            a0.z += (float)u3.h[1].x * pj3; a0.w += (float)u3.h[1].y * pj3;
            a1.x += (float)u3.h[2].x * pj3; a1.y += (float)u3.h[2].y * pj3;
            a1.z += (float)u3.h[3].x * pj3; a1.w += (float)u3.h[3].y * pj3;
        }
    }
    // self loop (every lane: its own 8 channels)
    {
        H8 u = ((const H8*)(h1h + (size_t)nc * 128))[g];
        dnum += psf_h;
        a0.x += (float)u.h[0].x * psf_h; a0.y += (float)u.h[0].y * psf_h;
        a0.z += (float)u.h[1].x * psf_h; a0.w += (float)u.h[1].y * psf_h;
        a1.x += (float)u.h[2].x * psf_h; a1.y += (float)u.h[2].y * psf_h;
        a1.z += (float)u.h[3].x * psf_h; a1.w += (float)u.h[3].y * psf_h;
    }
    // dnum and a0/a1 are COMPLETE per lane -- no reduction needed.
    if (vn) {
        float inv = __builtin_amdgcn_rcpf(dnum);
        const float4* b4 = (const float4*)b1;
        float4 bb0 = b4[g * 2], bb1 = b4[g * 2 + 1];
        float4 r0 = make_float4(elu(a0.x * inv + bb0.x), elu(a0.y * inv + bb0.y),
                                elu(a0.z * inv + bb0.z), elu(a0.w * inv + bb0.w));
        float4 r1 = make_float4(elu(a1.x * inv + bb1.x), elu(a1.y * inv + bb1.y),
                                elu(a1.z * inv + bb1.z), elu(a1.w * inv + bb1.w));
        H8 o8;
        o8.h[0] = half2v{(_Float16)r0.x, (_Float16)r0.y};
        o8.h[1] = half2v{(_Float16)r0.z, (_Float16)r0.w};
        o8.h[2] = half2v{(_Float16)r1.x, (_Float16)r1.y};
        o8.h[3] = half2v{(_Float16)r1.z, (_Float16)r1.w};
        *(float4*)&s_row[wave][q4][g * 8] = o8.f4;
    }
    // ---- fused layer-2 GEMV: 16 lanes/node, 2 output cols per lane ----
    int c0 = l4, c1 = l4 + 16;
    float acc2a = 0.f, acc2b = 0.f;
#pragma unroll
    for (int k8 = 0; k8 < 16; ++k8) {
        HH rv, w0, w1;
        rv.v = *(const f16x8*)&s_row[wave][q4][k8 * 8];
        w0.v = *(const f16x8*)&sW2[c0 * W2S + k8 * 8];
        w1.v = *(const f16x8*)&sW2[c1 * W2S + k8 * 8];
#if __has_builtin(__builtin_amdgcn_fdot2)
        acc2a = __builtin_amdgcn_fdot2(rv.h[0], w0.h[0], acc2a, false);
        acc2a = __builtin_amdgcn_fdot2(rv.h[1], w0.h[1], acc2a, false);
        acc2a = __builtin_amdgcn_fdot2(rv.h[2], w0.h[2], acc2a, false);
        acc2a = __builtin_amdgcn_fdot2(rv.h[3], w0.h[3], acc2a, false);
        acc2b = __builtin_amdgcn_fdot2(rv.h[0], w1.h[0], acc2b, false);
        acc2b = __builtin_amdgcn_fdot2(rv.h[1], w1.h[1], acc2b, false);
        acc2b = __builtin_amdgcn_fdot2(rv.h[2], w1.h[2], acc2b, false);
        acc2b = __builtin_amdgcn_fdot2(rv.h[3], w1.h[3], acc2b, false);
#else
#pragma unroll
        for (int e = 0; e < 8; ++e) {
            acc2a += (float)rv.v[e] * (float)w0.v[e];
            acc2b += (float)rv.v[e] * (float)w1.v[e];
        }
#endif
    }
    float ps = acc2a * a_src2[c0] + acc2b * a_src2[c1];
    float pd = acc2a * a_dst2[c0] + acc2b * a_dst2[c1];
#pragma unroll
    for (int o = 1; o < 16; o <<= 1) { ps += __shfl_xor(ps, o); pd += __shfl_xor(pd, o); }
    if (vn) {
        h2h[(size_t)nid * 32 + c0] = (_Float16)acc2a;
        h2h[(size_t)nid * 32 + c1] = (_Float16)acc2b;
        if (l4 == 0) { as2[nid] = ps; ad2[nid] = pd; }
    }
}

// D4: layer-2 softmax + aggregate (8 nodes/wave), batched x4 gathers.
__global__ __launch_bounds__(256) void agg2_kernel(const _Float16* __restrict__ h2h,
                                                   const float* __restrict__ as2,
                                                   const float* __restrict__ ad2,
                                                   const int* __restrict__ rp,
                                                   const int* __restrict__ col,
                                                   const float* __restrict__ b2,
                                                   float* __restrict__ out, int n) {
    int wave = threadIdx.x >> 6, lane = threadIdx.x & 63;
    int q8 = lane >> 3, l3 = lane & 7;
    int g = l3;                               // ch-group (4 ch each)
    int nid = blockIdx.x * 32 + wave * 8 + q8;
    bool vn = nid < n;
    int nc = vn ? nid : 0;
    int start = rp[nc];
    int end = vn ? rp[nc + 1] : start;
    float adn = ad2[nc];
    float psf = vn ? __expf(leaky(as2[nc] + adn)) : 0.f;
    float dnum = 0.f;
    float4 acc = make_float4(0.f, 0.f, 0.f, 0.f);
    int lb = lane & 56;
    for (int base = start; base < end; base += 8) {
        int i = base + l3;
        int sidx = 0;
        float p = 0.f;
        if (i < end) {
            sidx = col[i];
            p = __expf(leaky(as2[sidx] + adn));
        }
        int len = min(8, end - base);
        for (int s = 0; s < len; s += 4) {
            int rem = len - s;
            int sl0 = lb + s;
            int rj0 = __shfl(sidx, sl0);
            float pj0 = __shfl(p, sl0);
            H4 u0 = ((const H4*)(h2h + (size_t)rj0 * 32))[g];

            int sl1 = lb + ((1 < rem) ? s + 1 : s);
            int rj1 = __shfl(sidx, sl1);
            float pj1 = (1 < rem) ? __shfl(p, sl1) : 0.f;
            H4 u1 = ((const H4*)(h2h + (size_t)rj1 * 32))[g];

            int sl2 = lb + ((2 < rem) ? s + 2 : s);
            int rj2 = __shfl(sidx, sl2);
            float pj2 = (2 < rem) ? __shfl(p, sl2) : 0.f;
            H4 u2 = ((const H4*)(h2h + (size_t)rj2 * 32))[g];

            int sl3 = lb + ((3 < rem) ? s + 3 : s);
            int rj3 = __shfl(sidx, sl3);
            float pj3 = (3 < rem) ? __shfl(p, sl3) : 0.f;
            H4 u3 = ((const H4*)(h2h + (size_t)rj3 * 32))[g];

            dnum += pj0; dnum += pj1; dnum += pj2; dnum += pj3;
            acc.x += (float)u0.h[0].x * pj0; acc.y += (float)u0.h[0].y * pj0;
            acc.z += (float)u0.h[1].x * pj0; acc.w += (float)u0.h[1].y * pj0;
            acc.x += (float)u1.h[0].x * pj1; acc.y += (float)u1.h[0].y * pj1;
            acc.z += (float)u1.h[1].x * pj1; acc.w += (float)u1.h[1].y * pj1;
            acc.x += (float)u2.h[0].x * pj2; acc.y += (float)u2.h[0].y * pj2;
            acc.z += (float)u2.h[1].x * pj2; acc.w += (float)u2.h[1].y * pj2;
            acc.x += (float)u3.h[0].x * pj3; acc.y += (float)u3.h[0].y * pj3;
            acc.z += (float)u3.h[1].x * pj3; acc.w += (float)u3.h[1].y * pj3;
        }
    }
    {
        H4 u = ((const H4*)(h2h + (size_t)nc * 32))[g];
        dnum += psf;
        acc.x += (float)u.h[0].x * psf; acc.y += (float)u.h[0].y * psf;
        acc.z += (float)u.h[1].x * psf; acc.w += (float)u.h[1].y * psf;
    }
    // dnum and acc complete per lane -- direct store.
    if (vn) {
        float inv = __builtin_amdgcn_rcpf(dnum);
        float4 bb = ((const float4*)b2)[g];
        ((float4*)(out + (size_t)nid * 32))[g] =
            make_float4(acc.x * inv + bb.x, acc.y * inv + bb.y,
                        acc.z * inv + bb.z, acc.w * inv + bb.w);
    }
}

// ================= launch =================

extern "C" void kernel_launch(void* const* d_in, const int* in_sizes, int n_in,
                              void* d_out, int out_size, void* d_ws, size_t ws_size,
                              hipStream_t stream) {
    const float* x      = (const float*)d_in[0];
    const int*   ei     = (const int*)d_in[1];
    const float* W1     = (const float*)d_in[2];
    const float* a_src1 = (const float*)d_in[3];
    const float* a_dst1 = (const float*)d_in[4];
    const float* b1     = (const float*)d_in[5];
    const float* W2     = (const float*)d_in[6];
    const float* a_src2 = (const float*)d_in[7];
    const float* a_dst2 = (const float*)d_in[8];
    const float* b2     = (const float*)d_in[9];
    float* out = (float*)d_out;

    const int N = in_sizes[0] / 128;
    const int E = in_sizes[1] / 2;
    const int* src = ei;
    const int* dstp = ei + E;

    uint8_t* w = (uint8_t*)d_ws;
    auto carve = [&](size_t bytes) {
        uint8_t* p = w;
        w += (bytes + 255) & ~(size_t)255;
        return p;
    };
    _Float16* h1h = (_Float16*)carve((size_t)N * 128 * 2);
    _Float16* h2h = (_Float16*)carve((size_t)N * 32 * 2);
    _Float16* W1t = (_Float16*)carve((size_t)128 * 128 * 2);
    _Float16* W2t = (_Float16*)carve((size_t)32 * 128 * 2);
    float* as1 = (float*)carve((size_t)N * 4 * 4);
    float* ad1 = (float*)carve((size_t)N * 4 * 4);
    float* as2 = (float*)carve((size_t)N * 4);
    float* ad2 = (float*)carve((size_t)N * 4);
    int* rp    = (int*)carve((size_t)(N + 1) * 4);
    int* col   = (int*)carve((size_t)E * 4);
    int* bcur  = (int*)carve(256 * 4);       // per-bucket cursors

    const int NB = ((N - 1) >> 8) + 1;       // coarse buckets
    const int KB = (N >> 8) + 1;             // csr blocks (covers rp[N] corner)
    int CH = (E + PB - 1) / PB;
    CH = (CH + 3) & ~3;                      // int4 alignment of chunk bases
    const int gemmBlocks = (N + 63) / 64;
    const int agg1Groups = (N + 15) / 16;    // 16 nodes per block (4 per wave)
    const int agg2Groups = (N + 31) / 32;    // 32 nodes per block (8 per wave)

    int2* pairs = (int2*)carve((size_t)NB * CAP * 8);   // 8 MB

    // D0: zero bucket cursors (1 KB)
    hipMemsetAsync(bcur, 0, 256 * 4, stream);
    // D1: pair scatter (cursor-reserved bases) + weight transposes
    pairprep_kernel<<<PB + 80, 256, 0, stream>>>(src, dstp, bcur, pairs,
                                                 E, NB, CH, W1, W2, W1t, W2t);
    // D2: csr buckets + MFMA gemm1 (independent; csr hides under gemm)
    csr_gemm_kernel<<<KB + gemmBlocks, 256, 0, stream>>>(
        pairs, bcur, rp, col, E, N, NB, KB,
        x, W1t, a_src1, a_dst1, h1h, as1, ad1);
    // D3: layer-1 aggregate + fused layer-2 GEMV (4 nodes/wave, batched gathers)
    agg1_kernel<<<agg1Groups, 256, 0, stream>>>(h1h, (const float4*)as1,
                                                (const float4*)ad1, rp, col, b1,
                                                W2t, a_src2, a_dst2, h2h, as2, ad2, N);
    // D4: layer-2 aggregate (8 nodes/wave, batched gathers)
    agg2_kernel<<<agg2Groups, 256, 0, stream>>>(h2h, as2, ad2, rp, col, b2, out, N);
}